// Round 11
// baseline (367.050 us; speedup 1.0000x reference)
//
#include <hip/hip_runtime.h>

// Problem constants (Transformer-XL attention)
constexpr int BSZ  = 4;
constexpr int NH   = 16;
constexpr int DH   = 64;
constexpr int QL   = 1024;
constexpr int KLN  = 2048;
constexpr int DM   = 1024;   // d_model = NH*DH
constexpr int MEM  = 1024;   // KLEN - QLEN

typedef __bf16 bf16x8  __attribute__((ext_vector_type(8)));
typedef __bf16 bf16x4t __attribute__((ext_vector_type(4)));
typedef float  f32x4   __attribute__((ext_vector_type(4)));

// async global->LDS, 16B per lane; LDS dst is wave-uniform base + lane*16
__device__ __forceinline__ void g2l16(__bf16* lds, const __bf16* g) {
    __builtin_amdgcn_global_load_lds(
        (const __attribute__((address_space(1))) unsigned int*)g,
        (__attribute__((address_space(3))) unsigned int*)lds, 16, 0, 0);
}

// ---------------------------------------------------------------------------
// prep: one launch. Blocks [0,5120): cast w,r -> bf16. Blocks [5120,7168):
// transpose-cast the 4 weights (z = t>>9: 0 Wq, 1 Wr, 2 Wo, 3 Wkv).
// ---------------------------------------------------------------------------
__global__ __launch_bounds__(256)
void prep(const float* __restrict__ w, const float* __restrict__ r,
          const float* __restrict__ Wq, const float* __restrict__ Wr,
          const float* __restrict__ Wo, const float* __restrict__ Wkv,
          __bf16* __restrict__ wbh, __bf16* __restrict__ rbh,
          __bf16* __restrict__ WqT, __bf16* __restrict__ WrT,
          __bf16* __restrict__ WoT, __bf16* __restrict__ WkvT)
{
    __shared__ __bf16 t[64 * 72];
    const int id = blockIdx.x;
    if (id < 5120) {
        const float* in; __bf16* out; size_t i;
        if (id < 4096) { in = w; out = wbh; i = ((size_t)id * 256 + threadIdx.x) * 8; }
        else { in = r; out = rbh; i = ((size_t)(id - 4096) * 256 + threadIdx.x) * 8; }
        float4 a = *(const float4*)(in + i);
        float4 b = *(const float4*)(in + i + 4);
        bf16x8 y = {(__bf16)a.x, (__bf16)a.y, (__bf16)a.z, (__bf16)a.w,
                    (__bf16)b.x, (__bf16)b.y, (__bf16)b.z, (__bf16)b.w};
        *(bf16x8*)(out + i) = y;
        return;
    }
    const int tt = id - 5120;
    const int z = tt >> 9, rem = tt & 511;
    const int xx = rem & 31, yy = rem >> 5;
    const float* in; __bf16* out; int N;
    if (z == 0)      { in = Wq;  out = WqT;  N = 1024; }
    else if (z == 1) { in = Wr;  out = WrT;  N = 1024; }
    else if (z == 2) { in = Wo;  out = WoT;  N = 1024; }
    else             { in = Wkv; out = WkvT; N = 2048; }
    if (xx * 64 >= N) return;
    const int n0 = xx * 64, k0 = yy * 64;
    const int row = threadIdx.x >> 2, seg = (threadIdx.x & 3) << 4;
    const float* src = in + (long)(k0 + row) * N + n0 + seg;
#pragma unroll
    for (int u = 0; u < 16; u += 4) {
        float4 x = *(const float4*)(src + u);
        t[(seg + u + 0) * 72 + row] = (__bf16)x.x;
        t[(seg + u + 1) * 72 + row] = (__bf16)x.y;
        t[(seg + u + 2) * 72 + row] = (__bf16)x.z;
        t[(seg + u + 3) * 72 + row] = (__bf16)x.w;
    }
    __syncthreads();
    __bf16* dst = out + (long)(n0 + row) * 1024 + k0 + seg;
    *(uint4*)(dst)     = *(const uint4*)(t + row * 72 + seg);
    *(uint4*)(dst + 8) = *(const uint4*)(t + row * 72 + seg + 8);
}

// ---------------------------------------------------------------------------
// Shared GEMM core R15: 128x128 tile, BK=32, 4 waves, 2-phase double-buffer
// (kept: marginally positive, race-clean; incremental pipelining on this
// structure is otherwise confirmed null, matching m99/m100).
// ---------------------------------------------------------------------------
__device__ __forceinline__ void gemm_core(
    const __bf16* __restrict__ A, const __bf16* __restrict__ BT,
    __bf16* As, __bf16* Bs, int m0, int n0, int K, f32x4 (&acc)[4][4])
{
    const int tid = threadIdx.x, w = tid >> 6, l = tid & 63;
    const int il = l & 15, quad = l >> 4;
    const int wm = (w >> 1) * 64, wn = (w & 1) * 64;
    const int lr = l >> 2, kc = (l & 3) ^ (lr & 3);

    const __bf16* ag = A  + (long)(m0 + w * 32 + lr) * K + kc * 8;
    const __bf16* bg = BT + (long)(n0 + w * 32 + lr) * K + kc * 8;
    const int aoff0 = (w * 32) * 32;
    const int aoff1 = (w * 32 + 16) * 32;
    const int rsw = il & 3;
    const int rdoff = (quad ^ rsw) << 3;

    // prologue: stage tile k0=0 into buffer 0
    g2l16(As + aoff0, ag);
    g2l16(As + aoff1, ag + 16 * K);
    g2l16(Bs + aoff0, bg);
    g2l16(Bs + aoff1, bg + 16 * K);
    __syncthreads();                      // drains vmcnt; buf0 ready

    int cur = 0;
    for (int k0 = 0; k0 < K; k0 += 32) {
        const int nxt = cur ^ 1;
        if (k0 + 32 < K) {                // async prefetch next K-tile
            g2l16(As + nxt * 4096 + aoff0, ag + k0 + 32);
            g2l16(As + nxt * 4096 + aoff1, ag + k0 + 32 + 16 * K);
            g2l16(Bs + nxt * 4096 + aoff0, bg + k0 + 32);
            g2l16(Bs + nxt * 4096 + aoff1, bg + k0 + 32 + 16 * K);
        }

        bf16x8 af[4], bf[4];
#pragma unroll
        for (int f = 0; f < 4; ++f) {
            af[f] = *(const bf16x8*)(As + cur * 4096 + (wm + f * 16 + il) * 32 + rdoff);
            bf[f] = *(const bf16x8*)(Bs + cur * 4096 + (wn + f * 16 + il) * 32 + rdoff);
        }
#pragma unroll
        for (int i = 0; i < 4; ++i)
#pragma unroll
            for (int j = 0; j < 4; ++j)
                acc[i][j] = __builtin_amdgcn_mfma_f32_16x16x32_bf16(
                    af[i], bf[j], acc[i][j], 0, 0, 0);

        __syncthreads();                  // prefetch drained; cur reusable
        cur = nxt;
    }
}

// ---------------------------------------------------------------------------
// Merged projection GEMM: 1408 blocks.
// ---------------------------------------------------------------------------
__global__ __launch_bounds__(256, 2)
void gemm_proj(const __bf16* __restrict__ wbh, const __bf16* __restrict__ rbh,
               const __bf16* __restrict__ WqT, const __bf16* __restrict__ WkvT,
               const __bf16* __restrict__ WrT,
               __bf16* __restrict__ qwh, __bf16* __restrict__ qrh,
               __bf16* __restrict__ kh, __bf16* __restrict__ vhT,
               __bf16* __restrict__ rkh,
               const float* __restrict__ bw, const float* __restrict__ br)
{
    __shared__ __bf16 As[2 * 128 * 32];
    __shared__ __bf16 Bs[2 * 128 * 32];
    const int id = blockIdx.x;
    const __bf16 *A, *BT;
    int m0, n0, zz, kind;
    if (id < 1024) {
        n0 = (id & 15) * 128; m0 = ((id >> 4) & 15) * 128; zz = id >> 8;
        A = wbh + (size_t)zz * KLN * DM; BT = WkvT; kind = 3;
    } else if (id < 1280) {
        const int t = id - 1024;
        n0 = (t & 7) * 128; m0 = ((t >> 3) & 7) * 128; zz = t >> 6;
        A = wbh + (size_t)zz * KLN * DM + (size_t)MEM * DM; BT = WqT; kind = 2;
    } else {
        const int t = id - 1280;
        n0 = (t & 7) * 128; m0 = (t >> 3) * 128; zz = 0;
        A = rbh; BT = WrT; kind = 4;
    }

    f32x4 acc[4][4] = {};
    gemm_core(A, BT, As, Bs, m0, n0, DM, acc);

    const int tid = threadIdx.x, w = tid >> 6, l = tid & 63;
    const int il = l & 15, quad = l >> 4;
    const int wm = (w >> 1) * 64, wn = (w & 1) * 64;

    if (kind == 2) {
#pragma unroll
        for (int j = 0; j < 4; ++j) {
            const int col = n0 + wn + j * 16 + il;
            const int hn = col >> 6, d = col & 63;
            const float bwv = bw[col], brv = br[col];
            __bf16* q1 = qwh + ((size_t)(zz * 16 + hn) * 1024) * 64 + d;
            __bf16* q2 = qrh + ((size_t)(zz * 16 + hn) * 1024) * 64 + d;
#pragma unroll
            for (int i = 0; i < 4; ++i) {
                const int mb = m0 + wm + i * 16 + quad * 4;
#pragma unroll
                for (int rr = 0; rr < 4; ++rr) {
                    float v = acc[i][j][rr];
                    q1[(size_t)(mb + rr) * 64] = (__bf16)(v + bwv);
                    q2[(size_t)(mb + rr) * 64] = (__bf16)(v + brv);
                }
            }
        }
    } else if (kind == 3) {
        if (n0 + wn < 1024) {
#pragma unroll
            for (int j = 0; j < 4; ++j) {
                const int col = n0 + wn + j * 16 + il;
                const int hn = col >> 6, d = col & 63;
                __bf16* kp = kh + ((size_t)(zz * 16 + hn) * 2048) * 64 + d;
#pragma unroll
                for (int i = 0; i < 4; ++i) {
                    const int mb = m0 + wm + i * 16 + quad * 4;
#pragma unroll
                    for (int rr = 0; rr < 4; ++rr)
                        kp[(size_t)(mb + rr) * 64] = (__bf16)acc[i][j][rr];
                }
            }
        } else {
#pragma unroll
            for (int j = 0; j < 4; ++j) {
                const int col = n0 + wn + j * 16 + il - 1024;
                const int hn = col >> 6, d = col & 63;
                __bf16* vp = vhT + ((size_t)((zz * 16 + hn) * 64 + d)) * 2048;
#pragma unroll
                for (int i = 0; i < 4; ++i) {
                    const int mb = m0 + wm + i * 16 + quad * 4;
                    bf16x4t pk = {(__bf16)acc[i][j][0], (__bf16)acc[i][j][1],
                                  (__bf16)acc[i][j][2], (__bf16)acc[i][j][3]};
                    *(bf16x4t*)(vp + mb) = pk;
                }
            }
        }
    } else { // kind 4
#pragma unroll
        for (int j = 0; j < 4; ++j) {
            const int col = n0 + wn + j * 16 + il;
            const int hn = col >> 6, d = col & 63;
            __bf16* rp = rkh + ((size_t)hn * 2048) * 64 + d;
#pragma unroll
            for (int i = 0; i < 4; ++i) {
                const int mb = m0 + wm + i * 16 + quad * 4;
#pragma unroll
                for (int rr = 0; rr < 4; ++rr)
                    rp[(size_t)(mb + rr) * 64] = (__bf16)acc[i][j][rr];
            }
        }
    }
}

// ---------------------------------------------------------------------------
// Output projection: out = avh @ WoT^T, f32 C.  Grid (8,8,4).
// ---------------------------------------------------------------------------
__global__ __launch_bounds__(256, 2)
void gemm_out(const __bf16* __restrict__ avh, const __bf16* __restrict__ WoT,
              float* __restrict__ C)
{
    __shared__ __bf16 As[2 * 128 * 32];
    __shared__ __bf16 Bs[2 * 128 * 32];
    const int zz = blockIdx.z;
    const __bf16* A = avh + (size_t)zz * QL * DM;
    const int m0 = blockIdx.y * 128, n0 = blockIdx.x * 128;

    f32x4 acc[4][4] = {};
    gemm_core(A, WoT, As, Bs, m0, n0, DM, acc);

    const int tid = threadIdx.x, w = tid >> 6, l = tid & 63;
    const int il = l & 15, quad = l >> 4;
    const int wm = (w >> 1) * 64, wn = (w & 1) * 64;
    float* Cb = C + (size_t)zz * QL * DM;
#pragma unroll
    for (int i = 0; i < 4; ++i)
#pragma unroll
        for (int j = 0; j < 4; ++j) {
            float* cp = Cb + (long)(m0 + wm + i * 16 + quad * 4) * DM
                           + n0 + wn + j * 16 + il;
#pragma unroll
            for (int rr = 0; rr < 4; ++rr) cp[(long)rr * DM] = acc[i][j][rr];
        }
}

// ---------------------------------------------------------------------------
// MFMA flash attention, R16: R13 core + V-DESTAGE -> 3 BLOCKS/CU.
// R13 verified 136-138us (K/rk staged, f32 scratch).  R14 verified the
// V-direct global read path's CORRECTNESS (its perf failure was exposing
// latency on ALL operands).  Here only V is de-staged: its 8 loads issue
// with the staging (sharing the barrier's vmcnt drain) and are consumed
// ~1500 cyc later at PV -> latency fully hidden.  Dropping vt (8KB) puts
// LDS at kt 8192 + rkt 24576 + scf 21504 = 54272 B <= 54613 -> 3 blocks/CU
// (12 waves/CU, +50% latency hiding on the serial softmax chain).
// launch_bounds stays (256,2) -- R10 lesson: do NOT force the allocator;
// VGPR ~128 permits 4 waves/SIMD, LDS sets occupancy naturally.
// ---------------------------------------------------------------------------
__global__ __launch_bounds__(256, 2)
void attn_mfma(const __bf16* __restrict__ qwh, const __bf16* __restrict__ qrh,
               const __bf16* __restrict__ kh, const __bf16* __restrict__ vhT,
               const __bf16* __restrict__ rkh, float* __restrict__ Op,
               float* __restrict__ ml)
{
    extern __shared__ __bf16 smem[];
    __bf16* kt  = smem;            // [64][64] xor-swizzled, 8KB
    __bf16* rkt = smem + 4096;     // [192][64] xor, circular, 24KB
    float*  scf = (float*)(smem + 16384);  // 4 waves x [16][84] f32, 21.5KB

    const int bx = blockIdx.x;
    const int part = bx & 1;
    const int bx2 = bx >> 1;                     // 0..7
    const int ib = (bx2 & 1) ? (7 - (bx2 >> 1)) : (bx2 >> 1);
    const int i0 = ib * 128;
    const int n = blockIdx.y, b = blockIdx.z;
    const int tid = threadIdx.x;
    const int w = tid >> 6, l = tid & 63;
    const int il = l & 15, quad = l >> 4;
    const int iw0 = i0 + w * 32;

    // persistent Q fragments, 2 i-frags per wave
    bf16x8 qwf[2][2], qrf[2][2];
#pragma unroll
    for (int g = 0; g < 2; ++g) {
        const size_t qoff =
            ((size_t)((b * 16 + n) * QL + iw0 + 16 * g + il)) * 64 + quad * 8;
        qwf[g][0] = *(const bf16x8*)(qwh + qoff);
        qwf[g][1] = *(const bf16x8*)(qwh + qoff + 32);
        qrf[g][0] = *(const bf16x8*)(qrh + qoff);
        qrf[g][1] = *(const bf16x8*)(qrh + qoff + 32);
    }

    f32x4 O[2][4] = {};
    float m_i[2] = {-1e30f, -1e30f}, l_i[2] = {0.f, 0.f};
    const float c = 0.125f * 1.44269504f;        // scale * log2(e)

    const int srow = l >> 3, scl = l & 7;        // staging: 8 rows x 8 chunks
    const __bf16* kbase  = kh  + ((size_t)((b * 16 + n) * KLN)) * 64;
    const __bf16* vbase0 = vhT + ((size_t)((b * 16 + n) * 64)) * KLN;
    const __bf16* rbp    = rkh + ((size_t)(n * KLN)) * 64;

    const int xk0 = ((quad) ^ (il & 7)) << 3;
    const int xk1 = ((quad + 4) ^ (il & 7)) << 3;

    const int nt = 2 * ib + 18;
    const int t0 = (part * nt) / 2;
    const int t1 = ((part + 1) * nt) / 2;
    int rot = (t0 % 3) * 64;                     // circular offset for tile t0

    const int ubB = 96 - 32 * w;                 // logical base of shared BD frags

    for (int jt = t0; jt < t1; ++jt) {
        const int j0 = jt * 64;
        const int vu0 = j0 - i0 + 896;           // rk row of logical rkt row 0
        __syncthreads();
#pragma unroll
        for (int it = 0; it < 2; ++it) {         // K tile rows j
            const int row = w * 16 + it * 8 + srow;
            g2l16(kt + (w * 16 + it * 8) * 64,
                  kbase + ((size_t)(j0 + row)) * 64 + ((scl ^ srow) << 3));
        }
        if (jt == t0) {                          // full 192-row window fill
#pragma unroll
            for (int it = 0; it < 6; ++it) {
                const int lbase = w * 48 + it * 8;
                int pb = lbase + rot; if (pb >= 192) pb -= 192;
                int vu = vu0 + lbase + srow;
                vu = vu < 0 ? 0 : (vu > KLN - 1 ? KLN - 1 : vu);
                g2l16(rkt + pb * 64,
                      rbp + (size_t)vu * 64 + ((scl ^ srow) << 3));
            }
        } else {                                 // slide: logical rows 128..191
#pragma unroll
            for (int it = 0; it < 2; ++it) {
                const int lbase = 128 + w * 16 + it * 8;
                int pb = lbase + rot; if (pb >= 192) pb -= 192;
                int vu = vu0 + lbase + srow;
                vu = vu < 0 ? 0 : (vu > KLN - 1 ? KLN - 1 : vu);
                g2l16(rkt + pb * 64,
                      rbp + (size_t)vu * 64 + ((scl ^ srow) << 3));
            }
        }

        // ---- V^T frags DIRECT from global (R14-verified addressing);
        // issued alongside staging, drained by the same barrier, consumed
        // at PV ~1500 cyc later -> latency hidden.
        bf16x8 va[4][2];
#pragma unroll
        for (int df = 0; df < 4; ++df) {
            const __bf16* vp_ = vbase0 + (size_t)(df * 16 + il) * KLN + j0 + quad * 8;
            va[df][0] = *(const bf16x8*)(vp_);
            va[df][1] = *(const bf16x8*)(vp_ + 32);
        }
        __syncthreads();

        const bool edge = (j0 + 63 > i0 + MEM);

        // ---- Phase 1: AC for both g (kt frags read ONCE)
        f32x4 sf[2][4];
#pragma unroll
        for (int fr = 0; fr < 4; ++fr) {
            const __bf16* ka = kt + (fr * 16 + il) * 64;
            bf16x8 a0 = *(const bf16x8*)(ka + xk0);
            bf16x8 a1 = *(const bf16x8*)(ka + xk1);
            __builtin_amdgcn_s_setprio(1);
#pragma unroll
            for (int g = 0; g < 2; ++g) {
                f32x4 acc = {};
                acc = __builtin_amdgcn_mfma_f32_16x16x32_bf16(a0, qwf[g][0], acc, 0, 0, 0);
                acc = __builtin_amdgcn_mfma_f32_16x16x32_bf16(a1, qwf[g][1], acc, 0, 0, 0);
                sf[g][fr] = acc;
            }
            __builtin_amdgcn_s_setprio(0);
        }

        // ---- rk fragment loads, once per tile (used by both g)
        bf16x8 ra[6][2];
#pragma unroll
        for (int uf2 = 0; uf2 < 6; ++uf2) {
            int pr = ubB + uf2 * 16 + il + rot; if (pr >= 192) pr -= 192;
            const __bf16* rp_ = rkt + pr * 64;
            ra[uf2][0] = *(const bf16x8*)(rp_ + xk0);
            ra[uf2][1] = *(const bf16x8*)(rp_ + xk1);
        }

        // ---- per-g: BD(f32 scratch) -> gather/softmax -> P(scratch) -> PV
        float* scw = scf + w * 1344;             // per-wave [16][84] f32
#pragma unroll
        for (int g = 0; g < 2; ++g) {
            // BD: 5 frags, idx = uf+1-g (g0: ra[1..5], g1: ra[0..4])
#pragma unroll
            for (int uf = 0; uf < 5; ++uf) {
                const int idx = uf + 1 - g;
                f32x4 acc = {};
                __builtin_amdgcn_s_setprio(1);
                acc = __builtin_amdgcn_mfma_f32_16x16x32_bf16(ra[idx][0], qrf[g][0], acc, 0, 0, 0);
                acc = __builtin_amdgcn_mfma_f32_16x16x32_bf16(ra[idx][1], qrf[g][1], acc, 0, 0, 0);
                __builtin_amdgcn_s_setprio(0);
                *(f32x4*)(scw + il * 84 + uf * 16 + quad * 4) = acc;
            }

            const int i_gl = iw0 + 16 * g + il;
            float sv[4][4];
            float tmax = -1e30f;
#pragma unroll
            for (int fr = 0; fr < 4; ++fr) {
                const int base = il * 83 + fr * 16 + quad * 4 + 15;  // = il*84 + (jl_-il+15)
#pragma unroll
                for (int rr = 0; rr < 4; ++rr) {
                    const int jl_ = fr * 16 + quad * 4 + rr;
                    float s = sf[g][fr][rr] + scw[base + rr];
                    if (edge) s = (j0 + jl_ > i_gl + MEM) ? -1e30f : s;
                    sv[fr][rr] = s;
                    tmax = fmaxf(tmax, s);
                }
            }
            tmax = fmaxf(tmax, __shfl_xor(tmax, 16));
            tmax = fmaxf(tmax, __shfl_xor(tmax, 32));
            const float m_new = fmaxf(m_i[g], tmax);
            const float alpha = exp2f((m_i[g] - m_new) * c);
            float psum = 0.f;
            __bf16* prow = (__bf16*)(scw + il * 84);   // P overwrites row head
#pragma unroll
            for (int fr = 0; fr < 4; ++fr) {
                bf16x4t p4;
#pragma unroll
                for (int rr = 0; rr < 4; ++rr) {
                    float p = exp2f((sv[fr][rr] - m_new) * c);
                    psum += p;
                    p4[rr] = (__bf16)p;
                }
                // after all gathers for this g (same wave): safe overwrite
                *(bf16x4t*)(prow + fr * 16 + quad * 4) = p4;
            }
            psum += __shfl_xor(psum, 16);
            psum += __shfl_xor(psum, 32);
            l_i[g] = l_i[g] * alpha + psum;
            m_i[g] = m_new;
#pragma unroll
            for (int df = 0; df < 4; ++df) O[g][df] *= alpha;

            bf16x8 p0 = *(const bf16x8*)(prow + quad * 8);
            bf16x8 p1 = *(const bf16x8*)(prow + 32 + quad * 8);
            __builtin_amdgcn_s_setprio(1);
#pragma unroll
            for (int df = 0; df < 4; ++df) {
                O[g][df] = __builtin_amdgcn_mfma_f32_16x16x32_bf16(va[df][0], p0, O[g][df], 0, 0, 0);
                O[g][df] = __builtin_amdgcn_mfma_f32_16x16x32_bf16(va[df][1], p1, O[g][df], 0, 0, 0);
            }
            __builtin_amdgcn_s_setprio(0);
        }
        rot += 64; if (rot >= 192) rot -= 192;
    }

    // ---- write partials (unnormalized)
#pragma unroll
    for (int g = 0; g < 2; ++g) {
        const int iL = w * 32 + 16 * g + il;
        float* opb = Op + (size_t)part * 4194304
                        + ((((size_t)b * NH + n) * 8 + ib)) * 8192
                        + (size_t)iL * 64 + quad * 4;
#pragma unroll
        for (int df = 0; df < 4; ++df)
            *(f32x4*)(opb + df * 16) = O[g][df];
        if (quad == 0) {
            const size_t base = (((size_t)b * NH + n) * 8 + ib) * 128 + iL;
            ml[(size_t)part * 65536 + base]          = m_i[g];
            ml[131072 + (size_t)part * 65536 + base] = l_i[g];
        }
    }
}

// ---------------------------------------------------------------------------
// Combine 2 attention partials -> avh bf16.  Grid (QL/4, NH, BSZ).
// ---------------------------------------------------------------------------
__global__ __launch_bounds__(256)
void attn_combine(const float* __restrict__ Op, const float* __restrict__ ml,
                  __bf16* __restrict__ av)
{
    const int tid = threadIdx.x;
    const int i = blockIdx.x * 4 + (tid >> 6);
    const int d = tid & 63;
    const int n = blockIdx.y, b = blockIdx.z;
    const int ib = i >> 7, iL = i & 127;
    const float c = 0.125f * 1.44269504f;

    const size_t mb = (((size_t)b * NH + n) * 8 + ib) * 128 + iL;
    const float m0 = ml[mb], m1 = ml[mb + 65536];
    const float l0 = ml[131072 + mb], l1 = ml[131072 + 65536 + mb];
    const float ms = fmaxf(m0, m1);
    const float w0 = exp2f((m0 - ms) * c);
    const float w1 = exp2f((m1 - ms) * c);
    const float ls = w0 * l0 + w1 * l1;

    const size_t ob = (((size_t)b * NH + n) * 8 + ib) * 8192
                      + (size_t)iL * 64 + d;
    const float o = w0 * Op[ob] + w1 * Op[ob + 4194304];
    av[((size_t)(b * QL + i)) * DM + n * 64 + d] = (__bf16)(o / ls);
}

// ---------------------------------------------------------------------------
// Workspace (MB offsets, ~123 MB total):
//  0 wbh(16) | 16 rbh(4) | 20 WqT(2) | 22 WkvT(4) | 26 WrT(2) | 28 WoT(2)
//  30 qwh(8) | 38 qrh(8) | 46 kh(16) | 62 vhT(16) | 78 rkh(4) | 82 avh(8)
//  90 Op(32) | 122 ml(1)
// ---------------------------------------------------------------------------
extern "C" void kernel_launch(void* const* d_in, const int* in_sizes, int n_in,
                              void* d_out, int out_size, void* d_ws, size_t ws_size,
                              hipStream_t stream)
{
    const float* w   = (const float*)d_in[0];
    const float* r   = (const float*)d_in[1];
    const float* bwb = (const float*)d_in[2];
    const float* brb = (const float*)d_in[3];
    const float* Wq  = (const float*)d_in[4];
    const float* Wkv = (const float*)d_in[5];
    const float* Wr  = (const float*)d_in[6];
    const float* Wo  = (const float*)d_in[7];
    float* out = (float*)d_out;

    char* ws = (char*)d_ws;
    __bf16* wbh  = (__bf16*)(ws);
    __bf16* rbh  = (__bf16*)(ws + ((size_t)16 << 20));
    __bf16* WqT  = (__bf16*)(ws + ((size_t)20 << 20));
    __bf16* WkvT = (__bf16*)(ws + ((size_t)22 << 20));
    __bf16* WrT  = (__bf16*)(ws + ((size_t)26 << 20));
    __bf16* WoT  = (__bf16*)(ws + ((size_t)28 << 20));
    __bf16* qwh  = (__bf16*)(ws + ((size_t)30 << 20));
    __bf16* qrh  = (__bf16*)(ws + ((size_t)38 << 20));
    __bf16* kh   = (__bf16*)(ws + ((size_t)46 << 20));
    __bf16* vhT  = (__bf16*)(ws + ((size_t)62 << 20));
    __bf16* rkh  = (__bf16*)(ws + ((size_t)78 << 20));
    __bf16* avh  = (__bf16*)(ws + ((size_t)82 << 20));
    float*  Op   = (float*)(ws + ((size_t)90 << 20));
    float*  mlb  = (float*)(ws + ((size_t)122 << 20));

    dim3 blk(256);
    prep<<<7168, blk, 0, stream>>>(w, r, Wq, Wr, Wo, Wkv,
                                   wbh, rbh, WqT, WrT, WoT, WkvT);
    gemm_proj<<<1408, blk, 0, stream>>>(wbh, rbh, WqT, WkvT, WrT,
                                        qwh, qrh, kh, vhT, rkh, bwb, brb);
    attn_mfma<<<dim3(16, 16, 4), blk, 54272, stream>>>(
        qwh, qrh, kh, vhT, rkh, Op, mlb);
    attn_combine<<<dim3(256, 16, 4), blk, 0, stream>>>(Op, mlb, avh);
    gemm_out<<<dim3(8, 8, 4), blk, 0, stream>>>(avh, WoT, out);
}

// Round 12
// 346.890 us; speedup vs baseline: 1.0581x; 1.0581x over previous
//
#include <hip/hip_runtime.h>

// Problem constants (Transformer-XL attention)
constexpr int BSZ  = 4;
constexpr int NH   = 16;
constexpr int DH   = 64;
constexpr int QL   = 1024;
constexpr int KLN  = 2048;
constexpr int DM   = 1024;   // d_model = NH*DH
constexpr int MEM  = 1024;   // KLEN - QLEN

typedef __bf16 bf16x8  __attribute__((ext_vector_type(8)));
typedef __bf16 bf16x4t __attribute__((ext_vector_type(4)));
typedef float  f32x4   __attribute__((ext_vector_type(4)));

// async global->LDS, 16B per lane; LDS dst is wave-uniform base + lane*16
__device__ __forceinline__ void g2l16(__bf16* lds, const __bf16* g) {
    __builtin_amdgcn_global_load_lds(
        (const __attribute__((address_space(1))) unsigned int*)g,
        (__attribute__((address_space(3))) unsigned int*)lds, 16, 0, 0);
}

// ---------------------------------------------------------------------------
// prep: one launch. Blocks [0,5120): cast w,r -> bf16. Blocks [5120,7168):
// transpose-cast the 4 weights (z = t>>9: 0 Wq, 1 Wr, 2 Wo, 3 Wkv).
// ---------------------------------------------------------------------------
__global__ __launch_bounds__(256)
void prep(const float* __restrict__ w, const float* __restrict__ r,
          const float* __restrict__ Wq, const float* __restrict__ Wr,
          const float* __restrict__ Wo, const float* __restrict__ Wkv,
          __bf16* __restrict__ wbh, __bf16* __restrict__ rbh,
          __bf16* __restrict__ WqT, __bf16* __restrict__ WrT,
          __bf16* __restrict__ WoT, __bf16* __restrict__ WkvT)
{
    __shared__ __bf16 t[64 * 72];
    const int id = blockIdx.x;
    if (id < 5120) {
        const float* in; __bf16* out; size_t i;
        if (id < 4096) { in = w; out = wbh; i = ((size_t)id * 256 + threadIdx.x) * 8; }
        else { in = r; out = rbh; i = ((size_t)(id - 4096) * 256 + threadIdx.x) * 8; }
        float4 a = *(const float4*)(in + i);
        float4 b = *(const float4*)(in + i + 4);
        bf16x8 y = {(__bf16)a.x, (__bf16)a.y, (__bf16)a.z, (__bf16)a.w,
                    (__bf16)b.x, (__bf16)b.y, (__bf16)b.z, (__bf16)b.w};
        *(bf16x8*)(out + i) = y;
        return;
    }
    const int tt = id - 5120;
    const int z = tt >> 9, rem = tt & 511;
    const int xx = rem & 31, yy = rem >> 5;
    const float* in; __bf16* out; int N;
    if (z == 0)      { in = Wq;  out = WqT;  N = 1024; }
    else if (z == 1) { in = Wr;  out = WrT;  N = 1024; }
    else if (z == 2) { in = Wo;  out = WoT;  N = 1024; }
    else             { in = Wkv; out = WkvT; N = 2048; }
    if (xx * 64 >= N) return;
    const int n0 = xx * 64, k0 = yy * 64;
    const int row = threadIdx.x >> 2, seg = (threadIdx.x & 3) << 4;
    const float* src = in + (long)(k0 + row) * N + n0 + seg;
#pragma unroll
    for (int u = 0; u < 16; u += 4) {
        float4 x = *(const float4*)(src + u);
        t[(seg + u + 0) * 72 + row] = (__bf16)x.x;
        t[(seg + u + 1) * 72 + row] = (__bf16)x.y;
        t[(seg + u + 2) * 72 + row] = (__bf16)x.z;
        t[(seg + u + 3) * 72 + row] = (__bf16)x.w;
    }
    __syncthreads();
    __bf16* dst = out + (long)(n0 + row) * 1024 + k0 + seg;
    *(uint4*)(dst)     = *(const uint4*)(t + row * 72 + seg);
    *(uint4*)(dst + 8) = *(const uint4*)(t + row * 72 + seg + 8);
}

// ---------------------------------------------------------------------------
// Shared GEMM core R15: 128x128 tile, BK=32, 4 waves, 2-phase double-buffer
// (kept: marginally positive, race-clean; incremental pipelining on this
// structure is otherwise confirmed null, matching m99/m100).
// ---------------------------------------------------------------------------
__device__ __forceinline__ void gemm_core(
    const __bf16* __restrict__ A, const __bf16* __restrict__ BT,
    __bf16* As, __bf16* Bs, int m0, int n0, int K, f32x4 (&acc)[4][4])
{
    const int tid = threadIdx.x, w = tid >> 6, l = tid & 63;
    const int il = l & 15, quad = l >> 4;
    const int wm = (w >> 1) * 64, wn = (w & 1) * 64;
    const int lr = l >> 2, kc = (l & 3) ^ (lr & 3);

    const __bf16* ag = A  + (long)(m0 + w * 32 + lr) * K + kc * 8;
    const __bf16* bg = BT + (long)(n0 + w * 32 + lr) * K + kc * 8;
    const int aoff0 = (w * 32) * 32;
    const int aoff1 = (w * 32 + 16) * 32;
    const int rsw = il & 3;
    const int rdoff = (quad ^ rsw) << 3;

    // prologue: stage tile k0=0 into buffer 0
    g2l16(As + aoff0, ag);
    g2l16(As + aoff1, ag + 16 * K);
    g2l16(Bs + aoff0, bg);
    g2l16(Bs + aoff1, bg + 16 * K);
    __syncthreads();                      // drains vmcnt; buf0 ready

    int cur = 0;
    for (int k0 = 0; k0 < K; k0 += 32) {
        const int nxt = cur ^ 1;
        if (k0 + 32 < K) {                // async prefetch next K-tile
            g2l16(As + nxt * 4096 + aoff0, ag + k0 + 32);
            g2l16(As + nxt * 4096 + aoff1, ag + k0 + 32 + 16 * K);
            g2l16(Bs + nxt * 4096 + aoff0, bg + k0 + 32);
            g2l16(Bs + nxt * 4096 + aoff1, bg + k0 + 32 + 16 * K);
        }

        bf16x8 af[4], bf[4];
#pragma unroll
        for (int f = 0; f < 4; ++f) {
            af[f] = *(const bf16x8*)(As + cur * 4096 + (wm + f * 16 + il) * 32 + rdoff);
            bf[f] = *(const bf16x8*)(Bs + cur * 4096 + (wn + f * 16 + il) * 32 + rdoff);
        }
#pragma unroll
        for (int i = 0; i < 4; ++i)
#pragma unroll
            for (int j = 0; j < 4; ++j)
                acc[i][j] = __builtin_amdgcn_mfma_f32_16x16x32_bf16(
                    af[i], bf[j], acc[i][j], 0, 0, 0);

        __syncthreads();                  // prefetch drained; cur reusable
        cur = nxt;
    }
}

// ---------------------------------------------------------------------------
// Merged projection GEMM: 1408 blocks, T1 XCD-BIJECTIVE SWIZZLE (1408=8*176).
// Each XCD gets 176 contiguous logical ids -> per-XCD working set drops from
// ~20MB (all A-panels + B) to ~6.8MB (11 A-panels + B), near the 4MB L2.
// ---------------------------------------------------------------------------
__global__ __launch_bounds__(256, 2)
void gemm_proj(const __bf16* __restrict__ wbh, const __bf16* __restrict__ rbh,
               const __bf16* __restrict__ WqT, const __bf16* __restrict__ WkvT,
               const __bf16* __restrict__ WrT,
               __bf16* __restrict__ qwh, __bf16* __restrict__ qrh,
               __bf16* __restrict__ kh, __bf16* __restrict__ vhT,
               __bf16* __restrict__ rkh,
               const float* __restrict__ bw, const float* __restrict__ br)
{
    __shared__ __bf16 As[2 * 128 * 32];
    __shared__ __bf16 Bs[2 * 128 * 32];
    const int id0 = blockIdx.x;
    const int id = (id0 & 7) * 176 + (id0 >> 3);   // XCD clustering, bijective
    const __bf16 *A, *BT;
    int m0, n0, zz, kind;
    if (id < 1024) {
        n0 = (id & 15) * 128; m0 = ((id >> 4) & 15) * 128; zz = id >> 8;
        A = wbh + (size_t)zz * KLN * DM; BT = WkvT; kind = 3;
    } else if (id < 1280) {
        const int t = id - 1024;
        n0 = (t & 7) * 128; m0 = ((t >> 3) & 7) * 128; zz = t >> 6;
        A = wbh + (size_t)zz * KLN * DM + (size_t)MEM * DM; BT = WqT; kind = 2;
    } else {
        const int t = id - 1280;
        n0 = (t & 7) * 128; m0 = (t >> 3) * 128; zz = 0;
        A = rbh; BT = WrT; kind = 4;
    }

    f32x4 acc[4][4] = {};
    gemm_core(A, BT, As, Bs, m0, n0, DM, acc);

    const int tid = threadIdx.x, w = tid >> 6, l = tid & 63;
    const int il = l & 15, quad = l >> 4;
    const int wm = (w >> 1) * 64, wn = (w & 1) * 64;

    if (kind == 2) {
#pragma unroll
        for (int j = 0; j < 4; ++j) {
            const int col = n0 + wn + j * 16 + il;
            const int hn = col >> 6, d = col & 63;
            const float bwv = bw[col], brv = br[col];
            __bf16* q1 = qwh + ((size_t)(zz * 16 + hn) * 1024) * 64 + d;
            __bf16* q2 = qrh + ((size_t)(zz * 16 + hn) * 1024) * 64 + d;
#pragma unroll
            for (int i = 0; i < 4; ++i) {
                const int mb = m0 + wm + i * 16 + quad * 4;
#pragma unroll
                for (int rr = 0; rr < 4; ++rr) {
                    float v = acc[i][j][rr];
                    q1[(size_t)(mb + rr) * 64] = (__bf16)(v + bwv);
                    q2[(size_t)(mb + rr) * 64] = (__bf16)(v + brv);
                }
            }
        }
    } else if (kind == 3) {
        if (n0 + wn < 1024) {
#pragma unroll
            for (int j = 0; j < 4; ++j) {
                const int col = n0 + wn + j * 16 + il;
                const int hn = col >> 6, d = col & 63;
                __bf16* kp = kh + ((size_t)(zz * 16 + hn) * 2048) * 64 + d;
#pragma unroll
                for (int i = 0; i < 4; ++i) {
                    const int mb = m0 + wm + i * 16 + quad * 4;
#pragma unroll
                    for (int rr = 0; rr < 4; ++rr)
                        kp[(size_t)(mb + rr) * 64] = (__bf16)acc[i][j][rr];
                }
            }
        } else {
#pragma unroll
            for (int j = 0; j < 4; ++j) {
                const int col = n0 + wn + j * 16 + il - 1024;
                const int hn = col >> 6, d = col & 63;
                __bf16* vp = vhT + ((size_t)((zz * 16 + hn) * 64 + d)) * 2048;
#pragma unroll
                for (int i = 0; i < 4; ++i) {
                    const int mb = m0 + wm + i * 16 + quad * 4;
                    bf16x4t pk = {(__bf16)acc[i][j][0], (__bf16)acc[i][j][1],
                                  (__bf16)acc[i][j][2], (__bf16)acc[i][j][3]};
                    *(bf16x4t*)(vp + mb) = pk;
                }
            }
        }
    } else { // kind 4
#pragma unroll
        for (int j = 0; j < 4; ++j) {
            const int col = n0 + wn + j * 16 + il;
            const int hn = col >> 6, d = col & 63;
            __bf16* rp = rkh + ((size_t)hn * 2048) * 64 + d;
#pragma unroll
            for (int i = 0; i < 4; ++i) {
                const int mb = m0 + wm + i * 16 + quad * 4;
#pragma unroll
                for (int rr = 0; rr < 4; ++rr)
                    rp[(size_t)(mb + rr) * 64] = (__bf16)acc[i][j][rr];
            }
        }
    }
}

// ---------------------------------------------------------------------------
// Output projection: out = avh @ WoT^T, f32 C.  1D grid 256, T1 swizzle
// (256=8*32): each XCD gets 32 contiguous lin -> 4 A-panels + WoT ~ 3MB <= L2.
// ---------------------------------------------------------------------------
__global__ __launch_bounds__(256, 2)
void gemm_out(const __bf16* __restrict__ avh, const __bf16* __restrict__ WoT,
              float* __restrict__ C)
{
    __shared__ __bf16 As[2 * 128 * 32];
    __shared__ __bf16 Bs[2 * 128 * 32];
    const int bid = blockIdx.x;
    const int lin = (bid & 7) * 32 + (bid >> 3);   // bijective, 256=8*32
    const int n0 = (lin & 7) * 128;
    const int m0 = ((lin >> 3) & 7) * 128;
    const int zz = lin >> 6;
    const __bf16* A = avh + (size_t)zz * QL * DM;

    f32x4 acc[4][4] = {};
    gemm_core(A, WoT, As, Bs, m0, n0, DM, acc);

    const int tid = threadIdx.x, w = tid >> 6, l = tid & 63;
    const int il = l & 15, quad = l >> 4;
    const int wm = (w >> 1) * 64, wn = (w & 1) * 64;
    float* Cb = C + (size_t)zz * QL * DM;
#pragma unroll
    for (int i = 0; i < 4; ++i)
#pragma unroll
        for (int j = 0; j < 4; ++j) {
            float* cp = Cb + (long)(m0 + wm + i * 16 + quad * 4) * DM
                           + n0 + wn + j * 16 + il;
#pragma unroll
            for (int rr = 0; rr < 4; ++rr) cp[(long)rr * DM] = acc[i][j][rr];
        }
}

// ---------------------------------------------------------------------------
// MFMA flash attention, R15 EXACT (verified 138.4-139.0us): R8 structure +
// f32 BD scratch.  R16's V-destage REVERTED (-25us: extra VMEM L2 ops cost
// more than the DS ops they replace; occupancy did NOT rise at 54.3KB ->
// LDS granularity coarse).  De-staging and occupancy levers now closed.
// LDS: kt 8K | vt 8K | rkt 24K | scf 21K = 62464 B -> 2 blocks/CU.
// ---------------------------------------------------------------------------
__global__ __launch_bounds__(256, 2)
void attn_mfma(const __bf16* __restrict__ qwh, const __bf16* __restrict__ qrh,
               const __bf16* __restrict__ kh, const __bf16* __restrict__ vhT,
               const __bf16* __restrict__ rkh, float* __restrict__ Op,
               float* __restrict__ ml)
{
    extern __shared__ __bf16 smem[];
    __bf16* kt  = smem;            // [64][64] xor-swizzled
    __bf16* vt  = smem + 4096;     // [64][64] xor
    __bf16* rkt = smem + 8192;     // [192][64] xor, circular
    float*  scf = (float*)(smem + 20480);  // 4 waves x [16][84] f32 scratch

    const int bx = blockIdx.x;
    const int part = bx & 1;
    const int bx2 = bx >> 1;                     // 0..7
    const int ib = (bx2 & 1) ? (7 - (bx2 >> 1)) : (bx2 >> 1);
    const int i0 = ib * 128;
    const int n = blockIdx.y, b = blockIdx.z;
    const int tid = threadIdx.x;
    const int w = tid >> 6, l = tid & 63;
    const int il = l & 15, quad = l >> 4;
    const int iw0 = i0 + w * 32;

    // persistent Q fragments, 2 i-frags per wave
    bf16x8 qwf[2][2], qrf[2][2];
#pragma unroll
    for (int g = 0; g < 2; ++g) {
        const size_t qoff =
            ((size_t)((b * 16 + n) * QL + iw0 + 16 * g + il)) * 64 + quad * 8;
        qwf[g][0] = *(const bf16x8*)(qwh + qoff);
        qwf[g][1] = *(const bf16x8*)(qwh + qoff + 32);
        qrf[g][0] = *(const bf16x8*)(qrh + qoff);
        qrf[g][1] = *(const bf16x8*)(qrh + qoff + 32);
    }

    f32x4 O[2][4] = {};
    float m_i[2] = {-1e30f, -1e30f}, l_i[2] = {0.f, 0.f};
    const float c = 0.125f * 1.44269504f;        // scale * log2(e)

    const int srow = l >> 3, scl = l & 7;        // staging: 8 rows x 8 chunks
    const __bf16* kbase  = kh  + ((size_t)((b * 16 + n) * KLN)) * 64;
    const __bf16* vbase0 = vhT + ((size_t)((b * 16 + n) * 64)) * KLN;
    const __bf16* rbp    = rkh + ((size_t)(n * KLN)) * 64;

    const int xk0 = ((quad) ^ (il & 7)) << 3;
    const int xk1 = ((quad + 4) ^ (il & 7)) << 3;

    const int nt = 2 * ib + 18;
    const int t0 = (part * nt) / 2;
    const int t1 = ((part + 1) * nt) / 2;
    int rot = (t0 % 3) * 64;                     // circular offset for tile t0

    const int ubB = 96 - 32 * w;                 // logical base of shared BD frags

    for (int jt = t0; jt < t1; ++jt) {
        const int j0 = jt * 64;
        const int vu0 = j0 - i0 + 896;           // rk row of logical rkt row 0
        __syncthreads();
#pragma unroll
        for (int it = 0; it < 2; ++it) {         // K tile rows j
            const int row = w * 16 + it * 8 + srow;
            g2l16(kt + (w * 16 + it * 8) * 64,
                  kbase + ((size_t)(j0 + row)) * 64 + ((scl ^ srow) << 3));
        }
#pragma unroll
        for (int it = 0; it < 2; ++it) {         // V^T tile rows d
            const int row = w * 16 + it * 8 + srow;
            g2l16(vt + (w * 16 + it * 8) * 64,
                  vbase0 + (size_t)row * KLN + j0 + ((scl ^ srow) << 3));
        }
        if (jt == t0) {                          // full 192-row window fill
#pragma unroll
            for (int it = 0; it < 6; ++it) {
                const int lbase = w * 48 + it * 8;
                int pb = lbase + rot; if (pb >= 192) pb -= 192;
                int vu = vu0 + lbase + srow;
                vu = vu < 0 ? 0 : (vu > KLN - 1 ? KLN - 1 : vu);
                g2l16(rkt + pb * 64,
                      rbp + (size_t)vu * 64 + ((scl ^ srow) << 3));
            }
        } else {                                 // slide: logical rows 128..191
#pragma unroll
            for (int it = 0; it < 2; ++it) {
                const int lbase = 128 + w * 16 + it * 8;
                int pb = lbase + rot; if (pb >= 192) pb -= 192;
                int vu = vu0 + lbase + srow;
                vu = vu < 0 ? 0 : (vu > KLN - 1 ? KLN - 1 : vu);
                g2l16(rkt + pb * 64,
                      rbp + (size_t)vu * 64 + ((scl ^ srow) << 3));
            }
        }
        __syncthreads();

        const bool edge = (j0 + 63 > i0 + MEM);

        // ---- Phase 1: AC for both g (kt frags read ONCE)
        f32x4 sf[2][4];
#pragma unroll
        for (int fr = 0; fr < 4; ++fr) {
            const __bf16* ka = kt + (fr * 16 + il) * 64;
            bf16x8 a0 = *(const bf16x8*)(ka + xk0);
            bf16x8 a1 = *(const bf16x8*)(ka + xk1);
            __builtin_amdgcn_s_setprio(1);
#pragma unroll
            for (int g = 0; g < 2; ++g) {
                f32x4 acc = {};
                acc = __builtin_amdgcn_mfma_f32_16x16x32_bf16(a0, qwf[g][0], acc, 0, 0, 0);
                acc = __builtin_amdgcn_mfma_f32_16x16x32_bf16(a1, qwf[g][1], acc, 0, 0, 0);
                sf[g][fr] = acc;
            }
            __builtin_amdgcn_s_setprio(0);
        }

        // ---- shared fragment loads, once per tile (used by both g)
        bf16x8 ra[6][2];
#pragma unroll
        for (int uf2 = 0; uf2 < 6; ++uf2) {
            int pr = ubB + uf2 * 16 + il + rot; if (pr >= 192) pr -= 192;
            const __bf16* rp_ = rkt + pr * 64;
            ra[uf2][0] = *(const bf16x8*)(rp_ + xk0);
            ra[uf2][1] = *(const bf16x8*)(rp_ + xk1);
        }
        bf16x8 va[4][2];
#pragma unroll
        for (int df = 0; df < 4; ++df) {
            const __bf16* vp_ = vt + (df * 16 + il) * 64;
            va[df][0] = *(const bf16x8*)(vp_ + xk0);
            va[df][1] = *(const bf16x8*)(vp_ + xk1);
        }

        // ---- per-g: BD(f32 scratch) -> gather/softmax -> P(scratch) -> PV
        float* scw = scf + w * 1344;             // per-wave [16][84] f32
#pragma unroll
        for (int g = 0; g < 2; ++g) {
            // BD: 5 frags, idx = uf+1-g (g0: ra[1..5], g1: ra[0..4])
#pragma unroll
            for (int uf = 0; uf < 5; ++uf) {
                const int idx = uf + 1 - g;
                f32x4 acc = {};
                __builtin_amdgcn_s_setprio(1);
                acc = __builtin_amdgcn_mfma_f32_16x16x32_bf16(ra[idx][0], qrf[g][0], acc, 0, 0, 0);
                acc = __builtin_amdgcn_mfma_f32_16x16x32_bf16(ra[idx][1], qrf[g][1], acc, 0, 0, 0);
                __builtin_amdgcn_s_setprio(0);
                *(f32x4*)(scw + il * 84 + uf * 16 + quad * 4) = acc;
            }

            const int i_gl = iw0 + 16 * g + il;
            float sv[4][4];
            float tmax = -1e30f;
#pragma unroll
            for (int fr = 0; fr < 4; ++fr) {
                const int base = il * 83 + fr * 16 + quad * 4 + 15;  // = il*84 + (jl_-il+15)
#pragma unroll
                for (int rr = 0; rr < 4; ++rr) {
                    const int jl_ = fr * 16 + quad * 4 + rr;
                    float s = sf[g][fr][rr] + scw[base + rr];
                    if (edge) s = (j0 + jl_ > i_gl + MEM) ? -1e30f : s;
                    sv[fr][rr] = s;
                    tmax = fmaxf(tmax, s);
                }
            }
            tmax = fmaxf(tmax, __shfl_xor(tmax, 16));
            tmax = fmaxf(tmax, __shfl_xor(tmax, 32));
            const float m_new = fmaxf(m_i[g], tmax);
            const float alpha = exp2f((m_i[g] - m_new) * c);
            float psum = 0.f;
            __bf16* prow = (__bf16*)(scw + il * 84);   // P overwrites row head
#pragma unroll
            for (int fr = 0; fr < 4; ++fr) {
                bf16x4t p4;
#pragma unroll
                for (int rr = 0; rr < 4; ++rr) {
                    float p = exp2f((sv[fr][rr] - m_new) * c);
                    psum += p;
                    p4[rr] = (__bf16)p;
                }
                // after all gathers for this g (same wave): safe overwrite
                *(bf16x4t*)(prow + fr * 16 + quad * 4) = p4;
            }
            psum += __shfl_xor(psum, 16);
            psum += __shfl_xor(psum, 32);
            l_i[g] = l_i[g] * alpha + psum;
            m_i[g] = m_new;
#pragma unroll
            for (int df = 0; df < 4; ++df) O[g][df] *= alpha;

            bf16x8 p0 = *(const bf16x8*)(prow + quad * 8);
            bf16x8 p1 = *(const bf16x8*)(prow + 32 + quad * 8);
            __builtin_amdgcn_s_setprio(1);
#pragma unroll
            for (int df = 0; df < 4; ++df) {
                O[g][df] = __builtin_amdgcn_mfma_f32_16x16x32_bf16(va[df][0], p0, O[g][df], 0, 0, 0);
                O[g][df] = __builtin_amdgcn_mfma_f32_16x16x32_bf16(va[df][1], p1, O[g][df], 0, 0, 0);
            }
            __builtin_amdgcn_s_setprio(0);
        }
        rot += 64; if (rot >= 192) rot -= 192;
    }

    // ---- write partials (unnormalized)
#pragma unroll
    for (int g = 0; g < 2; ++g) {
        const int iL = w * 32 + 16 * g + il;
        float* opb = Op + (size_t)part * 4194304
                        + ((((size_t)b * NH + n) * 8 + ib)) * 8192
                        + (size_t)iL * 64 + quad * 4;
#pragma unroll
        for (int df = 0; df < 4; ++df)
            *(f32x4*)(opb + df * 16) = O[g][df];
        if (quad == 0) {
            const size_t base = (((size_t)b * NH + n) * 8 + ib) * 128 + iL;
            ml[(size_t)part * 65536 + base]          = m_i[g];
            ml[131072 + (size_t)part * 65536 + base] = l_i[g];
        }
    }
}

// ---------------------------------------------------------------------------
// Combine 2 attention partials -> avh bf16.  Grid (QL/4, NH, BSZ).
// ---------------------------------------------------------------------------
__global__ __launch_bounds__(256)
void attn_combine(const float* __restrict__ Op, const float* __restrict__ ml,
                  __bf16* __restrict__ av)
{
    const int tid = threadIdx.x;
    const int i = blockIdx.x * 4 + (tid >> 6);
    const int d = tid & 63;
    const int n = blockIdx.y, b = blockIdx.z;
    const int ib = i >> 7, iL = i & 127;
    const float c = 0.125f * 1.44269504f;

    const size_t mb = (((size_t)b * NH + n) * 8 + ib) * 128 + iL;
    const float m0 = ml[mb], m1 = ml[mb + 65536];
    const float l0 = ml[131072 + mb], l1 = ml[131072 + 65536 + mb];
    const float ms = fmaxf(m0, m1);
    const float w0 = exp2f((m0 - ms) * c);
    const float w1 = exp2f((m1 - ms) * c);
    const float ls = w0 * l0 + w1 * l1;

    const size_t ob = (((size_t)b * NH + n) * 8 + ib) * 8192
                      + (size_t)iL * 64 + d;
    const float o = w0 * Op[ob] + w1 * Op[ob + 4194304];
    av[((size_t)(b * QL + i)) * DM + n * 64 + d] = (__bf16)(o / ls);
}

// ---------------------------------------------------------------------------
// Workspace (MB offsets, ~123 MB total):
//  0 wbh(16) | 16 rbh(4) | 20 WqT(2) | 22 WkvT(4) | 26 WrT(2) | 28 WoT(2)
//  30 qwh(8) | 38 qrh(8) | 46 kh(16) | 62 vhT(16) | 78 rkh(4) | 82 avh(8)
//  90 Op(32) | 122 ml(1)
// ---------------------------------------------------------------------------
extern "C" void kernel_launch(void* const* d_in, const int* in_sizes, int n_in,
                              void* d_out, int out_size, void* d_ws, size_t ws_size,
                              hipStream_t stream)
{
    const float* w   = (const float*)d_in[0];
    const float* r   = (const float*)d_in[1];
    const float* bwb = (const float*)d_in[2];
    const float* brb = (const float*)d_in[3];
    const float* Wq  = (const float*)d_in[4];
    const float* Wkv = (const float*)d_in[5];
    const float* Wr  = (const float*)d_in[6];
    const float* Wo  = (const float*)d_in[7];
    float* out = (float*)d_out;

    char* ws = (char*)d_ws;
    __bf16* wbh  = (__bf16*)(ws);
    __bf16* rbh  = (__bf16*)(ws + ((size_t)16 << 20));
    __bf16* WqT  = (__bf16*)(ws + ((size_t)20 << 20));
    __bf16* WkvT = (__bf16*)(ws + ((size_t)22 << 20));
    __bf16* WrT  = (__bf16*)(ws + ((size_t)26 << 20));
    __bf16* WoT  = (__bf16*)(ws + ((size_t)28 << 20));
    __bf16* qwh  = (__bf16*)(ws + ((size_t)30 << 20));
    __bf16* qrh  = (__bf16*)(ws + ((size_t)38 << 20));
    __bf16* kh   = (__bf16*)(ws + ((size_t)46 << 20));
    __bf16* vhT  = (__bf16*)(ws + ((size_t)62 << 20));
    __bf16* rkh  = (__bf16*)(ws + ((size_t)78 << 20));
    __bf16* avh  = (__bf16*)(ws + ((size_t)82 << 20));
    float*  Op   = (float*)(ws + ((size_t)90 << 20));
    float*  mlb  = (float*)(ws + ((size_t)122 << 20));

    dim3 blk(256);
    prep<<<7168, blk, 0, stream>>>(w, r, Wq, Wr, Wo, Wkv,
                                   wbh, rbh, WqT, WrT, WoT, WkvT);
    gemm_proj<<<1408, blk, 0, stream>>>(wbh, rbh, WqT, WkvT, WrT,
                                        qwh, qrh, kh, vhT, rkh, bwb, brb);
    attn_mfma<<<dim3(16, 16, 4), blk, 62464, stream>>>(
        qwh, qrh, kh, vhT, rkh, Op, mlb);
    attn_combine<<<dim3(256, 16, 4), blk, 0, stream>>>(Op, mlb, avh);
    gemm_out<<<256, blk, 0, stream>>>(avh, WoT, out);
}

// Round 13
// 338.337 us; speedup vs baseline: 1.0849x; 1.0253x over previous
//
#include <hip/hip_runtime.h>

// Problem constants (Transformer-XL attention)
constexpr int BSZ  = 4;
constexpr int NH   = 16;
constexpr int DH   = 64;
constexpr int QL   = 1024;
constexpr int KLN  = 2048;
constexpr int DM   = 1024;   // d_model = NH*DH
constexpr int MEM  = 1024;   // KLEN - QLEN

typedef __bf16 bf16x8  __attribute__((ext_vector_type(8)));
typedef __bf16 bf16x4t __attribute__((ext_vector_type(4)));
typedef float  f32x4   __attribute__((ext_vector_type(4)));

// async global->LDS, 16B per lane; LDS dst is wave-uniform base + lane*16
__device__ __forceinline__ void g2l16(__bf16* lds, const __bf16* g) {
    __builtin_amdgcn_global_load_lds(
        (const __attribute__((address_space(1))) unsigned int*)g,
        (__attribute__((address_space(3))) unsigned int*)lds, 16, 0, 0);
}

// ---------------------------------------------------------------------------
// prep: one launch. Blocks [0,5120): cast w,r -> bf16. Blocks [5120,7168):
// transpose-cast the 4 weights (z = t>>9: 0 Wq, 1 Wr, 2 Wo, 3 Wkv).
// ---------------------------------------------------------------------------
__global__ __launch_bounds__(256)
void prep(const float* __restrict__ w, const float* __restrict__ r,
          const float* __restrict__ Wq, const float* __restrict__ Wr,
          const float* __restrict__ Wo, const float* __restrict__ Wkv,
          __bf16* __restrict__ wbh, __bf16* __restrict__ rbh,
          __bf16* __restrict__ WqT, __bf16* __restrict__ WrT,
          __bf16* __restrict__ WoT, __bf16* __restrict__ WkvT)
{
    __shared__ __bf16 t[64 * 72];
    const int id = blockIdx.x;
    if (id < 5120) {
        const float* in; __bf16* out; size_t i;
        if (id < 4096) { in = w; out = wbh; i = ((size_t)id * 256 + threadIdx.x) * 8; }
        else { in = r; out = rbh; i = ((size_t)(id - 4096) * 256 + threadIdx.x) * 8; }
        float4 a = *(const float4*)(in + i);
        float4 b = *(const float4*)(in + i + 4);
        bf16x8 y = {(__bf16)a.x, (__bf16)a.y, (__bf16)a.z, (__bf16)a.w,
                    (__bf16)b.x, (__bf16)b.y, (__bf16)b.z, (__bf16)b.w};
        *(bf16x8*)(out + i) = y;
        return;
    }
    const int tt = id - 5120;
    const int z = tt >> 9, rem = tt & 511;
    const int xx = rem & 31, yy = rem >> 5;
    const float* in; __bf16* out; int N;
    if (z == 0)      { in = Wq;  out = WqT;  N = 1024; }
    else if (z == 1) { in = Wr;  out = WrT;  N = 1024; }
    else if (z == 2) { in = Wo;  out = WoT;  N = 1024; }
    else             { in = Wkv; out = WkvT; N = 2048; }
    if (xx * 64 >= N) return;
    const int n0 = xx * 64, k0 = yy * 64;
    const int row = threadIdx.x >> 2, seg = (threadIdx.x & 3) << 4;
    const float* src = in + (long)(k0 + row) * N + n0 + seg;
#pragma unroll
    for (int u = 0; u < 16; u += 4) {
        float4 x = *(const float4*)(src + u);
        t[(seg + u + 0) * 72 + row] = (__bf16)x.x;
        t[(seg + u + 1) * 72 + row] = (__bf16)x.y;
        t[(seg + u + 2) * 72 + row] = (__bf16)x.z;
        t[(seg + u + 3) * 72 + row] = (__bf16)x.w;
    }
    __syncthreads();
    __bf16* dst = out + (long)(n0 + row) * 1024 + k0 + seg;
    *(uint4*)(dst)     = *(const uint4*)(t + row * 72 + seg);
    *(uint4*)(dst + 8) = *(const uint4*)(t + row * 72 + seg + 8);
}

// ---------------------------------------------------------------------------
// Shared GEMM core R15: 128x128 tile, BK=32, 4 waves, 2-phase double-buffer
// (kept: marginally positive, race-clean; incremental pipelining on this
// structure is otherwise confirmed null, matching m99/m100).
// ---------------------------------------------------------------------------
__device__ __forceinline__ void gemm_core(
    const __bf16* __restrict__ A, const __bf16* __restrict__ BT,
    __bf16* As, __bf16* Bs, int m0, int n0, int K, f32x4 (&acc)[4][4])
{
    const int tid = threadIdx.x, w = tid >> 6, l = tid & 63;
    const int il = l & 15, quad = l >> 4;
    const int wm = (w >> 1) * 64, wn = (w & 1) * 64;
    const int lr = l >> 2, kc = (l & 3) ^ (lr & 3);

    const __bf16* ag = A  + (long)(m0 + w * 32 + lr) * K + kc * 8;
    const __bf16* bg = BT + (long)(n0 + w * 32 + lr) * K + kc * 8;
    const int aoff0 = (w * 32) * 32;
    const int aoff1 = (w * 32 + 16) * 32;
    const int rsw = il & 3;
    const int rdoff = (quad ^ rsw) << 3;

    // prologue: stage tile k0=0 into buffer 0
    g2l16(As + aoff0, ag);
    g2l16(As + aoff1, ag + 16 * K);
    g2l16(Bs + aoff0, bg);
    g2l16(Bs + aoff1, bg + 16 * K);
    __syncthreads();                      // drains vmcnt; buf0 ready

    int cur = 0;
    for (int k0 = 0; k0 < K; k0 += 32) {
        const int nxt = cur ^ 1;
        if (k0 + 32 < K) {                // async prefetch next K-tile
            g2l16(As + nxt * 4096 + aoff0, ag + k0 + 32);
            g2l16(As + nxt * 4096 + aoff1, ag + k0 + 32 + 16 * K);
            g2l16(Bs + nxt * 4096 + aoff0, bg + k0 + 32);
            g2l16(Bs + nxt * 4096 + aoff1, bg + k0 + 32 + 16 * K);
        }

        bf16x8 af[4], bf[4];
#pragma unroll
        for (int f = 0; f < 4; ++f) {
            af[f] = *(const bf16x8*)(As + cur * 4096 + (wm + f * 16 + il) * 32 + rdoff);
            bf[f] = *(const bf16x8*)(Bs + cur * 4096 + (wn + f * 16 + il) * 32 + rdoff);
        }
#pragma unroll
        for (int i = 0; i < 4; ++i)
#pragma unroll
            for (int j = 0; j < 4; ++j)
                acc[i][j] = __builtin_amdgcn_mfma_f32_16x16x32_bf16(
                    af[i], bf[j], acc[i][j], 0, 0, 0);

        __syncthreads();                  // prefetch drained; cur reusable
        cur = nxt;
    }
}

// ---------------------------------------------------------------------------
// Merged projection GEMM: 1408 blocks.  (T1 swizzle reverted: R17 measured
// null, +2.9us noise -> L3 absorbs panel re-reads at these working sets.)
// ---------------------------------------------------------------------------
__global__ __launch_bounds__(256, 2)
void gemm_proj(const __bf16* __restrict__ wbh, const __bf16* __restrict__ rbh,
               const __bf16* __restrict__ WqT, const __bf16* __restrict__ WkvT,
               const __bf16* __restrict__ WrT,
               __bf16* __restrict__ qwh, __bf16* __restrict__ qrh,
               __bf16* __restrict__ kh, __bf16* __restrict__ vhT,
               __bf16* __restrict__ rkh,
               const float* __restrict__ bw, const float* __restrict__ br)
{
    __shared__ __bf16 As[2 * 128 * 32];
    __shared__ __bf16 Bs[2 * 128 * 32];
    const int id = blockIdx.x;
    const __bf16 *A, *BT;
    int m0, n0, zz, kind;
    if (id < 1024) {
        n0 = (id & 15) * 128; m0 = ((id >> 4) & 15) * 128; zz = id >> 8;
        A = wbh + (size_t)zz * KLN * DM; BT = WkvT; kind = 3;
    } else if (id < 1280) {
        const int t = id - 1024;
        n0 = (t & 7) * 128; m0 = ((t >> 3) & 7) * 128; zz = t >> 6;
        A = wbh + (size_t)zz * KLN * DM + (size_t)MEM * DM; BT = WqT; kind = 2;
    } else {
        const int t = id - 1280;
        n0 = (t & 7) * 128; m0 = (t >> 3) * 128; zz = 0;
        A = rbh; BT = WrT; kind = 4;
    }

    f32x4 acc[4][4] = {};
    gemm_core(A, BT, As, Bs, m0, n0, DM, acc);

    const int tid = threadIdx.x, w = tid >> 6, l = tid & 63;
    const int il = l & 15, quad = l >> 4;
    const int wm = (w >> 1) * 64, wn = (w & 1) * 64;

    if (kind == 2) {
#pragma unroll
        for (int j = 0; j < 4; ++j) {
            const int col = n0 + wn + j * 16 + il;
            const int hn = col >> 6, d = col & 63;
            const float bwv = bw[col], brv = br[col];
            __bf16* q1 = qwh + ((size_t)(zz * 16 + hn) * 1024) * 64 + d;
            __bf16* q2 = qrh + ((size_t)(zz * 16 + hn) * 1024) * 64 + d;
#pragma unroll
            for (int i = 0; i < 4; ++i) {
                const int mb = m0 + wm + i * 16 + quad * 4;
#pragma unroll
                for (int rr = 0; rr < 4; ++rr) {
                    float v = acc[i][j][rr];
                    q1[(size_t)(mb + rr) * 64] = (__bf16)(v + bwv);
                    q2[(size_t)(mb + rr) * 64] = (__bf16)(v + brv);
                }
            }
        }
    } else if (kind == 3) {
        if (n0 + wn < 1024) {
#pragma unroll
            for (int j = 0; j < 4; ++j) {
                const int col = n0 + wn + j * 16 + il;
                const int hn = col >> 6, d = col & 63;
                __bf16* kp = kh + ((size_t)(zz * 16 + hn) * 2048) * 64 + d;
#pragma unroll
                for (int i = 0; i < 4; ++i) {
                    const int mb = m0 + wm + i * 16 + quad * 4;
#pragma unroll
                    for (int rr = 0; rr < 4; ++rr)
                        kp[(size_t)(mb + rr) * 64] = (__bf16)acc[i][j][rr];
                }
            }
        } else {
#pragma unroll
            for (int j = 0; j < 4; ++j) {
                const int col = n0 + wn + j * 16 + il - 1024;
                const int hn = col >> 6, d = col & 63;
                __bf16* vp = vhT + ((size_t)((zz * 16 + hn) * 64 + d)) * 2048;
#pragma unroll
                for (int i = 0; i < 4; ++i) {
                    const int mb = m0 + wm + i * 16 + quad * 4;
                    bf16x4t pk = {(__bf16)acc[i][j][0], (__bf16)acc[i][j][1],
                                  (__bf16)acc[i][j][2], (__bf16)acc[i][j][3]};
                    *(bf16x4t*)(vp + mb) = pk;
                }
            }
        }
    } else { // kind 4
#pragma unroll
        for (int j = 0; j < 4; ++j) {
            const int col = n0 + wn + j * 16 + il;
            const int hn = col >> 6, d = col & 63;
            __bf16* rp = rkh + ((size_t)hn * 2048) * 64 + d;
#pragma unroll
            for (int i = 0; i < 4; ++i) {
                const int mb = m0 + wm + i * 16 + quad * 4;
#pragma unroll
                for (int rr = 0; rr < 4; ++rr)
                    rp[(size_t)(mb + rr) * 64] = (__bf16)acc[i][j][rr];
            }
        }
    }
}

// ---------------------------------------------------------------------------
// Output projection: out = avh @ WoT^T, f32 C.  Grid (8,8,4).
// ---------------------------------------------------------------------------
__global__ __launch_bounds__(256, 2)
void gemm_out(const __bf16* __restrict__ avh, const __bf16* __restrict__ WoT,
              float* __restrict__ C)
{
    __shared__ __bf16 As[2 * 128 * 32];
    __shared__ __bf16 Bs[2 * 128 * 32];
    const int zz = blockIdx.z;
    const __bf16* A = avh + (size_t)zz * QL * DM;
    const int m0 = blockIdx.y * 128, n0 = blockIdx.x * 128;

    f32x4 acc[4][4] = {};
    gemm_core(A, WoT, As, Bs, m0, n0, DM, acc);

    const int tid = threadIdx.x, w = tid >> 6, l = tid & 63;
    const int il = l & 15, quad = l >> 4;
    const int wm = (w >> 1) * 64, wn = (w & 1) * 64;
    float* Cb = C + (size_t)zz * QL * DM;
#pragma unroll
    for (int i = 0; i < 4; ++i)
#pragma unroll
        for (int j = 0; j < 4; ++j) {
            float* cp = Cb + (long)(m0 + wm + i * 16 + quad * 4) * DM
                           + n0 + wn + j * 16 + il;
#pragma unroll
            for (int rr = 0; rr < 4; ++rr) cp[(long)rr * DM] = acc[i][j][rr];
        }
}

// ---------------------------------------------------------------------------
// MFMA flash attention, R18: R15 verified core (138.4-139.0us) + T13
// DEFER-MAX (catalog m239, THR=8 score units).  When a tile's per-lane max
// hasn't grown past m_i+8 (checked wave-uniformly via __all, no DS), skip
// the 2 cross-quad max shuffles (~240 serial cyc), the alpha exp2, and the
// 8 O-multiplies.  P then bounded by e^1=2.72 (bf16-safe).  First tile
// always takes the slow path (m_i=-1e30).  psum reduction kept exact.
// LDS: kt 8K | vt 8K | rkt 24K | scf 21K = 62464 B -> 2 blocks/CU.
// ---------------------------------------------------------------------------
__global__ __launch_bounds__(256, 2)
void attn_mfma(const __bf16* __restrict__ qwh, const __bf16* __restrict__ qrh,
               const __bf16* __restrict__ kh, const __bf16* __restrict__ vhT,
               const __bf16* __restrict__ rkh, float* __restrict__ Op,
               float* __restrict__ ml)
{
    extern __shared__ __bf16 smem[];
    __bf16* kt  = smem;            // [64][64] xor-swizzled
    __bf16* vt  = smem + 4096;     // [64][64] xor
    __bf16* rkt = smem + 8192;     // [192][64] xor, circular
    float*  scf = (float*)(smem + 20480);  // 4 waves x [16][84] f32 scratch

    const int bx = blockIdx.x;
    const int part = bx & 1;
    const int bx2 = bx >> 1;                     // 0..7
    const int ib = (bx2 & 1) ? (7 - (bx2 >> 1)) : (bx2 >> 1);
    const int i0 = ib * 128;
    const int n = blockIdx.y, b = blockIdx.z;
    const int tid = threadIdx.x;
    const int w = tid >> 6, l = tid & 63;
    const int il = l & 15, quad = l >> 4;
    const int iw0 = i0 + w * 32;

    // persistent Q fragments, 2 i-frags per wave
    bf16x8 qwf[2][2], qrf[2][2];
#pragma unroll
    for (int g = 0; g < 2; ++g) {
        const size_t qoff =
            ((size_t)((b * 16 + n) * QL + iw0 + 16 * g + il)) * 64 + quad * 8;
        qwf[g][0] = *(const bf16x8*)(qwh + qoff);
        qwf[g][1] = *(const bf16x8*)(qwh + qoff + 32);
        qrf[g][0] = *(const bf16x8*)(qrh + qoff);
        qrf[g][1] = *(const bf16x8*)(qrh + qoff + 32);
    }

    f32x4 O[2][4] = {};
    float m_i[2] = {-1e30f, -1e30f}, l_i[2] = {0.f, 0.f};
    const float c = 0.125f * 1.44269504f;        // scale * log2(e)

    const int srow = l >> 3, scl = l & 7;        // staging: 8 rows x 8 chunks
    const __bf16* kbase  = kh  + ((size_t)((b * 16 + n) * KLN)) * 64;
    const __bf16* vbase0 = vhT + ((size_t)((b * 16 + n) * 64)) * KLN;
    const __bf16* rbp    = rkh + ((size_t)(n * KLN)) * 64;

    const int xk0 = ((quad) ^ (il & 7)) << 3;
    const int xk1 = ((quad + 4) ^ (il & 7)) << 3;

    const int nt = 2 * ib + 18;
    const int t0 = (part * nt) / 2;
    const int t1 = ((part + 1) * nt) / 2;
    int rot = (t0 % 3) * 64;                     // circular offset for tile t0

    const int ubB = 96 - 32 * w;                 // logical base of shared BD frags

    for (int jt = t0; jt < t1; ++jt) {
        const int j0 = jt * 64;
        const int vu0 = j0 - i0 + 896;           // rk row of logical rkt row 0
        __syncthreads();
#pragma unroll
        for (int it = 0; it < 2; ++it) {         // K tile rows j
            const int row = w * 16 + it * 8 + srow;
            g2l16(kt + (w * 16 + it * 8) * 64,
                  kbase + ((size_t)(j0 + row)) * 64 + ((scl ^ srow) << 3));
        }
#pragma unroll
        for (int it = 0; it < 2; ++it) {         // V^T tile rows d
            const int row = w * 16 + it * 8 + srow;
            g2l16(vt + (w * 16 + it * 8) * 64,
                  vbase0 + (size_t)row * KLN + j0 + ((scl ^ srow) << 3));
        }
        if (jt == t0) {                          // full 192-row window fill
#pragma unroll
            for (int it = 0; it < 6; ++it) {
                const int lbase = w * 48 + it * 8;
                int pb = lbase + rot; if (pb >= 192) pb -= 192;
                int vu = vu0 + lbase + srow;
                vu = vu < 0 ? 0 : (vu > KLN - 1 ? KLN - 1 : vu);
                g2l16(rkt + pb * 64,
                      rbp + (size_t)vu * 64 + ((scl ^ srow) << 3));
            }
        } else {                                 // slide: logical rows 128..191
#pragma unroll
            for (int it = 0; it < 2; ++it) {
                const int lbase = 128 + w * 16 + it * 8;
                int pb = lbase + rot; if (pb >= 192) pb -= 192;
                int vu = vu0 + lbase + srow;
                vu = vu < 0 ? 0 : (vu > KLN - 1 ? KLN - 1 : vu);
                g2l16(rkt + pb * 64,
                      rbp + (size_t)vu * 64 + ((scl ^ srow) << 3));
            }
        }
        __syncthreads();

        const bool edge = (j0 + 63 > i0 + MEM);

        // ---- Phase 1: AC for both g (kt frags read ONCE)
        f32x4 sf[2][4];
#pragma unroll
        for (int fr = 0; fr < 4; ++fr) {
            const __bf16* ka = kt + (fr * 16 + il) * 64;
            bf16x8 a0 = *(const bf16x8*)(ka + xk0);
            bf16x8 a1 = *(const bf16x8*)(ka + xk1);
            __builtin_amdgcn_s_setprio(1);
#pragma unroll
            for (int g = 0; g < 2; ++g) {
                f32x4 acc = {};
                acc = __builtin_amdgcn_mfma_f32_16x16x32_bf16(a0, qwf[g][0], acc, 0, 0, 0);
                acc = __builtin_amdgcn_mfma_f32_16x16x32_bf16(a1, qwf[g][1], acc, 0, 0, 0);
                sf[g][fr] = acc;
            }
            __builtin_amdgcn_s_setprio(0);
        }

        // ---- shared fragment loads, once per tile (used by both g)
        bf16x8 ra[6][2];
#pragma unroll
        for (int uf2 = 0; uf2 < 6; ++uf2) {
            int pr = ubB + uf2 * 16 + il + rot; if (pr >= 192) pr -= 192;
            const __bf16* rp_ = rkt + pr * 64;
            ra[uf2][0] = *(const bf16x8*)(rp_ + xk0);
            ra[uf2][1] = *(const bf16x8*)(rp_ + xk1);
        }
        bf16x8 va[4][2];
#pragma unroll
        for (int df = 0; df < 4; ++df) {
            const __bf16* vp_ = vt + (df * 16 + il) * 64;
            va[df][0] = *(const bf16x8*)(vp_ + xk0);
            va[df][1] = *(const bf16x8*)(vp_ + xk1);
        }

        // ---- per-g: BD(f32 scratch) -> gather/softmax -> P(scratch) -> PV
        float* scw = scf + w * 1344;             // per-wave [16][84] f32
#pragma unroll
        for (int g = 0; g < 2; ++g) {
            // BD: 5 frags, idx = uf+1-g (g0: ra[1..5], g1: ra[0..4])
#pragma unroll
            for (int uf = 0; uf < 5; ++uf) {
                const int idx = uf + 1 - g;
                f32x4 acc = {};
                __builtin_amdgcn_s_setprio(1);
                acc = __builtin_amdgcn_mfma_f32_16x16x32_bf16(ra[idx][0], qrf[g][0], acc, 0, 0, 0);
                acc = __builtin_amdgcn_mfma_f32_16x16x32_bf16(ra[idx][1], qrf[g][1], acc, 0, 0, 0);
                __builtin_amdgcn_s_setprio(0);
                *(f32x4*)(scw + il * 84 + uf * 16 + quad * 4) = acc;
            }

            const int i_gl = iw0 + 16 * g + il;
            float sv[4][4];
            float tmax = -1e30f;
#pragma unroll
            for (int fr = 0; fr < 4; ++fr) {
                const int base = il * 83 + fr * 16 + quad * 4 + 15;  // = il*84 + (jl_-il+15)
#pragma unroll
                for (int rr = 0; rr < 4; ++rr) {
                    const int jl_ = fr * 16 + quad * 4 + rr;
                    float s = sf[g][fr][rr] + scw[base + rr];
                    if (edge) s = (j0 + jl_ > i_gl + MEM) ? -1e30f : s;
                    sv[fr][rr] = s;
                    tmax = fmaxf(tmax, s);
                }
            }
            // ---- T13 defer-max: wave-uniform check, no divergence
            if (!__all(tmax <= m_i[g] + 8.0f)) {
                float t2 = fmaxf(tmax, __shfl_xor(tmax, 16));
                t2 = fmaxf(t2, __shfl_xor(t2, 32));
                const float m_new = fmaxf(m_i[g], t2);
                const float alpha = exp2f((m_i[g] - m_new) * c);
                l_i[g] *= alpha;
#pragma unroll
                for (int df = 0; df < 4; ++df) O[g][df] *= alpha;
                m_i[g] = m_new;
            }
            const float m_cur = m_i[g];
            float psum = 0.f;
            __bf16* prow = (__bf16*)(scw + il * 84);   // P overwrites row head
#pragma unroll
            for (int fr = 0; fr < 4; ++fr) {
                bf16x4t p4;
#pragma unroll
                for (int rr = 0; rr < 4; ++rr) {
                    float p = exp2f((sv[fr][rr] - m_cur) * c);
                    psum += p;
                    p4[rr] = (__bf16)p;
                }
                // after all gathers for this g (same wave): safe overwrite
                *(bf16x4t*)(prow + fr * 16 + quad * 4) = p4;
            }
            psum += __shfl_xor(psum, 16);
            psum += __shfl_xor(psum, 32);
            l_i[g] += psum;

            bf16x8 p0 = *(const bf16x8*)(prow + quad * 8);
            bf16x8 p1 = *(const bf16x8*)(prow + 32 + quad * 8);
            __builtin_amdgcn_s_setprio(1);
#pragma unroll
            for (int df = 0; df < 4; ++df) {
                O[g][df] = __builtin_amdgcn_mfma_f32_16x16x32_bf16(va[df][0], p0, O[g][df], 0, 0, 0);
                O[g][df] = __builtin_amdgcn_mfma_f32_16x16x32_bf16(va[df][1], p1, O[g][df], 0, 0, 0);
            }
            __builtin_amdgcn_s_setprio(0);
        }
        rot += 64; if (rot >= 192) rot -= 192;
    }

    // ---- write partials (unnormalized)
#pragma unroll
    for (int g = 0; g < 2; ++g) {
        const int iL = w * 32 + 16 * g + il;
        float* opb = Op + (size_t)part * 4194304
                        + ((((size_t)b * NH + n) * 8 + ib)) * 8192
                        + (size_t)iL * 64 + quad * 4;
#pragma unroll
        for (int df = 0; df < 4; ++df)
            *(f32x4*)(opb + df * 16) = O[g][df];
        if (quad == 0) {
            const size_t base = (((size_t)b * NH + n) * 8 + ib) * 128 + iL;
            ml[(size_t)part * 65536 + base]          = m_i[g];
            ml[131072 + (size_t)part * 65536 + base] = l_i[g];
        }
    }
}

// ---------------------------------------------------------------------------
// Combine 2 attention partials -> avh bf16.  Grid (QL/4, NH, BSZ).
// ---------------------------------------------------------------------------
__global__ __launch_bounds__(256)
void attn_combine(const float* __restrict__ Op, const float* __restrict__ ml,
                  __bf16* __restrict__ av)
{
    const int tid = threadIdx.x;
    const int i = blockIdx.x * 4 + (tid >> 6);
    const int d = tid & 63;
    const int n = blockIdx.y, b = blockIdx.z;
    const int ib = i >> 7, iL = i & 127;
    const float c = 0.125f * 1.44269504f;

    const size_t mb = (((size_t)b * NH + n) * 8 + ib) * 128 + iL;
    const float m0 = ml[mb], m1 = ml[mb + 65536];
    const float l0 = ml[131072 + mb], l1 = ml[131072 + 65536 + mb];
    const float ms = fmaxf(m0, m1);
    const float w0 = exp2f((m0 - ms) * c);
    const float w1 = exp2f((m1 - ms) * c);
    const float ls = w0 * l0 + w1 * l1;

    const size_t ob = (((size_t)b * NH + n) * 8 + ib) * 8192
                      + (size_t)iL * 64 + d;
    const float o = w0 * Op[ob] + w1 * Op[ob + 4194304];
    av[((size_t)(b * QL + i)) * DM + n * 64 + d] = (__bf16)(o / ls);
}

// ---------------------------------------------------------------------------
// Workspace (MB offsets, ~123 MB total):
//  0 wbh(16) | 16 rbh(4) | 20 WqT(2) | 22 WkvT(4) | 26 WrT(2) | 28 WoT(2)
//  30 qwh(8) | 38 qrh(8) | 46 kh(16) | 62 vhT(16) | 78 rkh(4) | 82 avh(8)
//  90 Op(32) | 122 ml(1)
// ---------------------------------------------------------------------------
extern "C" void kernel_launch(void* const* d_in, const int* in_sizes, int n_in,
                              void* d_out, int out_size, void* d_ws, size_t ws_size,
                              hipStream_t stream)
{
    const float* w   = (const float*)d_in[0];
    const float* r   = (const float*)d_in[1];
    const float* bwb = (const float*)d_in[2];
    const float* brb = (const float*)d_in[3];
    const float* Wq  = (const float*)d_in[4];
    const float* Wkv = (const float*)d_in[5];
    const float* Wr  = (const float*)d_in[6];
    const float* Wo  = (const float*)d_in[7];
    float* out = (float*)d_out;

    char* ws = (char*)d_ws;
    __bf16* wbh  = (__bf16*)(ws);
    __bf16* rbh  = (__bf16*)(ws + ((size_t)16 << 20));
    __bf16* WqT  = (__bf16*)(ws + ((size_t)20 << 20));
    __bf16* WkvT = (__bf16*)(ws + ((size_t)22 << 20));
    __bf16* WrT  = (__bf16*)(ws + ((size_t)26 << 20));
    __bf16* WoT  = (__bf16*)(ws + ((size_t)28 << 20));
    __bf16* qwh  = (__bf16*)(ws + ((size_t)30 << 20));
    __bf16* qrh  = (__bf16*)(ws + ((size_t)38 << 20));
    __bf16* kh   = (__bf16*)(ws + ((size_t)46 << 20));
    __bf16* vhT  = (__bf16*)(ws + ((size_t)62 << 20));
    __bf16* rkh  = (__bf16*)(ws + ((size_t)78 << 20));
    __bf16* avh  = (__bf16*)(ws + ((size_t)82 << 20));
    float*  Op   = (float*)(ws + ((size_t)90 << 20));
    float*  mlb  = (float*)(ws + ((size_t)122 << 20));

    dim3 blk(256);
    prep<<<7168, blk, 0, stream>>>(w, r, Wq, Wr, Wo, Wkv,
                                   wbh, rbh, WqT, WrT, WoT, WkvT);
    gemm_proj<<<1408, blk, 0, stream>>>(wbh, rbh, WqT, WkvT, WrT,
                                        qwh, qrh, kh, vhT, rkh, bwb, brb);
    attn_mfma<<<dim3(16, 16, 4), blk, 62464, stream>>>(
        qwh, qrh, kh, vhT, rkh, Op, mlb);
    attn_combine<<<dim3(256, 16, 4), blk, 0, stream>>>(Op, mlb, avh);
    gemm_out<<<dim3(8, 8, 4), blk, 0, stream>>>(avh, WoT, out);
}

// Round 15
// 334.131 us; speedup vs baseline: 1.0985x; 1.0126x over previous
//
#include <hip/hip_runtime.h>

// Problem constants (Transformer-XL attention)
constexpr int BSZ  = 4;
constexpr int NH   = 16;
constexpr int DH   = 64;
constexpr int QL   = 1024;
constexpr int KLN  = 2048;
constexpr int DM   = 1024;   // d_model = NH*DH
constexpr int MEM  = 1024;   // KLEN - QLEN

typedef __bf16 bf16x8  __attribute__((ext_vector_type(8)));
typedef __bf16 bf16x4t __attribute__((ext_vector_type(4)));
typedef float  f32x4   __attribute__((ext_vector_type(4)));

// async global->LDS, 16B per lane; LDS dst is wave-uniform base + lane*16
__device__ __forceinline__ void g2l16(__bf16* lds, const __bf16* g) {
    __builtin_amdgcn_global_load_lds(
        (const __attribute__((address_space(1))) unsigned int*)g,
        (__attribute__((address_space(3))) unsigned int*)lds, 16, 0, 0);
}

// ---------------------------------------------------------------------------
// prep: one launch. Blocks [0,5120): cast w,r -> bf16. Blocks [5120,7168):
// transpose-cast the 4 weights (z = t>>9: 0 Wq, 1 Wr, 2 Wo, 3 Wkv).
// ---------------------------------------------------------------------------
__global__ __launch_bounds__(256)
void prep(const float* __restrict__ w, const float* __restrict__ r,
          const float* __restrict__ Wq, const float* __restrict__ Wr,
          const float* __restrict__ Wo, const float* __restrict__ Wkv,
          __bf16* __restrict__ wbh, __bf16* __restrict__ rbh,
          __bf16* __restrict__ WqT, __bf16* __restrict__ WrT,
          __bf16* __restrict__ WoT, __bf16* __restrict__ WkvT)
{
    __shared__ __bf16 t[64 * 72];
    const int id = blockIdx.x;
    if (id < 5120) {
        const float* in; __bf16* out; size_t i;
        if (id < 4096) { in = w; out = wbh; i = ((size_t)id * 256 + threadIdx.x) * 8; }
        else { in = r; out = rbh; i = ((size_t)(id - 4096) * 256 + threadIdx.x) * 8; }
        float4 a = *(const float4*)(in + i);
        float4 b = *(const float4*)(in + i + 4);
        bf16x8 y = {(__bf16)a.x, (__bf16)a.y, (__bf16)a.z, (__bf16)a.w,
                    (__bf16)b.x, (__bf16)b.y, (__bf16)b.z, (__bf16)b.w};
        *(bf16x8*)(out + i) = y;
        return;
    }
    const int tt = id - 5120;
    const int z = tt >> 9, rem = tt & 511;
    const int xx = rem & 31, yy = rem >> 5;
    const float* in; __bf16* out; int N;
    if (z == 0)      { in = Wq;  out = WqT;  N = 1024; }
    else if (z == 1) { in = Wr;  out = WrT;  N = 1024; }
    else if (z == 2) { in = Wo;  out = WoT;  N = 1024; }
    else             { in = Wkv; out = WkvT; N = 2048; }
    if (xx * 64 >= N) return;
    const int n0 = xx * 64, k0 = yy * 64;
    const int row = threadIdx.x >> 2, seg = (threadIdx.x & 3) << 4;
    const float* src = in + (long)(k0 + row) * N + n0 + seg;
#pragma unroll
    for (int u = 0; u < 16; u += 4) {
        float4 x = *(const float4*)(src + u);
        t[(seg + u + 0) * 72 + row] = (__bf16)x.x;
        t[(seg + u + 1) * 72 + row] = (__bf16)x.y;
        t[(seg + u + 2) * 72 + row] = (__bf16)x.z;
        t[(seg + u + 3) * 72 + row] = (__bf16)x.w;
    }
    __syncthreads();
    __bf16* dst = out + (long)(n0 + row) * 1024 + k0 + seg;
    *(uint4*)(dst)     = *(const uint4*)(t + row * 72 + seg);
    *(uint4*)(dst + 8) = *(const uint4*)(t + row * 72 + seg + 8);
}

// ---------------------------------------------------------------------------
// Shared GEMM core R15: 128x128 tile, BK=32, 4 waves, 2-phase double-buffer
// (kept: marginally positive, race-clean; incremental pipelining on this
// structure is otherwise confirmed null, matching m99/m100).
// ---------------------------------------------------------------------------
__device__ __forceinline__ void gemm_core(
    const __bf16* __restrict__ A, const __bf16* __restrict__ BT,
    __bf16* As, __bf16* Bs, int m0, int n0, int K, f32x4 (&acc)[4][4])
{
    const int tid = threadIdx.x, w = tid >> 6, l = tid & 63;
    const int il = l & 15, quad = l >> 4;
    const int wm = (w >> 1) * 64, wn = (w & 1) * 64;
    const int lr = l >> 2, kc = (l & 3) ^ (lr & 3);

    const __bf16* ag = A  + (long)(m0 + w * 32 + lr) * K + kc * 8;
    const __bf16* bg = BT + (long)(n0 + w * 32 + lr) * K + kc * 8;
    const int aoff0 = (w * 32) * 32;
    const int aoff1 = (w * 32 + 16) * 32;
    const int rsw = il & 3;
    const int rdoff = (quad ^ rsw) << 3;

    // prologue: stage tile k0=0 into buffer 0
    g2l16(As + aoff0, ag);
    g2l16(As + aoff1, ag + 16 * K);
    g2l16(Bs + aoff0, bg);
    g2l16(Bs + aoff1, bg + 16 * K);
    __syncthreads();                      // drains vmcnt; buf0 ready

    int cur = 0;
    for (int k0 = 0; k0 < K; k0 += 32) {
        const int nxt = cur ^ 1;
        if (k0 + 32 < K) {                // async prefetch next K-tile
            g2l16(As + nxt * 4096 + aoff0, ag + k0 + 32);
            g2l16(As + nxt * 4096 + aoff1, ag + k0 + 32 + 16 * K);
            g2l16(Bs + nxt * 4096 + aoff0, bg + k0 + 32);
            g2l16(Bs + nxt * 4096 + aoff1, bg + k0 + 32 + 16 * K);
        }

        bf16x8 af[4], bf[4];
#pragma unroll
        for (int f = 0; f < 4; ++f) {
            af[f] = *(const bf16x8*)(As + cur * 4096 + (wm + f * 16 + il) * 32 + rdoff);
            bf[f] = *(const bf16x8*)(Bs + cur * 4096 + (wn + f * 16 + il) * 32 + rdoff);
        }
#pragma unroll
        for (int i = 0; i < 4; ++i)
#pragma unroll
            for (int j = 0; j < 4; ++j)
                acc[i][j] = __builtin_amdgcn_mfma_f32_16x16x32_bf16(
                    af[i], bf[j], acc[i][j], 0, 0, 0);

        __syncthreads();                  // prefetch drained; cur reusable
        cur = nxt;
    }
}

// ---------------------------------------------------------------------------
// Merged projection GEMM: 1408 blocks.
// ---------------------------------------------------------------------------
__global__ __launch_bounds__(256, 2)
void gemm_proj(const __bf16* __restrict__ wbh, const __bf16* __restrict__ rbh,
               const __bf16* __restrict__ WqT, const __bf16* __restrict__ WkvT,
               const __bf16* __restrict__ WrT,
               __bf16* __restrict__ qwh, __bf16* __restrict__ qrh,
               __bf16* __restrict__ kh, __bf16* __restrict__ vhT,
               __bf16* __restrict__ rkh,
               const float* __restrict__ bw, const float* __restrict__ br)
{
    __shared__ __bf16 As[2 * 128 * 32];
    __shared__ __bf16 Bs[2 * 128 * 32];
    const int id = blockIdx.x;
    const __bf16 *A, *BT;
    int m0, n0, zz, kind;
    if (id < 1024) {
        n0 = (id & 15) * 128; m0 = ((id >> 4) & 15) * 128; zz = id >> 8;
        A = wbh + (size_t)zz * KLN * DM; BT = WkvT; kind = 3;
    } else if (id < 1280) {
        const int t = id - 1024;
        n0 = (t & 7) * 128; m0 = ((t >> 3) & 7) * 128; zz = t >> 6;
        A = wbh + (size_t)zz * KLN * DM + (size_t)MEM * DM; BT = WqT; kind = 2;
    } else {
        const int t = id - 1280;
        n0 = (t & 7) * 128; m0 = (t >> 3) * 128; zz = 0;
        A = rbh; BT = WrT; kind = 4;
    }

    f32x4 acc[4][4] = {};
    gemm_core(A, BT, As, Bs, m0, n0, DM, acc);

    const int tid = threadIdx.x, w = tid >> 6, l = tid & 63;
    const int il = l & 15, quad = l >> 4;
    const int wm = (w >> 1) * 64, wn = (w & 1) * 64;

    if (kind == 2) {
#pragma unroll
        for (int j = 0; j < 4; ++j) {
            const int col = n0 + wn + j * 16 + il;
            const int hn = col >> 6, d = col & 63;
            const float bwv = bw[col], brv = br[col];
            __bf16* q1 = qwh + ((size_t)(zz * 16 + hn) * 1024) * 64 + d;
            __bf16* q2 = qrh + ((size_t)(zz * 16 + hn) * 1024) * 64 + d;
#pragma unroll
            for (int i = 0; i < 4; ++i) {
                const int mb = m0 + wm + i * 16 + quad * 4;
#pragma unroll
                for (int rr = 0; rr < 4; ++rr) {
                    float v = acc[i][j][rr];
                    q1[(size_t)(mb + rr) * 64] = (__bf16)(v + bwv);
                    q2[(size_t)(mb + rr) * 64] = (__bf16)(v + brv);
                }
            }
        }
    } else if (kind == 3) {
        if (n0 + wn < 1024) {
#pragma unroll
            for (int j = 0; j < 4; ++j) {
                const int col = n0 + wn + j * 16 + il;
                const int hn = col >> 6, d = col & 63;
                __bf16* kp = kh + ((size_t)(zz * 16 + hn) * 2048) * 64 + d;
#pragma unroll
                for (int i = 0; i < 4; ++i) {
                    const int mb = m0 + wm + i * 16 + quad * 4;
#pragma unroll
                    for (int rr = 0; rr < 4; ++rr)
                        kp[(size_t)(mb + rr) * 64] = (__bf16)acc[i][j][rr];
                }
            }
        } else {
#pragma unroll
            for (int j = 0; j < 4; ++j) {
                const int col = n0 + wn + j * 16 + il - 1024;
                const int hn = col >> 6, d = col & 63;
                __bf16* vp = vhT + ((size_t)((zz * 16 + hn) * 64 + d)) * 2048;
#pragma unroll
                for (int i = 0; i < 4; ++i) {
                    const int mb = m0 + wm + i * 16 + quad * 4;
                    bf16x4t pk = {(__bf16)acc[i][j][0], (__bf16)acc[i][j][1],
                                  (__bf16)acc[i][j][2], (__bf16)acc[i][j][3]};
                    *(bf16x4t*)(vp + mb) = pk;
                }
            }
        }
    } else { // kind 4
#pragma unroll
        for (int j = 0; j < 4; ++j) {
            const int col = n0 + wn + j * 16 + il;
            const int hn = col >> 6, d = col & 63;
            __bf16* rp = rkh + ((size_t)hn * 2048) * 64 + d;
#pragma unroll
            for (int i = 0; i < 4; ++i) {
                const int mb = m0 + wm + i * 16 + quad * 4;
#pragma unroll
                for (int rr = 0; rr < 4; ++rr)
                    rp[(size_t)(mb + rr) * 64] = (__bf16)acc[i][j][rr];
            }
        }
    }
}

// ---------------------------------------------------------------------------
// Output projection: out = avh @ WoT^T, f32 C.  Grid (8,8,4).
// ---------------------------------------------------------------------------
__global__ __launch_bounds__(256, 2)
void gemm_out(const __bf16* __restrict__ avh, const __bf16* __restrict__ WoT,
              float* __restrict__ C)
{
    __shared__ __bf16 As[2 * 128 * 32];
    __shared__ __bf16 Bs[2 * 128 * 32];
    const int zz = blockIdx.z;
    const __bf16* A = avh + (size_t)zz * QL * DM;
    const int m0 = blockIdx.y * 128, n0 = blockIdx.x * 128;

    f32x4 acc[4][4] = {};
    gemm_core(A, WoT, As, Bs, m0, n0, DM, acc);

    const int tid = threadIdx.x, w = tid >> 6, l = tid & 63;
    const int il = l & 15, quad = l >> 4;
    const int wm = (w >> 1) * 64, wn = (w & 1) * 64;
    float* Cb = C + (size_t)zz * QL * DM;
#pragma unroll
    for (int i = 0; i < 4; ++i)
#pragma unroll
        for (int j = 0; j < 4; ++j) {
            float* cp = Cb + (long)(m0 + wm + i * 16 + quad * 4) * DM
                           + n0 + wn + j * 16 + il;
#pragma unroll
            for (int rr = 0; rr < 4; ++rr) cp[(long)rr * DM] = acc[i][j][rr];
        }
}

// ---------------------------------------------------------------------------
// MFMA flash attention, R19: R18 verified core (131.2us) + serial-chain
// latency trims (no address-math changes):
//  * psum cross-quad shuffles MOVED OUT of the tile loop: l_i carries a
//    QUAD-PARTIAL sum (alpha is wave-uniform after reduction, so uniform
//    rescale of partials is exact); one 2-shuffle reduction after the loop.
//    Removes 2 DS ops x 2 g per tile from the serial chain.
//  * fmax/psum trees (exact for max; add reassociation noise << threshold):
//    dependent latency 16 -> ~5 ops.
// LDS: kt 8K | vt 8K | rkt 24K | scf 21K = 62464 B -> 2 blocks/CU.
// ---------------------------------------------------------------------------
__global__ __launch_bounds__(256, 2)
void attn_mfma(const __bf16* __restrict__ qwh, const __bf16* __restrict__ qrh,
               const __bf16* __restrict__ kh, const __bf16* __restrict__ vhT,
               const __bf16* __restrict__ rkh, float* __restrict__ Op,
               float* __restrict__ ml)
{
    extern __shared__ __bf16 smem[];
    __bf16* kt  = smem;            // [64][64] xor-swizzled
    __bf16* vt  = smem + 4096;     // [64][64] xor
    __bf16* rkt = smem + 8192;     // [192][64] xor, circular
    float*  scf = (float*)(smem + 20480);  // 4 waves x [16][84] f32 scratch

    const int bx = blockIdx.x;
    const int part = bx & 1;
    const int bx2 = bx >> 1;                     // 0..7
    const int ib = (bx2 & 1) ? (7 - (bx2 >> 1)) : (bx2 >> 1);
    const int i0 = ib * 128;
    const int n = blockIdx.y, b = blockIdx.z;
    const int tid = threadIdx.x;
    const int w = tid >> 6, l = tid & 63;
    const int il = l & 15, quad = l >> 4;
    const int iw0 = i0 + w * 32;

    // persistent Q fragments, 2 i-frags per wave
    bf16x8 qwf[2][2], qrf[2][2];
#pragma unroll
    for (int g = 0; g < 2; ++g) {
        const size_t qoff =
            ((size_t)((b * 16 + n) * QL + iw0 + 16 * g + il)) * 64 + quad * 8;
        qwf[g][0] = *(const bf16x8*)(qwh + qoff);
        qwf[g][1] = *(const bf16x8*)(qwh + qoff + 32);
        qrf[g][0] = *(const bf16x8*)(qrh + qoff);
        qrf[g][1] = *(const bf16x8*)(qrh + qoff + 32);
    }

    f32x4 O[2][4] = {};
    float m_i[2] = {-1e30f, -1e30f}, l_i[2] = {0.f, 0.f};  // l_i: quad-partial
    const float c = 0.125f * 1.44269504f;        // scale * log2(e)

    const int srow = l >> 3, scl = l & 7;        // staging: 8 rows x 8 chunks
    const __bf16* kbase  = kh  + ((size_t)((b * 16 + n) * KLN)) * 64;
    const __bf16* vbase0 = vhT + ((size_t)((b * 16 + n) * 64)) * KLN;
    const __bf16* rbp    = rkh + ((size_t)(n * KLN)) * 64;

    const int xk0 = ((quad) ^ (il & 7)) << 3;
    const int xk1 = ((quad + 4) ^ (il & 7)) << 3;

    const int nt = 2 * ib + 18;
    const int t0 = (part * nt) / 2;
    const int t1 = ((part + 1) * nt) / 2;
    int rot = (t0 % 3) * 64;                     // circular offset for tile t0

    const int ubB = 96 - 32 * w;                 // logical base of shared BD frags

    for (int jt = t0; jt < t1; ++jt) {
        const int j0 = jt * 64;
        const int vu0 = j0 - i0 + 896;           // rk row of logical rkt row 0
        __syncthreads();
#pragma unroll
        for (int it = 0; it < 2; ++it) {         // K tile rows j
            const int row = w * 16 + it * 8 + srow;
            g2l16(kt + (w * 16 + it * 8) * 64,
                  kbase + ((size_t)(j0 + row)) * 64 + ((scl ^ srow) << 3));
        }
#pragma unroll
        for (int it = 0; it < 2; ++it) {         // V^T tile rows d
            const int row = w * 16 + it * 8 + srow;
            g2l16(vt + (w * 16 + it * 8) * 64,
                  vbase0 + (size_t)row * KLN + j0 + ((scl ^ srow) << 3));
        }
        if (jt == t0) {                          // full 192-row window fill
#pragma unroll
            for (int it = 0; it < 6; ++it) {
                const int lbase = w * 48 + it * 8;
                int pb = lbase + rot; if (pb >= 192) pb -= 192;
                int vu = vu0 + lbase + srow;
                vu = vu < 0 ? 0 : (vu > KLN - 1 ? KLN - 1 : vu);
                g2l16(rkt + pb * 64,
                      rbp + (size_t)vu * 64 + ((scl ^ srow) << 3));
            }
        } else {                                 // slide: logical rows 128..191
#pragma unroll
            for (int it = 0; it < 2; ++it) {
                const int lbase = 128 + w * 16 + it * 8;
                int pb = lbase + rot; if (pb >= 192) pb -= 192;
                int vu = vu0 + lbase + srow;
                vu = vu < 0 ? 0 : (vu > KLN - 1 ? KLN - 1 : vu);
                g2l16(rkt + pb * 64,
                      rbp + (size_t)vu * 64 + ((scl ^ srow) << 3));
            }
        }
        __syncthreads();

        const bool edge = (j0 + 63 > i0 + MEM);

        // ---- Phase 1: AC for both g (kt frags read ONCE)
        f32x4 sf[2][4];
#pragma unroll
        for (int fr = 0; fr < 4; ++fr) {
            const __bf16* ka = kt + (fr * 16 + il) * 64;
            bf16x8 a0 = *(const bf16x8*)(ka + xk0);
            bf16x8 a1 = *(const bf16x8*)(ka + xk1);
            __builtin_amdgcn_s_setprio(1);
#pragma unroll
            for (int g = 0; g < 2; ++g) {
                f32x4 acc = {};
                acc = __builtin_amdgcn_mfma_f32_16x16x32_bf16(a0, qwf[g][0], acc, 0, 0, 0);
                acc = __builtin_amdgcn_mfma_f32_16x16x32_bf16(a1, qwf[g][1], acc, 0, 0, 0);
                sf[g][fr] = acc;
            }
            __builtin_amdgcn_s_setprio(0);
        }

        // ---- shared fragment loads, once per tile (used by both g)
        bf16x8 ra[6][2];
#pragma unroll
        for (int uf2 = 0; uf2 < 6; ++uf2) {
            int pr = ubB + uf2 * 16 + il + rot; if (pr >= 192) pr -= 192;
            const __bf16* rp_ = rkt + pr * 64;
            ra[uf2][0] = *(const bf16x8*)(rp_ + xk0);
            ra[uf2][1] = *(const bf16x8*)(rp_ + xk1);
        }
        bf16x8 va[4][2];
#pragma unroll
        for (int df = 0; df < 4; ++df) {
            const __bf16* vp_ = vt + (df * 16 + il) * 64;
            va[df][0] = *(const bf16x8*)(vp_ + xk0);
            va[df][1] = *(const bf16x8*)(vp_ + xk1);
        }

        // ---- per-g: BD(f32 scratch) -> gather/softmax -> P(scratch) -> PV
        float* scw = scf + w * 1344;             // per-wave [16][84] f32
#pragma unroll
        for (int g = 0; g < 2; ++g) {
            // BD: 5 frags, idx = uf+1-g (g0: ra[1..5], g1: ra[0..4])
#pragma unroll
            for (int uf = 0; uf < 5; ++uf) {
                const int idx = uf + 1 - g;
                f32x4 acc = {};
                __builtin_amdgcn_s_setprio(1);
                acc = __builtin_amdgcn_mfma_f32_16x16x32_bf16(ra[idx][0], qrf[g][0], acc, 0, 0, 0);
                acc = __builtin_amdgcn_mfma_f32_16x16x32_bf16(ra[idx][1], qrf[g][1], acc, 0, 0, 0);
                __builtin_amdgcn_s_setprio(0);
                *(f32x4*)(scw + il * 84 + uf * 16 + quad * 4) = acc;
            }

            const int i_gl = iw0 + 16 * g + il;
            float sv[4][4];
            float mfr[4];
#pragma unroll
            for (int fr = 0; fr < 4; ++fr) {
                const int base = il * 83 + fr * 16 + quad * 4 + 15;  // = il*84 + (jl_-il+15)
#pragma unroll
                for (int rr = 0; rr < 4; ++rr) {
                    const int jl_ = fr * 16 + quad * 4 + rr;
                    float s = sf[g][fr][rr] + scw[base + rr];
                    if (edge) s = (j0 + jl_ > i_gl + MEM) ? -1e30f : s;
                    sv[fr][rr] = s;
                }
                mfr[fr] = fmaxf(fmaxf(sv[fr][0], sv[fr][1]),
                                fmaxf(sv[fr][2], sv[fr][3]));
            }
            const float tmax = fmaxf(fmaxf(mfr[0], mfr[1]),
                                     fmaxf(mfr[2], mfr[3]));
            // ---- T13 defer-max: wave-uniform check, no divergence
            if (!__all(tmax <= m_i[g] + 8.0f)) {
                float t2 = fmaxf(tmax, __shfl_xor(tmax, 16));
                t2 = fmaxf(t2, __shfl_xor(t2, 32));
                const float m_new = fmaxf(m_i[g], t2);
                const float alpha = exp2f((m_i[g] - m_new) * c);
                l_i[g] *= alpha;                 // quad-partial: uniform scale
#pragma unroll
                for (int df = 0; df < 4; ++df) O[g][df] *= alpha;
                m_i[g] = m_new;
            }
            const float m_cur = m_i[g];
            float pfr[4];
            __bf16* prow = (__bf16*)(scw + il * 84);   // P overwrites row head
#pragma unroll
            for (int fr = 0; fr < 4; ++fr) {
                bf16x4t p4;
                float p0_ = exp2f((sv[fr][0] - m_cur) * c);
                float p1_ = exp2f((sv[fr][1] - m_cur) * c);
                float p2_ = exp2f((sv[fr][2] - m_cur) * c);
                float p3_ = exp2f((sv[fr][3] - m_cur) * c);
                p4[0] = (__bf16)p0_; p4[1] = (__bf16)p1_;
                p4[2] = (__bf16)p2_; p4[3] = (__bf16)p3_;
                pfr[fr] = (p0_ + p1_) + (p2_ + p3_);
                // after all gathers for this g (same wave): safe overwrite
                *(bf16x4t*)(prow + fr * 16 + quad * 4) = p4;
            }
            l_i[g] += (pfr[0] + pfr[1]) + (pfr[2] + pfr[3]);  // quad-partial

            bf16x8 p0 = *(const bf16x8*)(prow + quad * 8);
            bf16x8 p1 = *(const bf16x8*)(prow + 32 + quad * 8);
            __builtin_amdgcn_s_setprio(1);
#pragma unroll
            for (int df = 0; df < 4; ++df) {
                O[g][df] = __builtin_amdgcn_mfma_f32_16x16x32_bf16(va[df][0], p0, O[g][df], 0, 0, 0);
                O[g][df] = __builtin_amdgcn_mfma_f32_16x16x32_bf16(va[df][1], p1, O[g][df], 0, 0, 0);
            }
            __builtin_amdgcn_s_setprio(0);
        }
        rot += 64; if (rot >= 192) rot -= 192;
    }

    // ---- reduce quad-partial l across the 4 quads sharing il (once)
#pragma unroll
    for (int g = 0; g < 2; ++g) {
        l_i[g] += __shfl_xor(l_i[g], 16);
        l_i[g] += __shfl_xor(l_i[g], 32);
    }

    // ---- write partials (unnormalized)
#pragma unroll
    for (int g = 0; g < 2; ++g) {
        const int iL = w * 32 + 16 * g + il;
        float* opb = Op + (size_t)part * 4194304
                        + ((((size_t)b * NH + n) * 8 + ib)) * 8192
                        + (size_t)iL * 64 + quad * 4;
#pragma unroll
        for (int df = 0; df < 4; ++df)
            *(f32x4*)(opb + df * 16) = O[g][df];
        if (quad == 0) {
            const size_t base = (((size_t)b * NH + n) * 8 + ib) * 128 + iL;
            ml[(size_t)part * 65536 + base]          = m_i[g];
            ml[131072 + (size_t)part * 65536 + base] = l_i[g];
        }
    }
}

// ---------------------------------------------------------------------------
// Combine 2 attention partials -> avh bf16.  Grid (QL/4, NH, BSZ).
// ---------------------------------------------------------------------------
__global__ __launch_bounds__(256)
void attn_combine(const float* __restrict__ Op, const float* __restrict__ ml,
                  __bf16* __restrict__ av)
{
    const int tid = threadIdx.x;
    const int i = blockIdx.x * 4 + (tid >> 6);
    const int d = tid & 63;
    const int n = blockIdx.y, b = blockIdx.z;
    const int ib = i >> 7, iL = i & 127;
    const float c = 0.125f * 1.44269504f;

    const size_t mb = (((size_t)b * NH + n) * 8 + ib) * 128 + iL;
    const float m0 = ml[mb], m1 = ml[mb + 65536];
    const float l0 = ml[131072 + mb], l1 = ml[131072 + 65536 + mb];
    const float ms = fmaxf(m0, m1);
    const float w0 = exp2f((m0 - ms) * c);
    const float w1 = exp2f((m1 - ms) * c);
    const float ls = w0 * l0 + w1 * l1;

    const size_t ob = (((size_t)b * NH + n) * 8 + ib) * 8192
                      + (size_t)iL * 64 + d;
    const float o = w0 * Op[ob] + w1 * Op[ob + 4194304];
    av[((size_t)(b * QL + i)) * DM + n * 64 + d] = (__bf16)(o / ls);
}

// ---------------------------------------------------------------------------
// Workspace (MB offsets, ~123 MB total):
//  0 wbh(16) | 16 rbh(4) | 20 WqT(2) | 22 WkvT(4) | 26 WrT(2) | 28 WoT(2)
//  30 qwh(8) | 38 qrh(8) | 46 kh(16) | 62 vhT(16) | 78 rkh(4) | 82 avh(8)
//  90 Op(32) | 122 ml(1)
// ---------------------------------------------------------------------------
extern "C" void kernel_launch(void* const* d_in, const int* in_sizes, int n_in,
                              void* d_out, int out_size, void* d_ws, size_t ws_size,
                              hipStream_t stream)
{
    const float* w   = (const float*)d_in[0];
    const float* r   = (const float*)d_in[1];
    const float* bwb = (const float*)d_in[2];
    const float* brb = (const float*)d_in[3];
    const float* Wq  = (const float*)d_in[4];
    const float* Wkv = (const float*)d_in[5];
    const float* Wr  = (const float*)d_in[6];
    const float* Wo  = (const float*)d_in[7];
    float* out = (float*)d_out;

    char* ws = (char*)d_ws;
    __bf16* wbh  = (__bf16*)(ws);
    __bf16* rbh  = (__bf16*)(ws + ((size_t)16 << 20));
    __bf16* WqT  = (__bf16*)(ws + ((size_t)20 << 20));
    __bf16* WkvT = (__bf16*)(ws + ((size_t)22 << 20));
    __bf16* WrT  = (__bf16*)(ws + ((size_t)26 << 20));
    __bf16* WoT  = (__bf16*)(ws + ((size_t)28 << 20));
    __bf16* qwh  = (__bf16*)(ws + ((size_t)30 << 20));
    __bf16* qrh  = (__bf16*)(ws + ((size_t)38 << 20));
    __bf16* kh   = (__bf16*)(ws + ((size_t)46 << 20));
    __bf16* vhT  = (__bf16*)(ws + ((size_t)62 << 20));
    __bf16* rkh  = (__bf16*)(ws + ((size_t)78 << 20));
    __bf16* avh  = (__bf16*)(ws + ((size_t)82 << 20));
    float*  Op   = (float*)(ws + ((size_t)90 << 20));
    float*  mlb  = (float*)(ws + ((size_t)122 << 20));

    dim3 blk(256);
    prep<<<7168, blk, 0, stream>>>(w, r, Wq, Wr, Wo, Wkv,
                                   wbh, rbh, WqT, WrT, WoT, WkvT);
    gemm_proj<<<1408, blk, 0, stream>>>(wbh, rbh, WqT, WkvT, WrT,
                                        qwh, qrh, kh, vhT, rkh, bwb, brb);
    attn_mfma<<<dim3(16, 16, 4), blk, 62464, stream>>>(
        qwh, qrh, kh, vhT, rkh, Op, mlb);
    attn_combine<<<dim3(256, 16, 4), blk, 0, stream>>>(Op, mlb, avh);
    gemm_out<<<dim3(8, 8, 4), blk, 0, stream>>>(avh, WoT, out);
}

// Round 16
// 330.581 us; speedup vs baseline: 1.1103x; 1.0107x over previous
//
#include <hip/hip_runtime.h>

// Problem constants (Transformer-XL attention)
constexpr int BSZ  = 4;
constexpr int NH   = 16;
constexpr int DH   = 64;
constexpr int QL   = 1024;
constexpr int KLN  = 2048;
constexpr int DM   = 1024;   // d_model = NH*DH
constexpr int MEM  = 1024;   // KLEN - QLEN

typedef __bf16 bf16x8  __attribute__((ext_vector_type(8)));
typedef __bf16 bf16x4t __attribute__((ext_vector_type(4)));
typedef float  f32x4   __attribute__((ext_vector_type(4)));

// async global->LDS, 16B per lane; LDS dst is wave-uniform base + lane*16
__device__ __forceinline__ void g2l16(__bf16* lds, const __bf16* g) {
    __builtin_amdgcn_global_load_lds(
        (const __attribute__((address_space(1))) unsigned int*)g,
        (__attribute__((address_space(3))) unsigned int*)lds, 16, 0, 0);
}

// ---------------------------------------------------------------------------
// prep: one launch. Blocks [0,5120): cast w,r -> bf16. Blocks [5120,7168):
// transpose-cast the 4 weights (z = t>>9: 0 Wq, 1 Wr, 2 Wo, 3 Wkv).
// ---------------------------------------------------------------------------
__global__ __launch_bounds__(256)
void prep(const float* __restrict__ w, const float* __restrict__ r,
          const float* __restrict__ Wq, const float* __restrict__ Wr,
          const float* __restrict__ Wo, const float* __restrict__ Wkv,
          __bf16* __restrict__ wbh, __bf16* __restrict__ rbh,
          __bf16* __restrict__ WqT, __bf16* __restrict__ WrT,
          __bf16* __restrict__ WoT, __bf16* __restrict__ WkvT)
{
    __shared__ __bf16 t[64 * 72];
    const int id = blockIdx.x;
    if (id < 5120) {
        const float* in; __bf16* out; size_t i;
        if (id < 4096) { in = w; out = wbh; i = ((size_t)id * 256 + threadIdx.x) * 8; }
        else { in = r; out = rbh; i = ((size_t)(id - 4096) * 256 + threadIdx.x) * 8; }
        float4 a = *(const float4*)(in + i);
        float4 b = *(const float4*)(in + i + 4);
        bf16x8 y = {(__bf16)a.x, (__bf16)a.y, (__bf16)a.z, (__bf16)a.w,
                    (__bf16)b.x, (__bf16)b.y, (__bf16)b.z, (__bf16)b.w};
        *(bf16x8*)(out + i) = y;
        return;
    }
    const int tt = id - 5120;
    const int z = tt >> 9, rem = tt & 511;
    const int xx = rem & 31, yy = rem >> 5;
    const float* in; __bf16* out; int N;
    if (z == 0)      { in = Wq;  out = WqT;  N = 1024; }
    else if (z == 1) { in = Wr;  out = WrT;  N = 1024; }
    else if (z == 2) { in = Wo;  out = WoT;  N = 1024; }
    else             { in = Wkv; out = WkvT; N = 2048; }
    if (xx * 64 >= N) return;
    const int n0 = xx * 64, k0 = yy * 64;
    const int row = threadIdx.x >> 2, seg = (threadIdx.x & 3) << 4;
    const float* src = in + (long)(k0 + row) * N + n0 + seg;
#pragma unroll
    for (int u = 0; u < 16; u += 4) {
        float4 x = *(const float4*)(src + u);
        t[(seg + u + 0) * 72 + row] = (__bf16)x.x;
        t[(seg + u + 1) * 72 + row] = (__bf16)x.y;
        t[(seg + u + 2) * 72 + row] = (__bf16)x.z;
        t[(seg + u + 3) * 72 + row] = (__bf16)x.w;
    }
    __syncthreads();
    __bf16* dst = out + (long)(n0 + row) * 1024 + k0 + seg;
    *(uint4*)(dst)     = *(const uint4*)(t + row * 72 + seg);
    *(uint4*)(dst + 8) = *(const uint4*)(t + row * 72 + seg + 8);
}

// ---------------------------------------------------------------------------
// Shared GEMM core R20: 128x128 tile, BK=64, 4 waves, 2-phase double-buffer.
// Halves barrier-pair count (32 -> 16 per block; the m97-structure drain is
// the known ~20% cost) at UNCHANGED occupancy: LDS 64KB -> 2 blocks/CU
// (avoids m132's occupancy-loss failure).  64-col staging + xk0/xk1 2-chunk
// reads are a direct port of the attn kernel's VERIFIED pattern:
//   stage: lane l covers row srow=l>>3, holds global k-chunk (scl^srow),
//          g2l16 linear dst => LDS[row][c] = global chunk c^(row&7)
//   read:  row r chunk q at LDS col (q^(r&7))<<3; r&7 == il&7  (2-way bank
//          aliasing only = free, m136)
// Per K-step: 8 g2l16, 16 ds_read_b128, 32 MFMA (totals unchanged vs BK=32).
// ---------------------------------------------------------------------------
__device__ __forceinline__ void gemm_core(
    const __bf16* __restrict__ A, const __bf16* __restrict__ BT,
    __bf16* As, __bf16* Bs, int m0, int n0, int K, f32x4 (&acc)[4][4])
{
    const int tid = threadIdx.x, w = tid >> 6, l = tid & 63;
    const int il = l & 15, quad = l >> 4;
    const int wm = (w >> 1) * 64, wn = (w & 1) * 64;
    const int srow = l >> 3, scl = l & 7;            // 8 rows x 8 chunks

    const __bf16* ag = A  + (long)(m0 + w * 32 + srow) * K + ((scl ^ srow) << 3);
    const __bf16* bg = BT + (long)(n0 + w * 32 + srow) * K + ((scl ^ srow) << 3);
    const int xk0 = ((quad) ^ (il & 7)) << 3;
    const int xk1 = ((quad + 4) ^ (il & 7)) << 3;

    // prologue: stage K-tile 0 into buffer 0
#pragma unroll
    for (int j = 0; j < 4; ++j) {
        g2l16(As + (w * 32 + 8 * j) * 64, ag + (size_t)(8 * j) * K);
        g2l16(Bs + (w * 32 + 8 * j) * 64, bg + (size_t)(8 * j) * K);
    }
    __syncthreads();                      // drains vmcnt; buf0 ready

    int cur = 0;
    for (int k0 = 0; k0 < K; k0 += 64) {
        const int nxt = cur ^ 1;
        if (k0 + 64 < K) {                // async prefetch next K-tile
#pragma unroll
            for (int j = 0; j < 4; ++j) {
                g2l16(As + nxt * 8192 + (w * 32 + 8 * j) * 64,
                      ag + k0 + 64 + (size_t)(8 * j) * K);
                g2l16(Bs + nxt * 8192 + (w * 32 + 8 * j) * 64,
                      bg + k0 + 64 + (size_t)(8 * j) * K);
            }
        }

        bf16x8 af[4][2], bf[4][2];
#pragma unroll
        for (int f = 0; f < 4; ++f) {
            const __bf16* ar = As + cur * 8192 + (wm + f * 16 + il) * 64;
            af[f][0] = *(const bf16x8*)(ar + xk0);
            af[f][1] = *(const bf16x8*)(ar + xk1);
            const __bf16* br = Bs + cur * 8192 + (wn + f * 16 + il) * 64;
            bf[f][0] = *(const bf16x8*)(br + xk0);
            bf[f][1] = *(const bf16x8*)(br + xk1);
        }
#pragma unroll
        for (int i = 0; i < 4; ++i)
#pragma unroll
            for (int j = 0; j < 4; ++j) {
                acc[i][j] = __builtin_amdgcn_mfma_f32_16x16x32_bf16(
                    af[i][0], bf[j][0], acc[i][j], 0, 0, 0);
                acc[i][j] = __builtin_amdgcn_mfma_f32_16x16x32_bf16(
                    af[i][1], bf[j][1], acc[i][j], 0, 0, 0);
            }

        __syncthreads();                  // prefetch drained; cur reusable
        cur = nxt;
    }
}

// ---------------------------------------------------------------------------
// Merged projection GEMM: 1408 blocks.
// ---------------------------------------------------------------------------
__global__ __launch_bounds__(256, 2)
void gemm_proj(const __bf16* __restrict__ wbh, const __bf16* __restrict__ rbh,
               const __bf16* __restrict__ WqT, const __bf16* __restrict__ WkvT,
               const __bf16* __restrict__ WrT,
               __bf16* __restrict__ qwh, __bf16* __restrict__ qrh,
               __bf16* __restrict__ kh, __bf16* __restrict__ vhT,
               __bf16* __restrict__ rkh,
               const float* __restrict__ bw, const float* __restrict__ br)
{
    __shared__ __bf16 As[2 * 128 * 64];
    __shared__ __bf16 Bs[2 * 128 * 64];
    const int id = blockIdx.x;
    const __bf16 *A, *BT;
    int m0, n0, zz, kind;
    if (id < 1024) {
        n0 = (id & 15) * 128; m0 = ((id >> 4) & 15) * 128; zz = id >> 8;
        A = wbh + (size_t)zz * KLN * DM; BT = WkvT; kind = 3;
    } else if (id < 1280) {
        const int t = id - 1024;
        n0 = (t & 7) * 128; m0 = ((t >> 3) & 7) * 128; zz = t >> 6;
        A = wbh + (size_t)zz * KLN * DM + (size_t)MEM * DM; BT = WqT; kind = 2;
    } else {
        const int t = id - 1280;
        n0 = (t & 7) * 128; m0 = (t >> 3) * 128; zz = 0;
        A = rbh; BT = WrT; kind = 4;
    }

    f32x4 acc[4][4] = {};
    gemm_core(A, BT, As, Bs, m0, n0, DM, acc);

    const int tid = threadIdx.x, w = tid >> 6, l = tid & 63;
    const int il = l & 15, quad = l >> 4;
    const int wm = (w >> 1) * 64, wn = (w & 1) * 64;

    if (kind == 2) {
#pragma unroll
        for (int j = 0; j < 4; ++j) {
            const int col = n0 + wn + j * 16 + il;
            const int hn = col >> 6, d = col & 63;
            const float bwv = bw[col], brv = br[col];
            __bf16* q1 = qwh + ((size_t)(zz * 16 + hn) * 1024) * 64 + d;
            __bf16* q2 = qrh + ((size_t)(zz * 16 + hn) * 1024) * 64 + d;
#pragma unroll
            for (int i = 0; i < 4; ++i) {
                const int mb = m0 + wm + i * 16 + quad * 4;
#pragma unroll
                for (int rr = 0; rr < 4; ++rr) {
                    float v = acc[i][j][rr];
                    q1[(size_t)(mb + rr) * 64] = (__bf16)(v + bwv);
                    q2[(size_t)(mb + rr) * 64] = (__bf16)(v + brv);
                }
            }
        }
    } else if (kind == 3) {
        if (n0 + wn < 1024) {
#pragma unroll
            for (int j = 0; j < 4; ++j) {
                const int col = n0 + wn + j * 16 + il;
                const int hn = col >> 6, d = col & 63;
                __bf16* kp = kh + ((size_t)(zz * 16 + hn) * 2048) * 64 + d;
#pragma unroll
                for (int i = 0; i < 4; ++i) {
                    const int mb = m0 + wm + i * 16 + quad * 4;
#pragma unroll
                    for (int rr = 0; rr < 4; ++rr)
                        kp[(size_t)(mb + rr) * 64] = (__bf16)acc[i][j][rr];
                }
            }
        } else {
#pragma unroll
            for (int j = 0; j < 4; ++j) {
                const int col = n0 + wn + j * 16 + il - 1024;
                const int hn = col >> 6, d = col & 63;
                __bf16* vp = vhT + ((size_t)((zz * 16 + hn) * 64 + d)) * 2048;
#pragma unroll
                for (int i = 0; i < 4; ++i) {
                    const int mb = m0 + wm + i * 16 + quad * 4;
                    bf16x4t pk = {(__bf16)acc[i][j][0], (__bf16)acc[i][j][1],
                                  (__bf16)acc[i][j][2], (__bf16)acc[i][j][3]};
                    *(bf16x4t*)(vp + mb) = pk;
                }
            }
        }
    } else { // kind 4
#pragma unroll
        for (int j = 0; j < 4; ++j) {
            const int col = n0 + wn + j * 16 + il;
            const int hn = col >> 6, d = col & 63;
            __bf16* rp = rkh + ((size_t)hn * 2048) * 64 + d;
#pragma unroll
            for (int i = 0; i < 4; ++i) {
                const int mb = m0 + wm + i * 16 + quad * 4;
#pragma unroll
                for (int rr = 0; rr < 4; ++rr)
                    rp[(size_t)(mb + rr) * 64] = (__bf16)acc[i][j][rr];
            }
        }
    }
}

// ---------------------------------------------------------------------------
// Output projection: out = avh @ WoT^T, f32 C.  Grid (8,8,4).
// ---------------------------------------------------------------------------
__global__ __launch_bounds__(256, 2)
void gemm_out(const __bf16* __restrict__ avh, const __bf16* __restrict__ WoT,
              float* __restrict__ C)
{
    __shared__ __bf16 As[2 * 128 * 64];
    __shared__ __bf16 Bs[2 * 128 * 64];
    const int zz = blockIdx.z;
    const __bf16* A = avh + (size_t)zz * QL * DM;
    const int m0 = blockIdx.y * 128, n0 = blockIdx.x * 128;

    f32x4 acc[4][4] = {};
    gemm_core(A, WoT, As, Bs, m0, n0, DM, acc);

    const int tid = threadIdx.x, w = tid >> 6, l = tid & 63;
    const int il = l & 15, quad = l >> 4;
    const int wm = (w >> 1) * 64, wn = (w & 1) * 64;
    float* Cb = C + (size_t)zz * QL * DM;
#pragma unroll
    for (int i = 0; i < 4; ++i)
#pragma unroll
        for (int j = 0; j < 4; ++j) {
            float* cp = Cb + (long)(m0 + wm + i * 16 + quad * 4) * DM
                           + n0 + wn + j * 16 + il;
#pragma unroll
            for (int rr = 0; rr < 4; ++rr) cp[(long)rr * DM] = acc[i][j][rr];
        }
}

// ---------------------------------------------------------------------------
// MFMA flash attention, R19 EXACT (verified, total 334.1us): R18 core +
// quad-partial l deferred out of loop + fmax/psum trees.
// LDS: kt 8K | vt 8K | rkt 24K | scf 21K = 62464 B -> 2 blocks/CU.
// ---------------------------------------------------------------------------
__global__ __launch_bounds__(256, 2)
void attn_mfma(const __bf16* __restrict__ qwh, const __bf16* __restrict__ qrh,
               const __bf16* __restrict__ kh, const __bf16* __restrict__ vhT,
               const __bf16* __restrict__ rkh, float* __restrict__ Op,
               float* __restrict__ ml)
{
    extern __shared__ __bf16 smem[];
    __bf16* kt  = smem;            // [64][64] xor-swizzled
    __bf16* vt  = smem + 4096;     // [64][64] xor
    __bf16* rkt = smem + 8192;     // [192][64] xor, circular
    float*  scf = (float*)(smem + 20480);  // 4 waves x [16][84] f32 scratch

    const int bx = blockIdx.x;
    const int part = bx & 1;
    const int bx2 = bx >> 1;                     // 0..7
    const int ib = (bx2 & 1) ? (7 - (bx2 >> 1)) : (bx2 >> 1);
    const int i0 = ib * 128;
    const int n = blockIdx.y, b = blockIdx.z;
    const int tid = threadIdx.x;
    const int w = tid >> 6, l = tid & 63;
    const int il = l & 15, quad = l >> 4;
    const int iw0 = i0 + w * 32;

    // persistent Q fragments, 2 i-frags per wave
    bf16x8 qwf[2][2], qrf[2][2];
#pragma unroll
    for (int g = 0; g < 2; ++g) {
        const size_t qoff =
            ((size_t)((b * 16 + n) * QL + iw0 + 16 * g + il)) * 64 + quad * 8;
        qwf[g][0] = *(const bf16x8*)(qwh + qoff);
        qwf[g][1] = *(const bf16x8*)(qwh + qoff + 32);
        qrf[g][0] = *(const bf16x8*)(qrh + qoff);
        qrf[g][1] = *(const bf16x8*)(qrh + qoff + 32);
    }

    f32x4 O[2][4] = {};
    float m_i[2] = {-1e30f, -1e30f}, l_i[2] = {0.f, 0.f};  // l_i: quad-partial
    const float c = 0.125f * 1.44269504f;        // scale * log2(e)

    const int srow = l >> 3, scl = l & 7;        // staging: 8 rows x 8 chunks
    const __bf16* kbase  = kh  + ((size_t)((b * 16 + n) * KLN)) * 64;
    const __bf16* vbase0 = vhT + ((size_t)((b * 16 + n) * 64)) * KLN;
    const __bf16* rbp    = rkh + ((size_t)(n * KLN)) * 64;

    const int xk0 = ((quad) ^ (il & 7)) << 3;
    const int xk1 = ((quad + 4) ^ (il & 7)) << 3;

    const int nt = 2 * ib + 18;
    const int t0 = (part * nt) / 2;
    const int t1 = ((part + 1) * nt) / 2;
    int rot = (t0 % 3) * 64;                     // circular offset for tile t0

    const int ubB = 96 - 32 * w;                 // logical base of shared BD frags

    for (int jt = t0; jt < t1; ++jt) {
        const int j0 = jt * 64;
        const int vu0 = j0 - i0 + 896;           // rk row of logical rkt row 0
        __syncthreads();
#pragma unroll
        for (int it = 0; it < 2; ++it) {         // K tile rows j
            const int row = w * 16 + it * 8 + srow;
            g2l16(kt + (w * 16 + it * 8) * 64,
                  kbase + ((size_t)(j0 + row)) * 64 + ((scl ^ srow) << 3));
        }
#pragma unroll
        for (int it = 0; it < 2; ++it) {         // V^T tile rows d
            const int row = w * 16 + it * 8 + srow;
            g2l16(vt + (w * 16 + it * 8) * 64,
                  vbase0 + (size_t)row * KLN + j0 + ((scl ^ srow) << 3));
        }
        if (jt == t0) {                          // full 192-row window fill
#pragma unroll
            for (int it = 0; it < 6; ++it) {
                const int lbase = w * 48 + it * 8;
                int pb = lbase + rot; if (pb >= 192) pb -= 192;
                int vu = vu0 + lbase + srow;
                vu = vu < 0 ? 0 : (vu > KLN - 1 ? KLN - 1 : vu);
                g2l16(rkt + pb * 64,
                      rbp + (size_t)vu * 64 + ((scl ^ srow) << 3));
            }
        } else {                                 // slide: logical rows 128..191
#pragma unroll
            for (int it = 0; it < 2; ++it) {
                const int lbase = 128 + w * 16 + it * 8;
                int pb = lbase + rot; if (pb >= 192) pb -= 192;
                int vu = vu0 + lbase + srow;
                vu = vu < 0 ? 0 : (vu > KLN - 1 ? KLN - 1 : vu);
                g2l16(rkt + pb * 64,
                      rbp + (size_t)vu * 64 + ((scl ^ srow) << 3));
            }
        }
        __syncthreads();

        const bool edge = (j0 + 63 > i0 + MEM);

        // ---- Phase 1: AC for both g (kt frags read ONCE)
        f32x4 sf[2][4];
#pragma unroll
        for (int fr = 0; fr < 4; ++fr) {
            const __bf16* ka = kt + (fr * 16 + il) * 64;
            bf16x8 a0 = *(const bf16x8*)(ka + xk0);
            bf16x8 a1 = *(const bf16x8*)(ka + xk1);
            __builtin_amdgcn_s_setprio(1);
#pragma unroll
            for (int g = 0; g < 2; ++g) {
                f32x4 acc = {};
                acc = __builtin_amdgcn_mfma_f32_16x16x32_bf16(a0, qwf[g][0], acc, 0, 0, 0);
                acc = __builtin_amdgcn_mfma_f32_16x16x32_bf16(a1, qwf[g][1], acc, 0, 0, 0);
                sf[g][fr] = acc;
            }
            __builtin_amdgcn_s_setprio(0);
        }

        // ---- shared fragment loads, once per tile (used by both g)
        bf16x8 ra[6][2];
#pragma unroll
        for (int uf2 = 0; uf2 < 6; ++uf2) {
            int pr = ubB + uf2 * 16 + il + rot; if (pr >= 192) pr -= 192;
            const __bf16* rp_ = rkt + pr * 64;
            ra[uf2][0] = *(const bf16x8*)(rp_ + xk0);
            ra[uf2][1] = *(const bf16x8*)(rp_ + xk1);
        }
        bf16x8 va[4][2];
#pragma unroll
        for (int df = 0; df < 4; ++df) {
            const __bf16* vp_ = vt + (df * 16 + il) * 64;
            va[df][0] = *(const bf16x8*)(vp_ + xk0);
            va[df][1] = *(const bf16x8*)(vp_ + xk1);
        }

        // ---- per-g: BD(f32 scratch) -> gather/softmax -> P(scratch) -> PV
        float* scw = scf + w * 1344;             // per-wave [16][84] f32
#pragma unroll
        for (int g = 0; g < 2; ++g) {
            // BD: 5 frags, idx = uf+1-g (g0: ra[1..5], g1: ra[0..4])
#pragma unroll
            for (int uf = 0; uf < 5; ++uf) {
                const int idx = uf + 1 - g;
                f32x4 acc = {};
                __builtin_amdgcn_s_setprio(1);
                acc = __builtin_amdgcn_mfma_f32_16x16x32_bf16(ra[idx][0], qrf[g][0], acc, 0, 0, 0);
                acc = __builtin_amdgcn_mfma_f32_16x16x32_bf16(ra[idx][1], qrf[g][1], acc, 0, 0, 0);
                __builtin_amdgcn_s_setprio(0);
                *(f32x4*)(scw + il * 84 + uf * 16 + quad * 4) = acc;
            }

            const int i_gl = iw0 + 16 * g + il;
            float sv[4][4];
            float mfr[4];
#pragma unroll
            for (int fr = 0; fr < 4; ++fr) {
                const int base = il * 83 + fr * 16 + quad * 4 + 15;  // = il*84 + (jl_-il+15)
#pragma unroll
                for (int rr = 0; rr < 4; ++rr) {
                    const int jl_ = fr * 16 + quad * 4 + rr;
                    float s = sf[g][fr][rr] + scw[base + rr];
                    if (edge) s = (j0 + jl_ > i_gl + MEM) ? -1e30f : s;
                    sv[fr][rr] = s;
                }
                mfr[fr] = fmaxf(fmaxf(sv[fr][0], sv[fr][1]),
                                fmaxf(sv[fr][2], sv[fr][3]));
            }
            const float tmax = fmaxf(fmaxf(mfr[0], mfr[1]),
                                     fmaxf(mfr[2], mfr[3]));
            // ---- T13 defer-max: wave-uniform check, no divergence
            if (!__all(tmax <= m_i[g] + 8.0f)) {
                float t2 = fmaxf(tmax, __shfl_xor(tmax, 16));
                t2 = fmaxf(t2, __shfl_xor(t2, 32));
                const float m_new = fmaxf(m_i[g], t2);
                const float alpha = exp2f((m_i[g] - m_new) * c);
                l_i[g] *= alpha;                 // quad-partial: uniform scale
#pragma unroll
                for (int df = 0; df < 4; ++df) O[g][df] *= alpha;
                m_i[g] = m_new;
            }
            const float m_cur = m_i[g];
            float pfr[4];
            __bf16* prow = (__bf16*)(scw + il * 84);   // P overwrites row head
#pragma unroll
            for (int fr = 0; fr < 4; ++fr) {
                bf16x4t p4;
                float p0_ = exp2f((sv[fr][0] - m_cur) * c);
                float p1_ = exp2f((sv[fr][1] - m_cur) * c);
                float p2_ = exp2f((sv[fr][2] - m_cur) * c);
                float p3_ = exp2f((sv[fr][3] - m_cur) * c);
                p4[0] = (__bf16)p0_; p4[1] = (__bf16)p1_;
                p4[2] = (__bf16)p2_; p4[3] = (__bf16)p3_;
                pfr[fr] = (p0_ + p1_) + (p2_ + p3_);
                // after all gathers for this g (same wave): safe overwrite
                *(bf16x4t*)(prow + fr * 16 + quad * 4) = p4;
            }
            l_i[g] += (pfr[0] + pfr[1]) + (pfr[2] + pfr[3]);  // quad-partial

            bf16x8 p0 = *(const bf16x8*)(prow + quad * 8);
            bf16x8 p1 = *(const bf16x8*)(prow + 32 + quad * 8);
            __builtin_amdgcn_s_setprio(1);
#pragma unroll
            for (int df = 0; df < 4; ++df) {
                O[g][df] = __builtin_amdgcn_mfma_f32_16x16x32_bf16(va[df][0], p0, O[g][df], 0, 0, 0);
                O[g][df] = __builtin_amdgcn_mfma_f32_16x16x32_bf16(va[df][1], p1, O[g][df], 0, 0, 0);
            }
            __builtin_amdgcn_s_setprio(0);
        }
        rot += 64; if (rot >= 192) rot -= 192;
    }

    // ---- reduce quad-partial l across the 4 quads sharing il (once)
#pragma unroll
    for (int g = 0; g < 2; ++g) {
        l_i[g] += __shfl_xor(l_i[g], 16);
        l_i[g] += __shfl_xor(l_i[g], 32);
    }

    // ---- write partials (unnormalized)
#pragma unroll
    for (int g = 0; g < 2; ++g) {
        const int iL = w * 32 + 16 * g + il;
        float* opb = Op + (size_t)part * 4194304
                        + ((((size_t)b * NH + n) * 8 + ib)) * 8192
                        + (size_t)iL * 64 + quad * 4;
#pragma unroll
        for (int df = 0; df < 4; ++df)
            *(f32x4*)(opb + df * 16) = O[g][df];
        if (quad == 0) {
            const size_t base = (((size_t)b * NH + n) * 8 + ib) * 128 + iL;
            ml[(size_t)part * 65536 + base]          = m_i[g];
            ml[131072 + (size_t)part * 65536 + base] = l_i[g];
        }
    }
}

// ---------------------------------------------------------------------------
// Combine 2 attention partials -> avh bf16.  Grid (QL/4, NH, BSZ).
// ---------------------------------------------------------------------------
__global__ __launch_bounds__(256)
void attn_combine(const float* __restrict__ Op, const float* __restrict__ ml,
                  __bf16* __restrict__ av)
{
    const int tid = threadIdx.x;
    const int i = blockIdx.x * 4 + (tid >> 6);
    const int d = tid & 63;
    const int n = blockIdx.y, b = blockIdx.z;
    const int ib = i >> 7, iL = i & 127;
    const float c = 0.125f * 1.44269504f;

    const size_t mb = (((size_t)b * NH + n) * 8 + ib) * 128 + iL;
    const float m0 = ml[mb], m1 = ml[mb + 65536];
    const float l0 = ml[131072 + mb], l1 = ml[131072 + 65536 + mb];
    const float ms = fmaxf(m0, m1);
    const float w0 = exp2f((m0 - ms) * c);
    const float w1 = exp2f((m1 - ms) * c);
    const float ls = w0 * l0 + w1 * l1;

    const size_t ob = (((size_t)b * NH + n) * 8 + ib) * 8192
                      + (size_t)iL * 64 + d;
    const float o = w0 * Op[ob] + w1 * Op[ob + 4194304];
    av[((size_t)(b * QL + i)) * DM + n * 64 + d] = (__bf16)(o / ls);
}

// ---------------------------------------------------------------------------
// Workspace (MB offsets, ~123 MB total):
//  0 wbh(16) | 16 rbh(4) | 20 WqT(2) | 22 WkvT(4) | 26 WrT(2) | 28 WoT(2)
//  30 qwh(8) | 38 qrh(8) | 46 kh(16) | 62 vhT(16) | 78 rkh(4) | 82 avh(8)
//  90 Op(32) | 122 ml(1)
// ---------------------------------------------------------------------------
extern "C" void kernel_launch(void* const* d_in, const int* in_sizes, int n_in,
                              void* d_out, int out_size, void* d_ws, size_t ws_size,
                              hipStream_t stream)
{
    const float* w   = (const float*)d_in[0];
    const float* r   = (const float*)d_in[1];
    const float* bwb = (const float*)d_in[2];
    const float* brb = (const float*)d_in[3];
    const float* Wq  = (const float*)d_in[4];
    const float* Wkv = (const float*)d_in[5];
    const float* Wr  = (const float*)d_in[6];
    const float* Wo  = (const float*)d_in[7];
    float* out = (float*)d_out;

    char* ws = (char*)d_ws;
    __bf16* wbh  = (__bf16*)(ws);
    __bf16* rbh  = (__bf16*)(ws + ((size_t)16 << 20));
    __bf16* WqT  = (__bf16*)(ws + ((size_t)20 << 20));
    __bf16* WkvT = (__bf16*)(ws + ((size_t)22 << 20));
    __bf16* WrT  = (__bf16*)(ws + ((size_t)26 << 20));
    __bf16* WoT  = (__bf16*)(ws + ((size_t)28 << 20));
    __bf16* qwh  = (__bf16*)(ws + ((size_t)30 << 20));
    __bf16* qrh  = (__bf16*)(ws + ((size_t)38 << 20));
    __bf16* kh   = (__bf16*)(ws + ((size_t)46 << 20));
    __bf16* vhT  = (__bf16*)(ws + ((size_t)62 << 20));
    __bf16* rkh  = (__bf16*)(ws + ((size_t)78 << 20));
    __bf16* avh  = (__bf16*)(ws + ((size_t)82 << 20));
    float*  Op   = (float*)(ws + ((size_t)90 << 20));
    float*  mlb  = (float*)(ws + ((size_t)122 << 20));

    dim3 blk(256);
    prep<<<7168, blk, 0, stream>>>(w, r, Wq, Wr, Wo, Wkv,
                                   wbh, rbh, WqT, WrT, WoT, WkvT);
    gemm_proj<<<1408, blk, 0, stream>>>(wbh, rbh, WqT, WkvT, WrT,
                                        qwh, qrh, kh, vhT, rkh, bwb, brb);
    attn_mfma<<<dim3(16, 16, 4), blk, 62464, stream>>>(
        qwh, qrh, kh, vhT, rkh, Op, mlb);
    attn_combine<<<dim3(256, 16, 4), blk, 0, stream>>>(Op, mlb, avh);
    gemm_out<<<dim3(8, 8, 4), blk, 0, stream>>>(avh, WoT, out);
}

// Round 17
// 313.377 us; speedup vs baseline: 1.1713x; 1.0549x over previous
//
#include <hip/hip_runtime.h>

// Problem constants (Transformer-XL attention)
constexpr int BSZ  = 4;
constexpr int NH   = 16;
constexpr int DH   = 64;
constexpr int QL   = 1024;
constexpr int KLN  = 2048;
constexpr int DM   = 1024;   // d_model = NH*DH
constexpr int MEM  = 1024;   // KLEN - QLEN

typedef __bf16 bf16x8  __attribute__((ext_vector_type(8)));
typedef __bf16 bf16x4t __attribute__((ext_vector_type(4)));
typedef float  f32x4   __attribute__((ext_vector_type(4)));

// async global->LDS, 16B per lane; LDS dst is wave-uniform base + lane*16
__device__ __forceinline__ void g2l16(__bf16* lds, const __bf16* g) {
    __builtin_amdgcn_global_load_lds(
        (const __attribute__((address_space(1))) unsigned int*)g,
        (__attribute__((address_space(3))) unsigned int*)lds, 16, 0, 0);
}

// ---------------------------------------------------------------------------
// prep: one launch. Blocks [0,5120): cast w,r -> bf16. Blocks [5120,7168):
// transpose-cast the 4 weights (z = t>>9: 0 Wq, 1 Wr, 2 Wo, 3 Wkv).
// ---------------------------------------------------------------------------
__global__ __launch_bounds__(256)
void prep(const float* __restrict__ w, const float* __restrict__ r,
          const float* __restrict__ Wq, const float* __restrict__ Wr,
          const float* __restrict__ Wo, const float* __restrict__ Wkv,
          __bf16* __restrict__ wbh, __bf16* __restrict__ rbh,
          __bf16* __restrict__ WqT, __bf16* __restrict__ WrT,
          __bf16* __restrict__ WoT, __bf16* __restrict__ WkvT)
{
    __shared__ __bf16 t[64 * 72];
    const int id = blockIdx.x;
    if (id < 5120) {
        const float* in; __bf16* out; size_t i;
        if (id < 4096) { in = w; out = wbh; i = ((size_t)id * 256 + threadIdx.x) * 8; }
        else { in = r; out = rbh; i = ((size_t)(id - 4096) * 256 + threadIdx.x) * 8; }
        float4 a = *(const float4*)(in + i);
        float4 b = *(const float4*)(in + i + 4);
        bf16x8 y = {(__bf16)a.x, (__bf16)a.y, (__bf16)a.z, (__bf16)a.w,
                    (__bf16)b.x, (__bf16)b.y, (__bf16)b.z, (__bf16)b.w};
        *(bf16x8*)(out + i) = y;
        return;
    }
    const int tt = id - 5120;
    const int z = tt >> 9, rem = tt & 511;
    const int xx = rem & 31, yy = rem >> 5;
    const float* in; __bf16* out; int N;
    if (z == 0)      { in = Wq;  out = WqT;  N = 1024; }
    else if (z == 1) { in = Wr;  out = WrT;  N = 1024; }
    else if (z == 2) { in = Wo;  out = WoT;  N = 1024; }
    else             { in = Wkv; out = WkvT; N = 2048; }
    if (xx * 64 >= N) return;
    const int n0 = xx * 64, k0 = yy * 64;
    const int row = threadIdx.x >> 2, seg = (threadIdx.x & 3) << 4;
    const float* src = in + (long)(k0 + row) * N + n0 + seg;
#pragma unroll
    for (int u = 0; u < 16; u += 4) {
        float4 x = *(const float4*)(src + u);
        t[(seg + u + 0) * 72 + row] = (__bf16)x.x;
        t[(seg + u + 1) * 72 + row] = (__bf16)x.y;
        t[(seg + u + 2) * 72 + row] = (__bf16)x.z;
        t[(seg + u + 3) * 72 + row] = (__bf16)x.w;
    }
    __syncthreads();
    __bf16* dst = out + (long)(n0 + row) * 1024 + k0 + seg;
    *(uint4*)(dst)     = *(const uint4*)(t + row * 72 + seg);
    *(uint4*)(dst + 8) = *(const uint4*)(t + row * 72 + seg + 8);
}

// ---------------------------------------------------------------------------
// Shared GEMM core R20: 128x128 tile, BK=64, 4 waves, 2-phase double-buffer.
// (R20 measured: -3.5us vs BK=32 -- barrier drains mostly amortized already.)
// ---------------------------------------------------------------------------
__device__ __forceinline__ void gemm_core(
    const __bf16* __restrict__ A, const __bf16* __restrict__ BT,
    __bf16* As, __bf16* Bs, int m0, int n0, int K, f32x4 (&acc)[4][4])
{
    const int tid = threadIdx.x, w = tid >> 6, l = tid & 63;
    const int il = l & 15, quad = l >> 4;
    const int wm = (w >> 1) * 64, wn = (w & 1) * 64;
    const int srow = l >> 3, scl = l & 7;            // 8 rows x 8 chunks

    const __bf16* ag = A  + (long)(m0 + w * 32 + srow) * K + ((scl ^ srow) << 3);
    const __bf16* bg = BT + (long)(n0 + w * 32 + srow) * K + ((scl ^ srow) << 3);
    const int xk0 = ((quad) ^ (il & 7)) << 3;
    const int xk1 = ((quad + 4) ^ (il & 7)) << 3;

    // prologue: stage K-tile 0 into buffer 0
#pragma unroll
    for (int j = 0; j < 4; ++j) {
        g2l16(As + (w * 32 + 8 * j) * 64, ag + (size_t)(8 * j) * K);
        g2l16(Bs + (w * 32 + 8 * j) * 64, bg + (size_t)(8 * j) * K);
    }
    __syncthreads();                      // drains vmcnt; buf0 ready

    int cur = 0;
    for (int k0 = 0; k0 < K; k0 += 64) {
        const int nxt = cur ^ 1;
        if (k0 + 64 < K) {                // async prefetch next K-tile
#pragma unroll
            for (int j = 0; j < 4; ++j) {
                g2l16(As + nxt * 8192 + (w * 32 + 8 * j) * 64,
                      ag + k0 + 64 + (size_t)(8 * j) * K);
                g2l16(Bs + nxt * 8192 + (w * 32 + 8 * j) * 64,
                      bg + k0 + 64 + (size_t)(8 * j) * K);
            }
        }

        bf16x8 af[4][2], bf[4][2];
#pragma unroll
        for (int f = 0; f < 4; ++f) {
            const __bf16* ar = As + cur * 8192 + (wm + f * 16 + il) * 64;
            af[f][0] = *(const bf16x8*)(ar + xk0);
            af[f][1] = *(const bf16x8*)(ar + xk1);
            const __bf16* br = Bs + cur * 8192 + (wn + f * 16 + il) * 64;
            bf[f][0] = *(const bf16x8*)(br + xk0);
            bf[f][1] = *(const bf16x8*)(br + xk1);
        }
#pragma unroll
        for (int i = 0; i < 4; ++i)
#pragma unroll
            for (int j = 0; j < 4; ++j) {
                acc[i][j] = __builtin_amdgcn_mfma_f32_16x16x32_bf16(
                    af[i][0], bf[j][0], acc[i][j], 0, 0, 0);
                acc[i][j] = __builtin_amdgcn_mfma_f32_16x16x32_bf16(
                    af[i][1], bf[j][1], acc[i][j], 0, 0, 0);
            }

        __syncthreads();                  // prefetch drained; cur reusable
        cur = nxt;
    }
}

// ---------------------------------------------------------------------------
// Merged projection GEMM: 1408 blocks.
// ---------------------------------------------------------------------------
__global__ __launch_bounds__(256, 2)
void gemm_proj(const __bf16* __restrict__ wbh, const __bf16* __restrict__ rbh,
               const __bf16* __restrict__ WqT, const __bf16* __restrict__ WkvT,
               const __bf16* __restrict__ WrT,
               __bf16* __restrict__ qwh, __bf16* __restrict__ qrh,
               __bf16* __restrict__ kh, __bf16* __restrict__ vhT,
               __bf16* __restrict__ rkh,
               const float* __restrict__ bw, const float* __restrict__ br)
{
    __shared__ __bf16 As[2 * 128 * 64];
    __shared__ __bf16 Bs[2 * 128 * 64];
    const int id = blockIdx.x;
    const __bf16 *A, *BT;
    int m0, n0, zz, kind;
    if (id < 1024) {
        n0 = (id & 15) * 128; m0 = ((id >> 4) & 15) * 128; zz = id >> 8;
        A = wbh + (size_t)zz * KLN * DM; BT = WkvT; kind = 3;
    } else if (id < 1280) {
        const int t = id - 1024;
        n0 = (t & 7) * 128; m0 = ((t >> 3) & 7) * 128; zz = t >> 6;
        A = wbh + (size_t)zz * KLN * DM + (size_t)MEM * DM; BT = WqT; kind = 2;
    } else {
        const int t = id - 1280;
        n0 = (t & 7) * 128; m0 = (t >> 3) * 128; zz = 0;
        A = rbh; BT = WrT; kind = 4;
    }

    f32x4 acc[4][4] = {};
    gemm_core(A, BT, As, Bs, m0, n0, DM, acc);

    const int tid = threadIdx.x, w = tid >> 6, l = tid & 63;
    const int il = l & 15, quad = l >> 4;
    const int wm = (w >> 1) * 64, wn = (w & 1) * 64;

    if (kind == 2) {
#pragma unroll
        for (int j = 0; j < 4; ++j) {
            const int col = n0 + wn + j * 16 + il;
            const int hn = col >> 6, d = col & 63;
            const float bwv = bw[col], brv = br[col];
            __bf16* q1 = qwh + ((size_t)(zz * 16 + hn) * 1024) * 64 + d;
            __bf16* q2 = qrh + ((size_t)(zz * 16 + hn) * 1024) * 64 + d;
#pragma unroll
            for (int i = 0; i < 4; ++i) {
                const int mb = m0 + wm + i * 16 + quad * 4;
#pragma unroll
                for (int rr = 0; rr < 4; ++rr) {
                    float v = acc[i][j][rr];
                    q1[(size_t)(mb + rr) * 64] = (__bf16)(v + bwv);
                    q2[(size_t)(mb + rr) * 64] = (__bf16)(v + brv);
                }
            }
        }
    } else if (kind == 3) {
        if (n0 + wn < 1024) {
#pragma unroll
            for (int j = 0; j < 4; ++j) {
                const int col = n0 + wn + j * 16 + il;
                const int hn = col >> 6, d = col & 63;
                __bf16* kp = kh + ((size_t)(zz * 16 + hn) * 2048) * 64 + d;
#pragma unroll
                for (int i = 0; i < 4; ++i) {
                    const int mb = m0 + wm + i * 16 + quad * 4;
#pragma unroll
                    for (int rr = 0; rr < 4; ++rr)
                        kp[(size_t)(mb + rr) * 64] = (__bf16)acc[i][j][rr];
                }
            }
        } else {
#pragma unroll
            for (int j = 0; j < 4; ++j) {
                const int col = n0 + wn + j * 16 + il - 1024;
                const int hn = col >> 6, d = col & 63;
                __bf16* vp = vhT + ((size_t)((zz * 16 + hn) * 64 + d)) * 2048;
#pragma unroll
                for (int i = 0; i < 4; ++i) {
                    const int mb = m0 + wm + i * 16 + quad * 4;
                    bf16x4t pk = {(__bf16)acc[i][j][0], (__bf16)acc[i][j][1],
                                  (__bf16)acc[i][j][2], (__bf16)acc[i][j][3]};
                    *(bf16x4t*)(vp + mb) = pk;
                }
            }
        }
    } else { // kind 4
#pragma unroll
        for (int j = 0; j < 4; ++j) {
            const int col = n0 + wn + j * 16 + il;
            const int hn = col >> 6, d = col & 63;
            __bf16* rp = rkh + ((size_t)hn * 2048) * 64 + d;
#pragma unroll
            for (int i = 0; i < 4; ++i) {
                const int mb = m0 + wm + i * 16 + quad * 4;
#pragma unroll
                for (int rr = 0; rr < 4; ++rr)
                    rp[(size_t)(mb + rr) * 64] = (__bf16)acc[i][j][rr];
            }
        }
    }
}

// ---------------------------------------------------------------------------
// Output projection: out = avh @ WoT^T, f32 C.  Grid (8,8,4).
// ---------------------------------------------------------------------------
__global__ __launch_bounds__(256, 2)
void gemm_out(const __bf16* __restrict__ avh, const __bf16* __restrict__ WoT,
              float* __restrict__ C)
{
    __shared__ __bf16 As[2 * 128 * 64];
    __shared__ __bf16 Bs[2 * 128 * 64];
    const int zz = blockIdx.z;
    const __bf16* A = avh + (size_t)zz * QL * DM;
    const int m0 = blockIdx.y * 128, n0 = blockIdx.x * 128;

    f32x4 acc[4][4] = {};
    gemm_core(A, WoT, As, Bs, m0, n0, DM, acc);

    const int tid = threadIdx.x, w = tid >> 6, l = tid & 63;
    const int il = l & 15, quad = l >> 4;
    const int wm = (w >> 1) * 64, wn = (w & 1) * 64;
    float* Cb = C + (size_t)zz * QL * DM;
#pragma unroll
    for (int i = 0; i < 4; ++i)
#pragma unroll
        for (int j = 0; j < 4; ++j) {
            float* cp = Cb + (long)(m0 + wm + i * 16 + quad * 4) * DM
                           + n0 + wn + j * 16 + il;
#pragma unroll
            for (int rr = 0; rr < 4; ++rr) cp[(long)rr * DM] = acc[i][j][rr];
        }
}

// ---------------------------------------------------------------------------
// MFMA flash attention, R21: SINGLE-PASS (no part split, no combine kernel).
// Grid (8,16,4) = 512 blocks = 2/CU x 256 CU -> still full residency in one
// scheduling wave; each block runs ALL nt tiles and writes NORMALIZED bf16
// avh directly (O/l after the post-loop l reduction -- identical math to the
// old cross-part merge).  Eliminates: attn_combine launch (~16us), 65MB of
// Op/ml HBM round-trip, one rkt prologue fill + Q load per (head,i-block).
// Per-tile code byte-identical to verified R19/R20.
// LDS: kt 8K | vt 8K | rkt 24K | scf 21K = 62464 B -> 2 blocks/CU.
// ---------------------------------------------------------------------------
__global__ __launch_bounds__(256, 2)
void attn_mfma(const __bf16* __restrict__ qwh, const __bf16* __restrict__ qrh,
               const __bf16* __restrict__ kh, const __bf16* __restrict__ vhT,
               const __bf16* __restrict__ rkh, __bf16* __restrict__ av)
{
    extern __shared__ __bf16 smem[];
    __bf16* kt  = smem;            // [64][64] xor-swizzled
    __bf16* vt  = smem + 4096;     // [64][64] xor
    __bf16* rkt = smem + 8192;     // [192][64] xor, circular
    float*  scf = (float*)(smem + 20480);  // 4 waves x [16][84] f32 scratch

    const int bx = blockIdx.x;                   // 0..7
    const int ib = (bx & 1) ? (7 - (bx >> 1)) : (bx >> 1);
    const int i0 = ib * 128;
    const int n = blockIdx.y, b = blockIdx.z;
    const int tid = threadIdx.x;
    const int w = tid >> 6, l = tid & 63;
    const int il = l & 15, quad = l >> 4;
    const int iw0 = i0 + w * 32;

    // persistent Q fragments, 2 i-frags per wave
    bf16x8 qwf[2][2], qrf[2][2];
#pragma unroll
    for (int g = 0; g < 2; ++g) {
        const size_t qoff =
            ((size_t)((b * 16 + n) * QL + iw0 + 16 * g + il)) * 64 + quad * 8;
        qwf[g][0] = *(const bf16x8*)(qwh + qoff);
        qwf[g][1] = *(const bf16x8*)(qwh + qoff + 32);
        qrf[g][0] = *(const bf16x8*)(qrh + qoff);
        qrf[g][1] = *(const bf16x8*)(qrh + qoff + 32);
    }

    f32x4 O[2][4] = {};
    float m_i[2] = {-1e30f, -1e30f}, l_i[2] = {0.f, 0.f};  // l_i: quad-partial
    const float c = 0.125f * 1.44269504f;        // scale * log2(e)

    const int srow = l >> 3, scl = l & 7;        // staging: 8 rows x 8 chunks
    const __bf16* kbase  = kh  + ((size_t)((b * 16 + n) * KLN)) * 64;
    const __bf16* vbase0 = vhT + ((size_t)((b * 16 + n) * 64)) * KLN;
    const __bf16* rbp    = rkh + ((size_t)(n * KLN)) * 64;

    const int xk0 = ((quad) ^ (il & 7)) << 3;
    const int xk1 = ((quad + 4) ^ (il & 7)) << 3;

    const int nt = 2 * ib + 18;                  // all tiles, single pass
    int rot = 0;

    const int ubB = 96 - 32 * w;                 // logical base of shared BD frags

    for (int jt = 0; jt < nt; ++jt) {
        const int j0 = jt * 64;
        const int vu0 = j0 - i0 + 896;           // rk row of logical rkt row 0
        __syncthreads();
#pragma unroll
        for (int it = 0; it < 2; ++it) {         // K tile rows j
            const int row = w * 16 + it * 8 + srow;
            g2l16(kt + (w * 16 + it * 8) * 64,
                  kbase + ((size_t)(j0 + row)) * 64 + ((scl ^ srow) << 3));
        }
#pragma unroll
        for (int it = 0; it < 2; ++it) {         // V^T tile rows d
            const int row = w * 16 + it * 8 + srow;
            g2l16(vt + (w * 16 + it * 8) * 64,
                  vbase0 + (size_t)row * KLN + j0 + ((scl ^ srow) << 3));
        }
        if (jt == 0) {                           // full 192-row window fill
#pragma unroll
            for (int it = 0; it < 6; ++it) {
                const int lbase = w * 48 + it * 8;
                int pb = lbase + rot; if (pb >= 192) pb -= 192;
                int vu = vu0 + lbase + srow;
                vu = vu < 0 ? 0 : (vu > KLN - 1 ? KLN - 1 : vu);
                g2l16(rkt + pb * 64,
                      rbp + (size_t)vu * 64 + ((scl ^ srow) << 3));
            }
        } else {                                 // slide: logical rows 128..191
#pragma unroll
            for (int it = 0; it < 2; ++it) {
                const int lbase = 128 + w * 16 + it * 8;
                int pb = lbase + rot; if (pb >= 192) pb -= 192;
                int vu = vu0 + lbase + srow;
                vu = vu < 0 ? 0 : (vu > KLN - 1 ? KLN - 1 : vu);
                g2l16(rkt + pb * 64,
                      rbp + (size_t)vu * 64 + ((scl ^ srow) << 3));
            }
        }
        __syncthreads();

        const bool edge = (j0 + 63 > i0 + MEM);

        // ---- Phase 1: AC for both g (kt frags read ONCE)
        f32x4 sf[2][4];
#pragma unroll
        for (int fr = 0; fr < 4; ++fr) {
            const __bf16* ka = kt + (fr * 16 + il) * 64;
            bf16x8 a0 = *(const bf16x8*)(ka + xk0);
            bf16x8 a1 = *(const bf16x8*)(ka + xk1);
            __builtin_amdgcn_s_setprio(1);
#pragma unroll
            for (int g = 0; g < 2; ++g) {
                f32x4 acc = {};
                acc = __builtin_amdgcn_mfma_f32_16x16x32_bf16(a0, qwf[g][0], acc, 0, 0, 0);
                acc = __builtin_amdgcn_mfma_f32_16x16x32_bf16(a1, qwf[g][1], acc, 0, 0, 0);
                sf[g][fr] = acc;
            }
            __builtin_amdgcn_s_setprio(0);
        }

        // ---- shared fragment loads, once per tile (used by both g)
        bf16x8 ra[6][2];
#pragma unroll
        for (int uf2 = 0; uf2 < 6; ++uf2) {
            int pr = ubB + uf2 * 16 + il + rot; if (pr >= 192) pr -= 192;
            const __bf16* rp_ = rkt + pr * 64;
            ra[uf2][0] = *(const bf16x8*)(rp_ + xk0);
            ra[uf2][1] = *(const bf16x8*)(rp_ + xk1);
        }
        bf16x8 va[4][2];
#pragma unroll
        for (int df = 0; df < 4; ++df) {
            const __bf16* vp_ = vt + (df * 16 + il) * 64;
            va[df][0] = *(const bf16x8*)(vp_ + xk0);
            va[df][1] = *(const bf16x8*)(vp_ + xk1);
        }

        // ---- per-g: BD(f32 scratch) -> gather/softmax -> P(scratch) -> PV
        float* scw = scf + w * 1344;             // per-wave [16][84] f32
#pragma unroll
        for (int g = 0; g < 2; ++g) {
            // BD: 5 frags, idx = uf+1-g (g0: ra[1..5], g1: ra[0..4])
#pragma unroll
            for (int uf = 0; uf < 5; ++uf) {
                const int idx = uf + 1 - g;
                f32x4 acc = {};
                __builtin_amdgcn_s_setprio(1);
                acc = __builtin_amdgcn_mfma_f32_16x16x32_bf16(ra[idx][0], qrf[g][0], acc, 0, 0, 0);
                acc = __builtin_amdgcn_mfma_f32_16x16x32_bf16(ra[idx][1], qrf[g][1], acc, 0, 0, 0);
                __builtin_amdgcn_s_setprio(0);
                *(f32x4*)(scw + il * 84 + uf * 16 + quad * 4) = acc;
            }

            const int i_gl = iw0 + 16 * g + il;
            float sv[4][4];
            float mfr[4];
#pragma unroll
            for (int fr = 0; fr < 4; ++fr) {
                const int base = il * 83 + fr * 16 + quad * 4 + 15;  // = il*84 + (jl_-il+15)
#pragma unroll
                for (int rr = 0; rr < 4; ++rr) {
                    const int jl_ = fr * 16 + quad * 4 + rr;
                    float s = sf[g][fr][rr] + scw[base + rr];
                    if (edge) s = (j0 + jl_ > i_gl + MEM) ? -1e30f : s;
                    sv[fr][rr] = s;
                }
                mfr[fr] = fmaxf(fmaxf(sv[fr][0], sv[fr][1]),
                                fmaxf(sv[fr][2], sv[fr][3]));
            }
            const float tmax = fmaxf(fmaxf(mfr[0], mfr[1]),
                                     fmaxf(mfr[2], mfr[3]));
            // ---- T13 defer-max: wave-uniform check, no divergence
            if (!__all(tmax <= m_i[g] + 8.0f)) {
                float t2 = fmaxf(tmax, __shfl_xor(tmax, 16));
                t2 = fmaxf(t2, __shfl_xor(t2, 32));
                const float m_new = fmaxf(m_i[g], t2);
                const float alpha = exp2f((m_i[g] - m_new) * c);
                l_i[g] *= alpha;                 // quad-partial: uniform scale
#pragma unroll
                for (int df = 0; df < 4; ++df) O[g][df] *= alpha;
                m_i[g] = m_new;
            }
            const float m_cur = m_i[g];
            float pfr[4];
            __bf16* prow = (__bf16*)(scw + il * 84);   // P overwrites row head
#pragma unroll
            for (int fr = 0; fr < 4; ++fr) {
                bf16x4t p4;
                float p0_ = exp2f((sv[fr][0] - m_cur) * c);
                float p1_ = exp2f((sv[fr][1] - m_cur) * c);
                float p2_ = exp2f((sv[fr][2] - m_cur) * c);
                float p3_ = exp2f((sv[fr][3] - m_cur) * c);
                p4[0] = (__bf16)p0_; p4[1] = (__bf16)p1_;
                p4[2] = (__bf16)p2_; p4[3] = (__bf16)p3_;
                pfr[fr] = (p0_ + p1_) + (p2_ + p3_);
                // after all gathers for this g (same wave): safe overwrite
                *(bf16x4t*)(prow + fr * 16 + quad * 4) = p4;
            }
            l_i[g] += (pfr[0] + pfr[1]) + (pfr[2] + pfr[3]);  // quad-partial

            bf16x8 p0 = *(const bf16x8*)(prow + quad * 8);
            bf16x8 p1 = *(const bf16x8*)(prow + 32 + quad * 8);
            __builtin_amdgcn_s_setprio(1);
#pragma unroll
            for (int df = 0; df < 4; ++df) {
                O[g][df] = __builtin_amdgcn_mfma_f32_16x16x32_bf16(va[df][0], p0, O[g][df], 0, 0, 0);
                O[g][df] = __builtin_amdgcn_mfma_f32_16x16x32_bf16(va[df][1], p1, O[g][df], 0, 0, 0);
            }
            __builtin_amdgcn_s_setprio(0);
        }
        rot += 64; if (rot >= 192) rot -= 192;
    }

    // ---- reduce quad-partial l across the 4 quads sharing il (once)
#pragma unroll
    for (int g = 0; g < 2; ++g) {
        l_i[g] += __shfl_xor(l_i[g], 16);
        l_i[g] += __shfl_xor(l_i[g], 32);
    }

    // ---- write NORMALIZED bf16 output directly (no combine pass)
#pragma unroll
    for (int g = 0; g < 2; ++g) {
        const float rl = 1.0f / l_i[g];
        const int i_gl = i0 + w * 32 + 16 * g + il;
        __bf16* avb = av + ((size_t)(b * QL + i_gl)) * DM + n * 64 + quad * 4;
#pragma unroll
        for (int df = 0; df < 4; ++df) {
            bf16x4t o4 = {(__bf16)(O[g][df][0] * rl), (__bf16)(O[g][df][1] * rl),
                          (__bf16)(O[g][df][2] * rl), (__bf16)(O[g][df][3] * rl)};
            *(bf16x4t*)(avb + df * 16) = o4;
        }
    }
}

// ---------------------------------------------------------------------------
// Workspace (MB offsets):
//  0 wbh(16) | 16 rbh(4) | 20 WqT(2) | 22 WkvT(4) | 26 WrT(2) | 28 WoT(2)
//  30 qwh(8) | 38 qrh(8) | 46 kh(16) | 62 vhT(16) | 78 rkh(4) | 82 avh(8)
// ---------------------------------------------------------------------------
extern "C" void kernel_launch(void* const* d_in, const int* in_sizes, int n_in,
                              void* d_out, int out_size, void* d_ws, size_t ws_size,
                              hipStream_t stream)
{
    const float* w   = (const float*)d_in[0];
    const float* r   = (const float*)d_in[1];
    const float* bwb = (const float*)d_in[2];
    const float* brb = (const float*)d_in[3];
    const float* Wq  = (const float*)d_in[4];
    const float* Wkv = (const float*)d_in[5];
    const float* Wr  = (const float*)d_in[6];
    const float* Wo  = (const float*)d_in[7];
    float* out = (float*)d_out;

    char* ws = (char*)d_ws;
    __bf16* wbh  = (__bf16*)(ws);
    __bf16* rbh  = (__bf16*)(ws + ((size_t)16 << 20));
    __bf16* WqT  = (__bf16*)(ws + ((size_t)20 << 20));
    __bf16* WkvT = (__bf16*)(ws + ((size_t)22 << 20));
    __bf16* WrT  = (__bf16*)(ws + ((size_t)26 << 20));
    __bf16* WoT  = (__bf16*)(ws + ((size_t)28 << 20));
    __bf16* qwh  = (__bf16*)(ws + ((size_t)30 << 20));
    __bf16* qrh  = (__bf16*)(ws + ((size_t)38 << 20));
    __bf16* kh   = (__bf16*)(ws + ((size_t)46 << 20));
    __bf16* vhT  = (__bf16*)(ws + ((size_t)62 << 20));
    __bf16* rkh  = (__bf16*)(ws + ((size_t)78 << 20));
    __bf16* avh  = (__bf16*)(ws + ((size_t)82 << 20));

    dim3 blk(256);
    prep<<<7168, blk, 0, stream>>>(w, r, Wq, Wr, Wo, Wkv,
                                   wbh, rbh, WqT, WrT, WoT, WkvT);
    gemm_proj<<<1408, blk, 0, stream>>>(wbh, rbh, WqT, WkvT, WrT,
                                        qwh, qrh, kh, vhT, rkh, bwb, brb);
    attn_mfma<<<dim3(8, 16, 4), blk, 62464, stream>>>(
        qwh, qrh, kh, vhT, rkh, avh);
    gemm_out<<<dim3(8, 8, 4), blk, 0, stream>>>(avh, WoT, out);
}

// Round 18
// 311.705 us; speedup vs baseline: 1.1776x; 1.0054x over previous
//
#include <hip/hip_runtime.h>

// Problem constants (Transformer-XL attention)
constexpr int BSZ  = 4;
constexpr int NH   = 16;
constexpr int DH   = 64;
constexpr int QL   = 1024;
constexpr int KLN  = 2048;
constexpr int DM   = 1024;   // d_model = NH*DH
constexpr int MEM  = 1024;   // KLEN - QLEN

typedef __bf16 bf16x8  __attribute__((ext_vector_type(8)));
typedef __bf16 bf16x4t __attribute__((ext_vector_type(4)));
typedef float  f32x4   __attribute__((ext_vector_type(4)));

// async global->LDS, 16B per lane; LDS dst is wave-uniform base + lane*16
__device__ __forceinline__ void g2l16(__bf16* lds, const __bf16* g) {
    __builtin_amdgcn_global_load_lds(
        (const __attribute__((address_space(1))) unsigned int*)g,
        (__attribute__((address_space(3))) unsigned int*)lds, 16, 0, 0);
}

// ---------------------------------------------------------------------------
// prep: one launch. Blocks [0,5120): cast w,r -> bf16. Blocks [5120,7168):
// transpose-cast the 4 weights (z = t>>9: 0 Wq, 1 Wr, 2 Wo, 3 Wkv).
// ---------------------------------------------------------------------------
__global__ __launch_bounds__(256)
void prep(const float* __restrict__ w, const float* __restrict__ r,
          const float* __restrict__ Wq, const float* __restrict__ Wr,
          const float* __restrict__ Wo, const float* __restrict__ Wkv,
          __bf16* __restrict__ wbh, __bf16* __restrict__ rbh,
          __bf16* __restrict__ WqT, __bf16* __restrict__ WrT,
          __bf16* __restrict__ WoT, __bf16* __restrict__ WkvT)
{
    __shared__ __bf16 t[64 * 72];
    const int id = blockIdx.x;
    if (id < 5120) {
        const float* in; __bf16* out; size_t i;
        if (id < 4096) { in = w; out = wbh; i = ((size_t)id * 256 + threadIdx.x) * 8; }
        else { in = r; out = rbh; i = ((size_t)(id - 4096) * 256 + threadIdx.x) * 8; }
        float4 a = *(const float4*)(in + i);
        float4 b = *(const float4*)(in + i + 4);
        bf16x8 y = {(__bf16)a.x, (__bf16)a.y, (__bf16)a.z, (__bf16)a.w,
                    (__bf16)b.x, (__bf16)b.y, (__bf16)b.z, (__bf16)b.w};
        *(bf16x8*)(out + i) = y;
        return;
    }
    const int tt = id - 5120;
    const int z = tt >> 9, rem = tt & 511;
    const int xx = rem & 31, yy = rem >> 5;
    const float* in; __bf16* out; int N;
    if (z == 0)      { in = Wq;  out = WqT;  N = 1024; }
    else if (z == 1) { in = Wr;  out = WrT;  N = 1024; }
    else if (z == 2) { in = Wo;  out = WoT;  N = 1024; }
    else             { in = Wkv; out = WkvT; N = 2048; }
    if (xx * 64 >= N) return;
    const int n0 = xx * 64, k0 = yy * 64;
    const int row = threadIdx.x >> 2, seg = (threadIdx.x & 3) << 4;
    const float* src = in + (long)(k0 + row) * N + n0 + seg;
#pragma unroll
    for (int u = 0; u < 16; u += 4) {
        float4 x = *(const float4*)(src + u);
        t[(seg + u + 0) * 72 + row] = (__bf16)x.x;
        t[(seg + u + 1) * 72 + row] = (__bf16)x.y;
        t[(seg + u + 2) * 72 + row] = (__bf16)x.z;
        t[(seg + u + 3) * 72 + row] = (__bf16)x.w;
    }
    __syncthreads();
    __bf16* dst = out + (long)(n0 + row) * 1024 + k0 + seg;
    *(uint4*)(dst)     = *(const uint4*)(t + row * 72 + seg);
    *(uint4*)(dst + 8) = *(const uint4*)(t + row * 72 + seg + 8);
}

// ---------------------------------------------------------------------------
// Shared GEMM core R20: 128x128 tile, BK=64, 4 waves, 2-phase double-buffer.
// ---------------------------------------------------------------------------
__device__ __forceinline__ void gemm_core(
    const __bf16* __restrict__ A, const __bf16* __restrict__ BT,
    __bf16* As, __bf16* Bs, int m0, int n0, int K, f32x4 (&acc)[4][4])
{
    const int tid = threadIdx.x, w = tid >> 6, l = tid & 63;
    const int il = l & 15, quad = l >> 4;
    const int wm = (w >> 1) * 64, wn = (w & 1) * 64;
    const int srow = l >> 3, scl = l & 7;            // 8 rows x 8 chunks

    const __bf16* ag = A  + (long)(m0 + w * 32 + srow) * K + ((scl ^ srow) << 3);
    const __bf16* bg = BT + (long)(n0 + w * 32 + srow) * K + ((scl ^ srow) << 3);
    const int xk0 = ((quad) ^ (il & 7)) << 3;
    const int xk1 = ((quad + 4) ^ (il & 7)) << 3;

    // prologue: stage K-tile 0 into buffer 0
#pragma unroll
    for (int j = 0; j < 4; ++j) {
        g2l16(As + (w * 32 + 8 * j) * 64, ag + (size_t)(8 * j) * K);
        g2l16(Bs + (w * 32 + 8 * j) * 64, bg + (size_t)(8 * j) * K);
    }
    __syncthreads();                      // drains vmcnt; buf0 ready

    int cur = 0;
    for (int k0 = 0; k0 < K; k0 += 64) {
        const int nxt = cur ^ 1;
        if (k0 + 64 < K) {                // async prefetch next K-tile
#pragma unroll
            for (int j = 0; j < 4; ++j) {
                g2l16(As + nxt * 8192 + (w * 32 + 8 * j) * 64,
                      ag + k0 + 64 + (size_t)(8 * j) * K);
                g2l16(Bs + nxt * 8192 + (w * 32 + 8 * j) * 64,
                      bg + k0 + 64 + (size_t)(8 * j) * K);
            }
        }

        bf16x8 af[4][2], bf[4][2];
#pragma unroll
        for (int f = 0; f < 4; ++f) {
            const __bf16* ar = As + cur * 8192 + (wm + f * 16 + il) * 64;
            af[f][0] = *(const bf16x8*)(ar + xk0);
            af[f][1] = *(const bf16x8*)(ar + xk1);
            const __bf16* br = Bs + cur * 8192 + (wn + f * 16 + il) * 64;
            bf[f][0] = *(const bf16x8*)(br + xk0);
            bf[f][1] = *(const bf16x8*)(br + xk1);
        }
#pragma unroll
        for (int i = 0; i < 4; ++i)
#pragma unroll
            for (int j = 0; j < 4; ++j) {
                acc[i][j] = __builtin_amdgcn_mfma_f32_16x16x32_bf16(
                    af[i][0], bf[j][0], acc[i][j], 0, 0, 0);
                acc[i][j] = __builtin_amdgcn_mfma_f32_16x16x32_bf16(
                    af[i][1], bf[j][1], acc[i][j], 0, 0, 0);
            }

        __syncthreads();                  // prefetch drained; cur reusable
        cur = nxt;
    }
}

// ---------------------------------------------------------------------------
// Merged projection GEMM: 1408 blocks.
// ---------------------------------------------------------------------------
__global__ __launch_bounds__(256, 2)
void gemm_proj(const __bf16* __restrict__ wbh, const __bf16* __restrict__ rbh,
               const __bf16* __restrict__ WqT, const __bf16* __restrict__ WkvT,
               const __bf16* __restrict__ WrT,
               __bf16* __restrict__ qwh, __bf16* __restrict__ qrh,
               __bf16* __restrict__ kh, __bf16* __restrict__ vhT,
               __bf16* __restrict__ rkh,
               const float* __restrict__ bw, const float* __restrict__ br)
{
    __shared__ __bf16 As[2 * 128 * 64];
    __shared__ __bf16 Bs[2 * 128 * 64];
    const int id = blockIdx.x;
    const __bf16 *A, *BT;
    int m0, n0, zz, kind;
    if (id < 1024) {
        n0 = (id & 15) * 128; m0 = ((id >> 4) & 15) * 128; zz = id >> 8;
        A = wbh + (size_t)zz * KLN * DM; BT = WkvT; kind = 3;
    } else if (id < 1280) {
        const int t = id - 1024;
        n0 = (t & 7) * 128; m0 = ((t >> 3) & 7) * 128; zz = t >> 6;
        A = wbh + (size_t)zz * KLN * DM + (size_t)MEM * DM; BT = WqT; kind = 2;
    } else {
        const int t = id - 1280;
        n0 = (t & 7) * 128; m0 = (t >> 3) * 128; zz = 0;
        A = rbh; BT = WrT; kind = 4;
    }

    f32x4 acc[4][4] = {};
    gemm_core(A, BT, As, Bs, m0, n0, DM, acc);

    const int tid = threadIdx.x, w = tid >> 6, l = tid & 63;
    const int il = l & 15, quad = l >> 4;
    const int wm = (w >> 1) * 64, wn = (w & 1) * 64;

    if (kind == 2) {
#pragma unroll
        for (int j = 0; j < 4; ++j) {
            const int col = n0 + wn + j * 16 + il;
            const int hn = col >> 6, d = col & 63;
            const float bwv = bw[col], brv = br[col];
            __bf16* q1 = qwh + ((size_t)(zz * 16 + hn) * 1024) * 64 + d;
            __bf16* q2 = qrh + ((size_t)(zz * 16 + hn) * 1024) * 64 + d;
#pragma unroll
            for (int i = 0; i < 4; ++i) {
                const int mb = m0 + wm + i * 16 + quad * 4;
#pragma unroll
                for (int rr = 0; rr < 4; ++rr) {
                    float v = acc[i][j][rr];
                    q1[(size_t)(mb + rr) * 64] = (__bf16)(v + bwv);
                    q2[(size_t)(mb + rr) * 64] = (__bf16)(v + brv);
                }
            }
        }
    } else if (kind == 3) {
        if (n0 + wn < 1024) {
#pragma unroll
            for (int j = 0; j < 4; ++j) {
                const int col = n0 + wn + j * 16 + il;
                const int hn = col >> 6, d = col & 63;
                __bf16* kp = kh + ((size_t)(zz * 16 + hn) * 2048) * 64 + d;
#pragma unroll
                for (int i = 0; i < 4; ++i) {
                    const int mb = m0 + wm + i * 16 + quad * 4;
#pragma unroll
                    for (int rr = 0; rr < 4; ++rr)
                        kp[(size_t)(mb + rr) * 64] = (__bf16)acc[i][j][rr];
                }
            }
        } else {
#pragma unroll
            for (int j = 0; j < 4; ++j) {
                const int col = n0 + wn + j * 16 + il - 1024;
                const int hn = col >> 6, d = col & 63;
                __bf16* vp = vhT + ((size_t)((zz * 16 + hn) * 64 + d)) * 2048;
#pragma unroll
                for (int i = 0; i < 4; ++i) {
                    const int mb = m0 + wm + i * 16 + quad * 4;
                    bf16x4t pk = {(__bf16)acc[i][j][0], (__bf16)acc[i][j][1],
                                  (__bf16)acc[i][j][2], (__bf16)acc[i][j][3]};
                    *(bf16x4t*)(vp + mb) = pk;
                }
            }
        }
    } else { // kind 4
#pragma unroll
        for (int j = 0; j < 4; ++j) {
            const int col = n0 + wn + j * 16 + il;
            const int hn = col >> 6, d = col & 63;
            __bf16* rp = rkh + ((size_t)hn * 2048) * 64 + d;
#pragma unroll
            for (int i = 0; i < 4; ++i) {
                const int mb = m0 + wm + i * 16 + quad * 4;
#pragma unroll
                for (int rr = 0; rr < 4; ++rr)
                    rp[(size_t)(mb + rr) * 64] = (__bf16)acc[i][j][rr];
            }
        }
    }
}

// ---------------------------------------------------------------------------
// Output projection: out = avh @ WoT^T, f32 C.  Grid (8,8,4).
// ---------------------------------------------------------------------------
__global__ __launch_bounds__(256, 2)
void gemm_out(const __bf16* __restrict__ avh, const __bf16* __restrict__ WoT,
              float* __restrict__ C)
{
    __shared__ __bf16 As[2 * 128 * 64];
    __shared__ __bf16 Bs[2 * 128 * 64];
    const int zz = blockIdx.z;
    const __bf16* A = avh + (size_t)zz * QL * DM;
    const int m0 = blockIdx.y * 128, n0 = blockIdx.x * 128;

    f32x4 acc[4][4] = {};
    gemm_core(A, WoT, As, Bs, m0, n0, DM, acc);

    const int tid = threadIdx.x, w = tid >> 6, l = tid & 63;
    const int il = l & 15, quad = l >> 4;
    const int wm = (w >> 1) * 64, wn = (w & 1) * 64;
    float* Cb = C + (size_t)zz * QL * DM;
#pragma unroll
    for (int i = 0; i < 4; ++i)
#pragma unroll
        for (int j = 0; j < 4; ++j) {
            float* cp = Cb + (long)(m0 + wm + i * 16 + quad * 4) * DM
                           + n0 + wn + j * 16 + il;
#pragma unroll
            for (int rr = 0; rr < 4; ++rr) cp[(long)rr * DM] = acc[i][j][rr];
        }
}

// ---------------------------------------------------------------------------
// MFMA flash attention, R22: R21 single-pass + COMPLEMENTARY CU PAIRING.
// R21 measured: attn 132->145us absorbing combine; per-block work nt=2*ib+18
// in {18..32}.  With 512 blocks on 512 slots, a CU's two blocks are lin and
// lin+256 (grid x-fastest, 256 = b-half boundary) -> SAME ib -> per-CU load
// 2*nt in {36..64}, makespan set by 64 while mean is 50 (~28% tail idle).
// Fix: flip ib -> 7-ib for b>=2, so each CU pairs (nt, 50-nt): all CUs = 50.
// Bijective per b (permutation of ib) -> correctness independent of dispatch
// order (G16); only speed rides on the round-robin heuristic.
// Per-tile code byte-identical to verified R21.
// LDS: kt 8K | vt 8K | rkt 24K | scf 21K = 62464 B -> 2 blocks/CU.
// ---------------------------------------------------------------------------
__global__ __launch_bounds__(256, 2)
void attn_mfma(const __bf16* __restrict__ qwh, const __bf16* __restrict__ qrh,
               const __bf16* __restrict__ kh, const __bf16* __restrict__ vhT,
               const __bf16* __restrict__ rkh, __bf16* __restrict__ av)
{
    extern __shared__ __bf16 smem[];
    __bf16* kt  = smem;            // [64][64] xor-swizzled
    __bf16* vt  = smem + 4096;     // [64][64] xor
    __bf16* rkt = smem + 8192;     // [192][64] xor, circular
    float*  scf = (float*)(smem + 20480);  // 4 waves x [16][84] f32 scratch

    const int bx = blockIdx.x;                   // 0..7
    int ib = (bx & 1) ? (7 - (bx >> 1)) : (bx >> 1);
    const int n = blockIdx.y, b = blockIdx.z;
    if (b >= 2) ib = 7 - ib;                     // complementary CU pairing
    const int i0 = ib * 128;
    const int tid = threadIdx.x;
    const int w = tid >> 6, l = tid & 63;
    const int il = l & 15, quad = l >> 4;
    const int iw0 = i0 + w * 32;

    // persistent Q fragments, 2 i-frags per wave
    bf16x8 qwf[2][2], qrf[2][2];
#pragma unroll
    for (int g = 0; g < 2; ++g) {
        const size_t qoff =
            ((size_t)((b * 16 + n) * QL + iw0 + 16 * g + il)) * 64 + quad * 8;
        qwf[g][0] = *(const bf16x8*)(qwh + qoff);
        qwf[g][1] = *(const bf16x8*)(qwh + qoff + 32);
        qrf[g][0] = *(const bf16x8*)(qrh + qoff);
        qrf[g][1] = *(const bf16x8*)(qrh + qoff + 32);
    }

    f32x4 O[2][4] = {};
    float m_i[2] = {-1e30f, -1e30f}, l_i[2] = {0.f, 0.f};  // l_i: quad-partial
    const float c = 0.125f * 1.44269504f;        // scale * log2(e)

    const int srow = l >> 3, scl = l & 7;        // staging: 8 rows x 8 chunks
    const __bf16* kbase  = kh  + ((size_t)((b * 16 + n) * KLN)) * 64;
    const __bf16* vbase0 = vhT + ((size_t)((b * 16 + n) * 64)) * KLN;
    const __bf16* rbp    = rkh + ((size_t)(n * KLN)) * 64;

    const int xk0 = ((quad) ^ (il & 7)) << 3;
    const int xk1 = ((quad + 4) ^ (il & 7)) << 3;

    const int nt = 2 * ib + 18;                  // all tiles, single pass
    int rot = 0;

    const int ubB = 96 - 32 * w;                 // logical base of shared BD frags

    for (int jt = 0; jt < nt; ++jt) {
        const int j0 = jt * 64;
        const int vu0 = j0 - i0 + 896;           // rk row of logical rkt row 0
        __syncthreads();
#pragma unroll
        for (int it = 0; it < 2; ++it) {         // K tile rows j
            const int row = w * 16 + it * 8 + srow;
            g2l16(kt + (w * 16 + it * 8) * 64,
                  kbase + ((size_t)(j0 + row)) * 64 + ((scl ^ srow) << 3));
        }
#pragma unroll
        for (int it = 0; it < 2; ++it) {         // V^T tile rows d
            const int row = w * 16 + it * 8 + srow;
            g2l16(vt + (w * 16 + it * 8) * 64,
                  vbase0 + (size_t)row * KLN + j0 + ((scl ^ srow) << 3));
        }
        if (jt == 0) {                           // full 192-row window fill
#pragma unroll
            for (int it = 0; it < 6; ++it) {
                const int lbase = w * 48 + it * 8;
                int pb = lbase + rot; if (pb >= 192) pb -= 192;
                int vu = vu0 + lbase + srow;
                vu = vu < 0 ? 0 : (vu > KLN - 1 ? KLN - 1 : vu);
                g2l16(rkt + pb * 64,
                      rbp + (size_t)vu * 64 + ((scl ^ srow) << 3));
            }
        } else {                                 // slide: logical rows 128..191
#pragma unroll
            for (int it = 0; it < 2; ++it) {
                const int lbase = 128 + w * 16 + it * 8;
                int pb = lbase + rot; if (pb >= 192) pb -= 192;
                int vu = vu0 + lbase + srow;
                vu = vu < 0 ? 0 : (vu > KLN - 1 ? KLN - 1 : vu);
                g2l16(rkt + pb * 64,
                      rbp + (size_t)vu * 64 + ((scl ^ srow) << 3));
            }
        }
        __syncthreads();

        const bool edge = (j0 + 63 > i0 + MEM);

        // ---- Phase 1: AC for both g (kt frags read ONCE)
        f32x4 sf[2][4];
#pragma unroll
        for (int fr = 0; fr < 4; ++fr) {
            const __bf16* ka = kt + (fr * 16 + il) * 64;
            bf16x8 a0 = *(const bf16x8*)(ka + xk0);
            bf16x8 a1 = *(const bf16x8*)(ka + xk1);
            __builtin_amdgcn_s_setprio(1);
#pragma unroll
            for (int g = 0; g < 2; ++g) {
                f32x4 acc = {};
                acc = __builtin_amdgcn_mfma_f32_16x16x32_bf16(a0, qwf[g][0], acc, 0, 0, 0);
                acc = __builtin_amdgcn_mfma_f32_16x16x32_bf16(a1, qwf[g][1], acc, 0, 0, 0);
                sf[g][fr] = acc;
            }
            __builtin_amdgcn_s_setprio(0);
        }

        // ---- shared fragment loads, once per tile (used by both g)
        bf16x8 ra[6][2];
#pragma unroll
        for (int uf2 = 0; uf2 < 6; ++uf2) {
            int pr = ubB + uf2 * 16 + il + rot; if (pr >= 192) pr -= 192;
            const __bf16* rp_ = rkt + pr * 64;
            ra[uf2][0] = *(const bf16x8*)(rp_ + xk0);
            ra[uf2][1] = *(const bf16x8*)(rp_ + xk1);
        }
        bf16x8 va[4][2];
#pragma unroll
        for (int df = 0; df < 4; ++df) {
            const __bf16* vp_ = vt + (df * 16 + il) * 64;
            va[df][0] = *(const bf16x8*)(vp_ + xk0);
            va[df][1] = *(const bf16x8*)(vp_ + xk1);
        }

        // ---- per-g: BD(f32 scratch) -> gather/softmax -> P(scratch) -> PV
        float* scw = scf + w * 1344;             // per-wave [16][84] f32
#pragma unroll
        for (int g = 0; g < 2; ++g) {
            // BD: 5 frags, idx = uf+1-g (g0: ra[1..5], g1: ra[0..4])
#pragma unroll
            for (int uf = 0; uf < 5; ++uf) {
                const int idx = uf + 1 - g;
                f32x4 acc = {};
                __builtin_amdgcn_s_setprio(1);
                acc = __builtin_amdgcn_mfma_f32_16x16x32_bf16(ra[idx][0], qrf[g][0], acc, 0, 0, 0);
                acc = __builtin_amdgcn_mfma_f32_16x16x32_bf16(ra[idx][1], qrf[g][1], acc, 0, 0, 0);
                __builtin_amdgcn_s_setprio(0);
                *(f32x4*)(scw + il * 84 + uf * 16 + quad * 4) = acc;
            }

            const int i_gl = iw0 + 16 * g + il;
            float sv[4][4];
            float mfr[4];
#pragma unroll
            for (int fr = 0; fr < 4; ++fr) {
                const int base = il * 83 + fr * 16 + quad * 4 + 15;  // = il*84 + (jl_-il+15)
#pragma unroll
                for (int rr = 0; rr < 4; ++rr) {
                    const int jl_ = fr * 16 + quad * 4 + rr;
                    float s = sf[g][fr][rr] + scw[base + rr];
                    if (edge) s = (j0 + jl_ > i_gl + MEM) ? -1e30f : s;
                    sv[fr][rr] = s;
                }
                mfr[fr] = fmaxf(fmaxf(sv[fr][0], sv[fr][1]),
                                fmaxf(sv[fr][2], sv[fr][3]));
            }
            const float tmax = fmaxf(fmaxf(mfr[0], mfr[1]),
                                     fmaxf(mfr[2], mfr[3]));
            // ---- T13 defer-max: wave-uniform check, no divergence
            if (!__all(tmax <= m_i[g] + 8.0f)) {
                float t2 = fmaxf(tmax, __shfl_xor(tmax, 16));
                t2 = fmaxf(t2, __shfl_xor(t2, 32));
                const float m_new = fmaxf(m_i[g], t2);
                const float alpha = exp2f((m_i[g] - m_new) * c);
                l_i[g] *= alpha;                 // quad-partial: uniform scale
#pragma unroll
                for (int df = 0; df < 4; ++df) O[g][df] *= alpha;
                m_i[g] = m_new;
            }
            const float m_cur = m_i[g];
            float pfr[4];
            __bf16* prow = (__bf16*)(scw + il * 84);   // P overwrites row head
#pragma unroll
            for (int fr = 0; fr < 4; ++fr) {
                bf16x4t p4;
                float p0_ = exp2f((sv[fr][0] - m_cur) * c);
                float p1_ = exp2f((sv[fr][1] - m_cur) * c);
                float p2_ = exp2f((sv[fr][2] - m_cur) * c);
                float p3_ = exp2f((sv[fr][3] - m_cur) * c);
                p4[0] = (__bf16)p0_; p4[1] = (__bf16)p1_;
                p4[2] = (__bf16)p2_; p4[3] = (__bf16)p3_;
                pfr[fr] = (p0_ + p1_) + (p2_ + p3_);
                // after all gathers for this g (same wave): safe overwrite
                *(bf16x4t*)(prow + fr * 16 + quad * 4) = p4;
            }
            l_i[g] += (pfr[0] + pfr[1]) + (pfr[2] + pfr[3]);  // quad-partial

            bf16x8 p0 = *(const bf16x8*)(prow + quad * 8);
            bf16x8 p1 = *(const bf16x8*)(prow + 32 + quad * 8);
            __builtin_amdgcn_s_setprio(1);
#pragma unroll
            for (int df = 0; df < 4; ++df) {
                O[g][df] = __builtin_amdgcn_mfma_f32_16x16x32_bf16(va[df][0], p0, O[g][df], 0, 0, 0);
                O[g][df] = __builtin_amdgcn_mfma_f32_16x16x32_bf16(va[df][1], p1, O[g][df], 0, 0, 0);
            }
            __builtin_amdgcn_s_setprio(0);
        }
        rot += 64; if (rot >= 192) rot -= 192;
    }

    // ---- reduce quad-partial l across the 4 quads sharing il (once)
#pragma unroll
    for (int g = 0; g < 2; ++g) {
        l_i[g] += __shfl_xor(l_i[g], 16);
        l_i[g] += __shfl_xor(l_i[g], 32);
    }

    // ---- write NORMALIZED bf16 output directly (no combine pass)
#pragma unroll
    for (int g = 0; g < 2; ++g) {
        const float rl = 1.0f / l_i[g];
        const int i_gl = i0 + w * 32 + 16 * g + il;
        __bf16* avb = av + ((size_t)(b * QL + i_gl)) * DM + n * 64 + quad * 4;
#pragma unroll
        for (int df = 0; df < 4; ++df) {
            bf16x4t o4 = {(__bf16)(O[g][df][0] * rl), (__bf16)(O[g][df][1] * rl),
                          (__bf16)(O[g][df][2] * rl), (__bf16)(O[g][df][3] * rl)};
            *(bf16x4t*)(avb + df * 16) = o4;
        }
    }
}

// ---------------------------------------------------------------------------
// Workspace (MB offsets):
//  0 wbh(16) | 16 rbh(4) | 20 WqT(2) | 22 WkvT(4) | 26 WrT(2) | 28 WoT(2)
//  30 qwh(8) | 38 qrh(8) | 46 kh(16) | 62 vhT(16) | 78 rkh(4) | 82 avh(8)
// ---------------------------------------------------------------------------
extern "C" void kernel_launch(void* const* d_in, const int* in_sizes, int n_in,
                              void* d_out, int out_size, void* d_ws, size_t ws_size,
                              hipStream_t stream)
{
    const float* w   = (const float*)d_in[0];
    const float* r   = (const float*)d_in[1];
    const float* bwb = (const float*)d_in[2];
    const float* brb = (const float*)d_in[3];
    const float* Wq  = (const float*)d_in[4];
    const float* Wkv = (const float*)d_in[5];
    const float* Wr  = (const float*)d_in[6];
    const float* Wo  = (const float*)d_in[7];
    float* out = (float*)d_out;

    char* ws = (char*)d_ws;
    __bf16* wbh  = (__bf16*)(ws);
    __bf16* rbh  = (__bf16*)(ws + ((size_t)16 << 20));
    __bf16* WqT  = (__bf16*)(ws + ((size_t)20 << 20));
    __bf16* WkvT = (__bf16*)(ws + ((size_t)22 << 20));
    __bf16* WrT  = (__bf16*)(ws + ((size_t)26 << 20));
    __bf16* WoT  = (__bf16*)(ws + ((size_t)28 << 20));
    __bf16* qwh  = (__bf16*)(ws + ((size_t)30 << 20));
    __bf16* qrh  = (__bf16*)(ws + ((size_t)38 << 20));
    __bf16* kh   = (__bf16*)(ws + ((size_t)46 << 20));
    __bf16* vhT  = (__bf16*)(ws + ((size_t)62 << 20));
    __bf16* rkh  = (__bf16*)(ws + ((size_t)78 << 20));
    __bf16* avh  = (__bf16*)(ws + ((size_t)82 << 20));

    dim3 blk(256);
    prep<<<7168, blk, 0, stream>>>(w, r, Wq, Wr, Wo, Wkv,
                                   wbh, rbh, WqT, WrT, WoT, WkvT);
    gemm_proj<<<1408, blk, 0, stream>>>(wbh, rbh, WqT, WkvT, WrT,
                                        qwh, qrh, kh, vhT, rkh, bwb, brb);
    attn_mfma<<<dim3(8, 16, 4), blk, 62464, stream>>>(
        qwh, qrh, kh, vhT, rkh, avh);
    gemm_out<<<dim3(8, 8, 4), blk, 0, stream>>>(avh, WoT, out);
}